// Round 17
// baseline (631.937 us; speedup 1.0000x reference)
//
#include <hip/hip_runtime.h>
#include <hip/hip_bf16.h>
#include <math.h>

#define N_NODES 50000
#define N_EDGES 800000
#define T_G 4
#define IN_F 128
#define HID_F 64
#define OUT_F 3
#define H_M 8

// bucketed CSR build params
#define BSH 9
#define NBKT 98            // ceil(50000 / 512)
#define CHK 4096
#define NCHK 196           // ceil(800000 / 4096)
#define HTOT (NBKT * NCHK) // 19208

typedef short bf16x8 __attribute__((ext_vector_type(8)));
typedef float f32x4 __attribute__((ext_vector_type(4)));

__device__ __forceinline__ float lrelu(float v) { return v > 0.f ? v : 0.2f * v; }

__device__ __forceinline__ float wred_sum(float v) {
#pragma unroll
    for (int o = 32; o; o >>= 1) v += __shfl_xor(v, o);
    return v;
}
__device__ __forceinline__ float bf2f(unsigned int u) {
    return __uint_as_float(u << 16);
}
__device__ __forceinline__ float bflo(unsigned int u) {  // low bf16 of pair, 1 op
    return __uint_as_float(u << 16);
}
__device__ __forceinline__ float bfhi(unsigned int u) {  // high bf16 of pair, 1 op
    return __uint_as_float(u & 0xFFFF0000u);
}
__device__ __forceinline__ short f2bf(float f) {  // RNE f32->bf16 bits
    unsigned u = __float_as_uint(f);
    u += 0x7FFF + ((u >> 16) & 1);
    return (short)(u >> 16);
}

// ---- weight/bias precompute:
// w[0:4]=w2, [4:8]=w3, [8:11]=cb2, [11:14]=cb3, [16:40]=cbM, [64:128]=bavg1
__global__ void k_wvec(const float* __restrict__ fc2, const float* __restrict__ fc3,
                       const float* __restrict__ b1, const float* __restrict__ b2,
                       const float* __restrict__ b3, const float* __restrict__ bM,
                       float* __restrict__ w) {
    __shared__ float w2[4], w3[4];
    int i = threadIdx.x;
    if (i < 4) {
        float a = 0.f, b = 0.f;
        for (int r = 0; r < T_G; r++) { a += fc2[r * T_G + i]; b += fc3[r * T_G + i]; }
        w2[i] = 0.25f * a; w3[i] = 0.25f * b;
        w[i] = w2[i]; w[4 + i] = w3[i];
    }
    __syncthreads();
    if (i < 3) {
        float c = 0.f;
        for (int t = 0; t < T_G; t++) c += w2[t] * b2[t * 3 + i];
        w[8 + i] = c;
    }
    if (i >= 8 && i < 11) {
        int d = i - 8;
        float c = 0.f;
        for (int t = 0; t < T_G; t++) c += w3[t] * b3[t * 3 + d];
        w[11 + d] = c;
    }
    if (i >= 16 && i < 40) {
        int j = i - 16;
        float c = 0.f;
        for (int t = 0; t < T_G; t++) c += w3[t] * bM[t * 24 + j];
        w[16 + j] = c;
    }
    if (i >= 64 && i < 128) {
        int c = i - 64;
        w[i] = 0.25f * (b1[c] + b1[HID_F + c] + b1[2 * HID_F + c] + b1[3 * HID_F + c]);
    }
}

// ---- one-shot init of all pre-biased accumulators
__global__ void k_init_all(const float* __restrict__ w, float* __restrict__ h1,
                           float* __restrict__ h2, float* __restrict__ h3,
                           float* __restrict__ hM) {
    int i = blockIdx.x * 256 + threadIdx.x;
    if (i < N_NODES * HID_F) h1[i] = w[64 + (i & 63)];
    if (i < N_NODES * 3) { h2[i] = w[8 + i % 3]; h3[i] = w[11 + i % 3]; }
    if (i < N_NODES * 24) hM[i] = w[16 + i % 24];
}

// ---- layer-1 GEMM via MFMA: block = 16 nodes x 64 cols x one t; wave = 16-col tile
__global__ __launch_bounds__(256) void k_gemm1(
    const float* __restrict__ x, const float* __restrict__ W1,
    const float* __restrict__ al1, const float* __restrict__ ar1,
    __hip_bfloat16* __restrict__ feat1, float* __restrict__ el1, float* __restrict__ er1) {
    __shared__ float tile[16][HID_F];
    int t = blockIdx.y;
    int base = blockIdx.x * 16;
    int w = threadIdx.x >> 6, lane = threadIdx.x & 63;
    int lr = lane & 15, lk = lane >> 4;
    const float* xrow = x + (size_t)(base + lr) * IN_F;
    const float* Wt = W1 + (size_t)t * IN_F * HID_F;
    f32x4 acc = {0.f, 0.f, 0.f, 0.f};
#pragma unroll
    for (int ks = 0; ks < 4; ks++) {
        int k0 = ks * 32 + lk * 8;
        const float4* xp = (const float4*)(xrow + k0);
        float4 v0 = xp[0], v1 = xp[1];
        bf16x8 a, b;
        a[0] = f2bf(v0.x); a[1] = f2bf(v0.y); a[2] = f2bf(v0.z); a[3] = f2bf(v0.w);
        a[4] = f2bf(v1.x); a[5] = f2bf(v1.y); a[6] = f2bf(v1.z); a[7] = f2bf(v1.w);
#pragma unroll
        for (int j = 0; j < 8; j++) b[j] = f2bf(Wt[(k0 + j) * HID_F + w * 16 + lr]);
        acc = __builtin_amdgcn_mfma_f32_16x16x32_bf16(a, b, acc, 0, 0, 0);
    }
#pragma unroll
    for (int r = 0; r < 4; r++) tile[lk * 4 + r][w * 16 + lr] = acc[r];
    __syncthreads();
#pragma unroll
    for (int q = 0; q < 4; q++) {
        int e = q * 256 + threadIdx.x;
        int node = e >> 6, c = e & 63;
        feat1[((size_t)t * N_NODES + base + node) * HID_F + c] = __float2bfloat16(tile[node][c]);
    }
    float alv = al1[t * HID_F + lane], arv = ar1[t * HID_F + lane];
#pragma unroll
    for (int q = 0; q < 4; q++) {
        int node = w * 4 + q;
        float f = tile[node][lane];
        float vl = wred_sum(f * alv);
        float vr = wred_sum(f * arv);
        if (lane == 0) {
            el1[t * N_NODES + base + node] = vl;
            er1[t * N_NODES + base + node] = vr;
        }
    }
}

// ==== bucketed CSR build (no global atomics, no random HBM RMW) ====

__global__ __launch_bounds__(256) void k_bcount(const int* __restrict__ edges,
                                                int* __restrict__ hist) {
    int t = blockIdx.y, c = blockIdx.x;
    __shared__ int hl[NBKT];
    if (threadIdx.x < NBKT) hl[threadIdx.x] = 0;
    __syncthreads();
    const int* dst = edges + (t * 2 + 1) * N_EDGES;
    int e0 = c * CHK, e1 = min(e0 + CHK, N_EDGES);
    for (int i = e0 + threadIdx.x; i < e1; i += 256)
        atomicAdd(&hl[dst[i] >> BSH], 1);
    __syncthreads();
    if (threadIdx.x < NBKT) hist[t * HTOT + threadIdx.x * NCHK + c] = hl[threadIdx.x];
}

__global__ __launch_bounds__(1024) void k_bscan(int* __restrict__ hist) {
    int t = blockIdx.x;
    int* H = hist + t * HTOT;
    __shared__ int ws[16];
    __shared__ int carry;
    if (threadIdx.x == 0) carry = 0;
    __syncthreads();
    int lane = threadIdx.x & 63, wid = threadIdx.x >> 6;
    for (int base = 0; base < HTOT; base += 1024) {
        int i = base + threadIdx.x;
        int v = (i < HTOT) ? H[i] : 0;
        int sc = v;
#pragma unroll
        for (int o = 1; o < 64; o <<= 1) { int u = __shfl_up(sc, o); if (lane >= o) sc += u; }
        if (lane == 63) ws[wid] = sc;
        __syncthreads();
        if (wid == 0 && lane < 16) {
            int wv = ws[lane];
#pragma unroll
            for (int o = 1; o < 16; o <<= 1) { int u = __shfl_up(wv, o); if (lane >= o) wv += u; }
            ws[lane] = wv;
        }
        __syncthreads();
        int woff = (wid == 0) ? 0 : ws[wid - 1];
        if (i < HTOT) H[i] = carry + woff + sc - v;  // exclusive
        int tot = ws[15];
        __syncthreads();
        if (threadIdx.x == 0) carry += tot;
        __syncthreads();
    }
}

__global__ __launch_bounds__(256) void k_bscatter(const int* __restrict__ edges,
                                                  const int* __restrict__ hist,
                                                  int2* __restrict__ bedge) {
    int t = blockIdx.y, c = blockIdx.x;
    __shared__ int cur[NBKT];
    if (threadIdx.x < NBKT) cur[threadIdx.x] = hist[t * HTOT + threadIdx.x * NCHK + c];
    __syncthreads();
    const int* srcp = edges + (t * 2 + 0) * N_EDGES;
    const int* dstp = edges + (t * 2 + 1) * N_EDGES;
    int2* be = bedge + (size_t)t * N_EDGES;
    int e0 = c * CHK, e1 = min(e0 + CHK, N_EDGES);
    for (int i = e0 + threadIdx.x; i < e1; i += 256) {
        int d = dstp[i], s = srcp[i];
        int pos = atomicAdd(&cur[d >> BSH], 1);
        be[pos] = make_int2(s, d);
    }
}

__global__ __launch_bounds__(512) void k_bfinal(const int* __restrict__ hist,
                                                const int2* __restrict__ bedge,
                                                int* __restrict__ deg, int* __restrict__ rowptr,
                                                int* __restrict__ csr_src) {
    int t = blockIdx.y, b = blockIdx.x;
    int n0 = b << BSH;
    int nn = min(512, N_NODES - n0);
    __shared__ int degl[512], curl[512], ws[8];
    degl[threadIdx.x] = 0;
    __syncthreads();
    int base = hist[t * HTOT + b * NCHK];
    int end  = (b == NBKT - 1) ? N_EDGES : hist[t * HTOT + (b + 1) * NCHK];
    const int2* be = bedge + (size_t)t * N_EDGES;
    for (int e = base + threadIdx.x; e < end; e += 512)
        atomicAdd(&degl[be[e].y - n0], 1);
    __syncthreads();
    int v = degl[threadIdx.x];
    int lane = threadIdx.x & 63, wid = threadIdx.x >> 6;
    int sc = v;
#pragma unroll
    for (int o = 1; o < 64; o <<= 1) { int u = __shfl_up(sc, o); if (lane >= o) sc += u; }
    if (lane == 63) ws[wid] = sc;
    __syncthreads();
    if (wid == 0 && lane < 8) {
        int wv = ws[lane];
#pragma unroll
        for (int o = 1; o < 8; o <<= 1) { int u = __shfl_up(wv, o); if (lane >= o) wv += u; }
        ws[lane] = wv;
    }
    __syncthreads();
    int excl = ((wid == 0) ? 0 : ws[wid - 1]) + sc - v;
    if (threadIdx.x < nn) {
        rowptr[t * N_NODES + n0 + threadIdx.x] = base + excl;
        deg[t * N_NODES + n0 + threadIdx.x] = v;
    }
    curl[threadIdx.x] = base + excl;
    __syncthreads();
    for (int e = base + threadIdx.x; e < end; e += 512) {
        int2 ed = be[e];
        int pos = atomicAdd(&curl[ed.y - n0], 1);
        csr_src[t * N_EDGES + pos] = ed.x;
    }
}

// ---- fused layer-1 softmax+gather, single pass, batched-p structure:
//      phase A: 64 lanes compute p for 64 distinct edges (no redundancy);
//      phase B: 8 sub-iters broadcast (p,s) via shfl, uint4 gather + 8 FMA.
__global__ __launch_bounds__(256) void k_sg1(
    const __hip_bfloat16* __restrict__ feat1, const float* __restrict__ el1,
    const float* __restrict__ er1, const int* __restrict__ rowptr,
    const int* __restrict__ deg, const int* __restrict__ cs_all,
    float* __restrict__ h1) {
    __shared__ float xfer[4][HID_F];
    int t = blockIdx.y;
    int w = threadIdx.x >> 6;
    int n = blockIdx.x * 4 + w;
    int lane = threadIdx.x & 63;
    int beg = rowptr[t * N_NODES + n], cnt = deg[t * N_NODES + n];
    int g = lane >> 3, i = lane & 7;
    if (cnt > 0) {  // wave-uniform condition
        const int* cs = cs_all + t * N_EDGES + beg;
        const float* el = el1 + t * N_NODES;
        float ern = er1[t * N_NODES + n];
        const unsigned short* ft = (const unsigned short*)feat1 + (size_t)t * N_NODES * HID_F;
        float acc[8];
#pragma unroll
        for (int j = 0; j < 8; j++) acc[j] = 0.f;
        float sacc = 0.f;
        for (int c0 = 0; c0 < cnt; c0 += 64) {
            // phase A: p for edges c0+lane (all 64 lanes, distinct edges)
            bool pv = (c0 + lane) < cnt;
            int ps = __builtin_nontemporal_load(cs + (pv ? c0 + lane : 0));
            float preg = pv ? __expf(lrelu(el[ps] + ern)) : 0.f;
            sacc += preg;
            // phase B: 8 edges per sub-iter; (p,s) broadcast from owning lane
            int nsub = min(64, cnt - c0);
            for (int sub = 0; sub < nsub; sub += 8) {
                int idx = sub + g;
                float p = __shfl(preg, idx);  // 0 for idx >= nsub
                int s = __shfl(ps, idx);
                uint4 u = *(const uint4*)(ft + (size_t)s * HID_F + i * 8);
                acc[0] += p * bflo(u.x);
                acc[1] += p * bfhi(u.x);
                acc[2] += p * bflo(u.y);
                acc[3] += p * bfhi(u.y);
                acc[4] += p * bflo(u.z);
                acc[5] += p * bfhi(u.z);
                acc[6] += p * bflo(u.w);
                acc[7] += p * bfhi(u.w);
            }
        }
        sacc = wred_sum(sacc);  // full 64-lane sum of p
#pragma unroll
        for (int o = 8; o < 64; o <<= 1) {
#pragma unroll
            for (int j = 0; j < 8; j++) acc[j] += __shfl_xor(acc[j], o);
        }
        if (g == 0) {
            float inv = 0.25f / sacc;
#pragma unroll
            for (int j = 0; j < 8; j++) xfer[w][i * 8 + j] = acc[j] * inv;
        }
    }
    __syncthreads();
    if (cnt > 0) atomicAdd(&h1[n * HID_F + lane], xfer[w][lane]);
}

// ---- layer-2 featurization: packed row2[t][n] = float4(f0,f1,f2,el); er2 separate
__global__ __launch_bounds__(256) void k_feat2(
    const float* __restrict__ h1, const float* __restrict__ W2,
    const float* __restrict__ al2, const float* __restrict__ ar2,
    float4* __restrict__ row2, float* __restrict__ er2) {
    __shared__ float Wl[T_G * HID_F * OUT_F];
    __shared__ float Al[T_G * OUT_F], Ar[T_G * OUT_F];
    for (int i = threadIdx.x; i < T_G * HID_F * OUT_F; i += 256) Wl[i] = W2[i];
    if (threadIdx.x < T_G * OUT_F) { Al[threadIdx.x] = al2[threadIdx.x]; Ar[threadIdx.x] = ar2[threadIdx.x]; }
    __syncthreads();
    int n = blockIdx.x * 256 + threadIdx.x;
    if (n >= N_NODES) return;
    float h[HID_F];
    const float4* hp = (const float4*)(h1 + n * HID_F);
#pragma unroll
    for (int i = 0; i < 16; i++) {
        float4 v = hp[i];
        h[4 * i] = v.x; h[4 * i + 1] = v.y; h[4 * i + 2] = v.z; h[4 * i + 3] = v.w;
    }
    for (int t = 0; t < T_G; t++) {
        float f0 = 0.f, f1 = 0.f, f2 = 0.f;
#pragma unroll
        for (int k = 0; k < HID_F; k++) {
            float hv = h[k];
            f0 += hv * Wl[(t * HID_F + k) * 3 + 0];
            f1 += hv * Wl[(t * HID_F + k) * 3 + 1];
            f2 += hv * Wl[(t * HID_F + k) * 3 + 2];
        }
        float el = f0 * Al[t * 3] + f1 * Al[t * 3 + 1] + f2 * Al[t * 3 + 2];
        row2[t * N_NODES + n] = make_float4(f0, f1, f2, el);
        er2[t * N_NODES + n] = f0 * Ar[t * 3] + f1 * Ar[t * 3 + 1] + f2 * Ar[t * 3 + 2];
    }
}

// ---- fused d=3 aggregation (max-free): 4 nodes per wave, 16 lanes per node,
//      2x-unrolled edge loop, intra-group butterfly, atomicAdd into pre-biased hout
__global__ __launch_bounds__(256) void k_gat3f(
    const float4* __restrict__ row, const float* __restrict__ er_,
    const int* __restrict__ rowptr, const int* __restrict__ deg, const int* __restrict__ csr_src,
    const float* __restrict__ wv, float* __restrict__ hout) {
    int t = blockIdx.y;
    int lane = threadIdx.x & 63;
    int w = threadIdx.x >> 6;
    int nq = lane >> 4, e = lane & 15;
    int n = blockIdx.x * 16 + w * 4 + nq;  // 3125*16 == 50000 exact
    int beg = rowptr[t * N_NODES + n], cnt = deg[t * N_NODES + n];
    if (cnt == 0) return;  // group-uniform (16-lane groups share n)
    float erh = er_[t * N_NODES + n];
    const int* cs = csr_src + t * N_EDGES;
    const float4* rt = row + t * N_NODES;
    float s_run = 0.f, a0 = 0.f, a1 = 0.f, a2 = 0.f;
    for (int idx = e; idx < cnt; idx += 32) {
        int i1 = idx + 16;
        bool v1 = i1 < cnt;
        int s0 = __builtin_nontemporal_load(cs + beg + idx);
        int s1 = __builtin_nontemporal_load(cs + beg + (v1 ? i1 : idx));
        float4 r0 = rt[s0];
        float4 r1 = rt[s1];
        float p0 = __expf(lrelu(r0.w + erh));
        float p1 = v1 ? __expf(lrelu(r1.w + erh)) : 0.f;
        a0 += p0 * r0.x + p1 * r1.x;
        a1 += p0 * r0.y + p1 * r1.y;
        a2 += p0 * r0.z + p1 * r1.z;
        s_run += p0 + p1;
    }
#pragma unroll
    for (int o = 1; o < 16; o <<= 1) {  // xor<16 stays within the 16-lane group
        a0 += __shfl_xor(a0, o);
        a1 += __shfl_xor(a1, o);
        a2 += __shfl_xor(a2, o);
        s_run += __shfl_xor(s_run, o);
    }
    if (e < 3) {
        float v = (e == 0) ? a0 : (e == 1) ? a1 : a2;
        atomicAdd(&hout[n * 3 + e], wv[t] * v / s_run);
    }
}

// ---- layer-3 featurization (3->3): packed row3 + er3
__global__ void k_feat3(const float* __restrict__ h2, const float* __restrict__ W3,
                        const float* __restrict__ al3, const float* __restrict__ ar3,
                        float4* __restrict__ row3, float* __restrict__ er3) {
    int n = blockIdx.x * 256 + threadIdx.x;
    if (n >= N_NODES) return;
    float h0 = h2[n * 3], h1v = h2[n * 3 + 1], h2v = h2[n * 3 + 2];
    for (int t = 0; t < T_G; t++) {
        float f[3], el = 0.f, er = 0.f;
#pragma unroll
        for (int d = 0; d < 3; d++) {
            f[d] = h0 * W3[(t * 3 + 0) * 3 + d] + h1v * W3[(t * 3 + 1) * 3 + d] + h2v * W3[(t * 3 + 2) * 3 + d];
            el += f[d] * al3[t * 3 + d];
            er += f[d] * ar3[t * 3 + d];
        }
        row3[t * N_NODES + n] = make_float4(f[0], f[1], f[2], el);
        er3[t * N_NODES + n] = er;
    }
}

// ---- layer-M featurization: rowM[t][n][32] bf16 with [h*4+{0,1,2}]=f, [h*4+3]=el; erM f32
__global__ void k_featM(const float* __restrict__ h3, const float* __restrict__ WM,
                        const float* __restrict__ alM, const float* __restrict__ arM,
                        __hip_bfloat16* __restrict__ rowM, float* __restrict__ erM) {
    int n = blockIdx.x * 256 + threadIdx.x;
    if (n >= N_NODES) return;
    float h0 = h3[n * 3], h1v = h3[n * 3 + 1], h2v = h3[n * 3 + 2];
    for (int t = 0; t < T_G; t++) {
        int nb = t * N_NODES + n;
        size_t rb = (size_t)nb * 32;
#pragma unroll
        for (int hh = 0; hh < H_M; hh++) {
            float el = 0.f, er = 0.f;
#pragma unroll
            for (int d = 0; d < 3; d++) {
                int j = hh * 3 + d;
                float f = h0 * WM[(t * 3 + 0) * 24 + j] + h1v * WM[(t * 3 + 1) * 24 + j] + h2v * WM[(t * 3 + 2) * 24 + j];
                rowM[rb + hh * 4 + d] = __float2bfloat16(f);
                el += f * alM[(t * H_M + hh) * 3 + d];
                er += f * arM[(t * H_M + hh) * 3 + d];
            }
            rowM[rb + hh * 4 + 3] = __float2bfloat16(el);
            erM[nb * 8 + hh] = er;
        }
    }
}

// ---- fused layer-M aggregation (max-free): lane=(eo,h), 2x-unrolled (16 edges/iter),
//      one 8B gather per edge-lane, plain butterfly sums over eo
__global__ __launch_bounds__(256) void k_aggMf(
    const __hip_bfloat16* __restrict__ rowM, const float* __restrict__ erM,
    const int* __restrict__ rowptr, const int* __restrict__ deg, const int* __restrict__ csr_src,
    const float* __restrict__ wv, float* __restrict__ hM) {
    int t = blockIdx.y;
    int n = blockIdx.x * 4 + (threadIdx.x >> 6);
    int lane = threadIdx.x & 63;
    int h = lane & 7, eo = lane >> 3;
    int beg = rowptr[t * N_NODES + n], cnt = deg[t * N_NODES + n];
    if (cnt == 0) return;
    float erh = erM[(t * N_NODES + n) * 8 + h];
    const int* cs = csr_src + t * N_EDGES;
    const unsigned short* rt = (const unsigned short*)rowM + (size_t)t * N_NODES * 32;
    float s_run = 0.f, a0 = 0.f, a1 = 0.f, a2 = 0.f;
    for (int idx = eo; idx < cnt; idx += 16) {
        int i1 = idx + 8;
        bool v1 = i1 < cnt;
        int s0 = __builtin_nontemporal_load(cs + beg + idx);
        int s1 = __builtin_nontemporal_load(cs + beg + (v1 ? i1 : idx));
        ushort4 u0 = *(const ushort4*)(rt + (size_t)s0 * 32 + h * 4);
        ushort4 u1 = *(const ushort4*)(rt + (size_t)s1 * 32 + h * 4);
        float p0 = __expf(lrelu(bf2f(u0.w) + erh));
        float p1 = v1 ? __expf(lrelu(bf2f(u1.w) + erh)) : 0.f;
        a0 += p0 * bf2f(u0.x) + p1 * bf2f(u1.x);
        a1 += p0 * bf2f(u0.y) + p1 * bf2f(u1.y);
        a2 += p0 * bf2f(u0.z) + p1 * bf2f(u1.z);
        s_run += p0 + p1;
    }
#pragma unroll
    for (int o = 8; o < 64; o <<= 1) {
        a0 += __shfl_xor(a0, o);
        a1 += __shfl_xor(a1, o);
        a2 += __shfl_xor(a2, o);
        s_run += __shfl_xor(s_run, o);
    }
    if (eo == 0) {
        float inv = wv[t] / s_run;
        atomicAdd(&hM[n * 24 + h * 3 + 0], inv * a0);
        atomicAdd(&hM[n * 24 + h * 3 + 1], inv * a1);
        atomicAdd(&hM[n * 24 + h * 3 + 2], inv * a2);
    }
}

// ---- delta norms per head + fused top-16-bit histogram
__global__ void k_norms(const float* __restrict__ hM, float* __restrict__ norms,
                        unsigned int* __restrict__ hist1) {
    int idx = blockIdx.x * 256 + threadIdx.x;
    if (idx >= N_NODES * H_M) return;
    int n = idx >> 3, hh = idx & 7;
    float s = 0.f;
#pragma unroll
    for (int d = 0; d < 3; d++) {
        float cur = hM[n * 24 + hh * 3 + d];
        float prev = (n > 0) ? hM[(n - 1) * 24 + hh * 3 + d] : 0.f;
        float dx = cur - prev;
        s += dx * dx;
    }
    float v = sqrtf(s);
    norms[hh * N_NODES + n] = v;
    unsigned int u = __float_as_uint(v);
    atomicAdd(&hist1[hh * 65536 + (u >> 16)], 1u);
}

__device__ __forceinline__ unsigned int blk_exscan(unsigned int v) {
    int lane = threadIdx.x & 63, wid = threadIdx.x >> 6;
    unsigned int sc = v;
#pragma unroll
    for (int o = 1; o < 64; o <<= 1) { unsigned int u = __shfl_up(sc, o); if (lane >= o) sc += u; }
    __shared__ unsigned int ws[4];
    if (lane == 63) ws[wid] = sc;
    __syncthreads();
    unsigned int woff = 0;
    for (int w = 0; w < wid; w++) woff += ws[w];
    __syncthreads();
    return woff + sc - v;
}

__global__ __launch_bounds__(256) void k_findbin(
    const unsigned int* __restrict__ hist1, int* __restrict__ selbin, int* __restrict__ resrank) {
    int hh = blockIdx.x >> 1, k = blockIdx.x & 1;
    unsigned int rank = N_NODES / 2 - 1 + k;  // 24999 / 25000
    const unsigned int* H = hist1 + hh * 65536;
    int tid = threadIdx.x;
    unsigned int local = 0;
    for (int j = 0; j < 256; j++) local += H[tid * 256 + j];
    unsigned int excl = blk_exscan(local);
    if (rank >= excl && rank < excl + local) {
        unsigned int cum = excl;
        for (int j = 0; j < 256; j++) {
            unsigned int c = H[tid * 256 + j];
            if (cum + c > rank) {
                selbin[hh * 2 + k] = tid * 256 + j;
                resrank[hh * 2 + k] = (int)(rank - cum);
                break;
            }
            cum += c;
        }
    }
}

__global__ void k_h2(const float* __restrict__ norms, const int* __restrict__ selbin,
                     unsigned int* __restrict__ hist2) {
    int idx = blockIdx.x * 256 + threadIdx.x;
    if (idx >= N_NODES * H_M) return;
    int hh = idx / N_NODES;
    unsigned int u = __float_as_uint(norms[idx]);
    int top = (int)(u >> 16);
#pragma unroll
    for (int k = 0; k < 2; k++)
        if (top == selbin[hh * 2 + k])
            atomicAdd(&hist2[(hh * 2 + k) * 65536 + (u & 0xFFFFu)], 1u);
}

__global__ __launch_bounds__(256) void k_findval(
    const unsigned int* __restrict__ hist2, const int* __restrict__ selbin,
    const int* __restrict__ resrank, float* __restrict__ medpair) {
    int hh = blockIdx.x >> 1, k = blockIdx.x & 1;
    unsigned int rank = (unsigned int)resrank[hh * 2 + k];
    const unsigned int* H = hist2 + (hh * 2 + k) * 65536;
    int tid = threadIdx.x;
    unsigned int local = 0;
    for (int j = 0; j < 256; j++) local += H[tid * 256 + j];
    unsigned int excl = blk_exscan(local);
    if (rank >= excl && rank < excl + local) {
        unsigned int cum = excl;
        for (int j = 0; j < 256; j++) {
            unsigned int c = H[tid * 256 + j];
            if (cum + c > rank) {
                unsigned int u = ((unsigned int)selbin[hh * 2 + k] << 16) | (unsigned int)(tid * 256 + j);
                medpair[hh * 2 + k] = __uint_as_float(u);
                break;
            }
            cum += c;
        }
    }
}

__global__ void k_final(const float* __restrict__ hM, const float* __restrict__ medpair,
                        const float* __restrict__ noise, float* __restrict__ out) {
    int idx = blockIdx.x * 256 + threadIdx.x;
    if (idx >= N_NODES * 24) return;
    int hh = (idx / 3) & 7;
    float med = 0.5f * (medpair[hh * 2] + medpair[hh * 2 + 1]) + 1e-4f;
    float v = hM[idx] / med;
    if (isnan(v)) v = 0.f;
    else if (isinf(v)) v = v > 0.f ? 100.f : -100.f;
    out[idx] = v + 0.3f * noise[idx];
}

extern "C" void kernel_launch(void* const* d_in, const int* in_sizes, int n_in,
                              void* d_out, int out_size, void* d_ws, size_t ws_size,
                              hipStream_t stream) {
    const float* x     = (const float*)d_in[0];
    const int*   edges = (const int*)d_in[1];
    const float* noise = (const float*)d_in[2];
    const float* W1  = (const float*)d_in[3];
    const float* al1 = (const float*)d_in[4];
    const float* ar1 = (const float*)d_in[5];
    const float* b1  = (const float*)d_in[6];
    const float* W2  = (const float*)d_in[7];
    const float* al2 = (const float*)d_in[8];
    const float* ar2 = (const float*)d_in[9];
    const float* b2  = (const float*)d_in[10];
    const float* W3  = (const float*)d_in[11];
    const float* al3 = (const float*)d_in[12];
    const float* ar3 = (const float*)d_in[13];
    const float* b3  = (const float*)d_in[14];
    const float* WM  = (const float*)d_in[15];
    const float* alM = (const float*)d_in[16];
    const float* arM = (const float*)d_in[17];
    const float* bM  = (const float*)d_in[18];
    const float* fc2 = (const float*)d_in[19];
    const float* fc3 = (const float*)d_in[20];
    float* out = (float*)d_out;

    char* basep = (char*)d_ws;
    size_t off = 0;
    auto alloc = [&](size_t bytes) -> void* {
        void* p = basep + off;
        off += (bytes + 255) & ~(size_t)255;
        return p;
    };
    // Region A: feat1 bf16 (25.6 MB); rowM (12.8) + erM (6.4) alias it after k_sg1
    char* regA = (char*)alloc((size_t)T_G * N_NODES * HID_F * 2);
    __hip_bfloat16* feat1 = (__hip_bfloat16*)regA;
    __hip_bfloat16* rowM  = (__hip_bfloat16*)regA;                 // T*N*32 bf16 = 12.8MB
    float*          erM   = (float*)(regA + 12800000);             // T*N*8 f32 = 6.4MB
    // Region U (25.6MB): bedge (int2, CSR build only)
    char* regU = (char*)alloc((size_t)T_G * N_EDGES * 8);
    int2*  bedge = (int2*)regU;
    float* el1 = (float*)alloc((size_t)T_G * N_NODES * 4);
    float* er1 = (float*)alloc((size_t)T_G * N_NODES * 4);
    float* h1  = (float*)alloc((size_t)N_NODES * HID_F * 4);
    float4* row2 = (float4*)alloc((size_t)T_G * N_NODES * 16);
    float* er2 = (float*)alloc((size_t)T_G * N_NODES * 4);
    float* h2  = (float*)alloc((size_t)N_NODES * 3 * 4);
    float4* row3 = (float4*)alloc((size_t)T_G * N_NODES * 16);
    float* er3 = (float*)alloc((size_t)T_G * N_NODES * 4);
    float* h3  = (float*)alloc((size_t)N_NODES * 3 * 4);
    float* hM  = (float*)alloc((size_t)N_NODES * 24 * 4);
    float* norms = (float*)alloc((size_t)H_M * N_NODES * 4);
    float* medpair = (float*)alloc(64);
    float* wbuf = (float*)alloc(512);
    int* deg    = (int*)alloc((size_t)T_G * N_NODES * 4);
    int* rowptr = (int*)alloc((size_t)T_G * N_NODES * 4);
    int* hist   = (int*)alloc((size_t)T_G * HTOT * 4);       // 307KB
    int* csr_src = (int*)alloc((size_t)T_G * N_EDGES * 4);
    unsigned int* hist1 = (unsigned int*)alloc((size_t)H_M * 65536 * 4);
    unsigned int* hist2 = (unsigned int*)alloc((size_t)H_M * 2 * 65536 * 4);
    int* selbin  = (int*)alloc(64);
    int* resrank = (int*)alloc(64);

    const int NB = (N_NODES + 255) / 256;   // 196
    const int NW = (N_NODES + 3) / 4;       // 12500
    const int NG = N_NODES / 16;            // 3125 (16 nodes per block)
    const int NE8 = (N_NODES * H_M + 255) / 256;

    hipMemsetAsync(hist1, 0, (size_t)H_M * 65536 * 4, stream);
    hipMemsetAsync(hist2, 0, (size_t)H_M * 2 * 65536 * 4, stream);

    k_wvec<<<1, 128, 0, stream>>>(fc2, fc3, b1, b2, b3, bM, wbuf);
    k_init_all<<<(N_NODES * HID_F + 255) / 256, 256, 0, stream>>>(wbuf, h1, h2, h3, hM);

    // Bucketed CSR build (no global atomics)
    k_bcount<<<dim3(NCHK, T_G), 256, 0, stream>>>(edges, hist);
    k_bscan<<<T_G, 1024, 0, stream>>>(hist);
    k_bscatter<<<dim3(NCHK, T_G), 256, 0, stream>>>(edges, hist, bedge);
    k_bfinal<<<dim3(NBKT, T_G), 512, 0, stream>>>(hist, bedge, deg, rowptr, csr_src);

    // Layer 1 (MFMA GEMM + batched-p fused softmax/gather)
    k_gemm1<<<dim3(N_NODES / 16, T_G), 256, 0, stream>>>(x, W1, al1, ar1, feat1, el1, er1);
    k_sg1<<<dim3(NW, T_G), 256, 0, stream>>>(feat1, el1, er1, rowptr, deg, csr_src, h1);

    // Layer 2 (fused softmax+gather, 4 nodes/wave)
    k_feat2<<<NB, 256, 0, stream>>>(h1, W2, al2, ar2, row2, er2);
    k_gat3f<<<dim3(NG, T_G), 256, 0, stream>>>(row2, er2, rowptr, deg, csr_src, wbuf + 0, h2);

    // Layer 3 (fused)
    k_feat3<<<NB, 256, 0, stream>>>(h2, W3, al3, ar3, row3, er3);
    k_gat3f<<<dim3(NG, T_G), 256, 0, stream>>>(row3, er3, rowptr, deg, csr_src, wbuf + 4, h3);

    // Layer M (fused; rowM/erM alias feat1 region — feat1 dead after k_sg1)
    k_featM<<<NB, 256, 0, stream>>>(h3, WM, alM, arM, rowM, erM);
    k_aggMf<<<dim3(NW, T_G), 256, 0, stream>>>(rowM, erM, rowptr, deg, csr_src, wbuf + 4, hM);

    // norm_ (telescoped): parallel exact median via 2-level histogram select
    k_norms<<<NE8, 256, 0, stream>>>(hM, norms, hist1);
    k_findbin<<<16, 256, 0, stream>>>(hist1, selbin, resrank);
    k_h2<<<NE8, 256, 0, stream>>>(norms, selbin, hist2);
    k_findval<<<16, 256, 0, stream>>>(hist2, selbin, resrank, medpair);
    k_final<<<(N_NODES * 24 + 255) / 256, 256, 0, stream>>>(hM, medpair, noise, out);
}

// Round 18
// 588.225 us; speedup vs baseline: 1.0743x; 1.0743x over previous
//
#include <hip/hip_runtime.h>
#include <hip/hip_bf16.h>
#include <math.h>

#define N_NODES 50000
#define N_EDGES 800000
#define T_G 4
#define IN_F 128
#define HID_F 64
#define OUT_F 3
#define H_M 8

// bucketed CSR build params
#define BSH 9
#define NBKT 98            // ceil(50000 / 512)
#define CHK 4096
#define NCHK 196           // ceil(800000 / 4096)
#define HTOT (NBKT * NCHK) // 19208

typedef short bf16x8 __attribute__((ext_vector_type(8)));
typedef float f32x4 __attribute__((ext_vector_type(4)));

__device__ __forceinline__ float lrelu(float v) { return v > 0.f ? v : 0.2f * v; }

__device__ __forceinline__ float wred_sum(float v) {
#pragma unroll
    for (int o = 32; o; o >>= 1) v += __shfl_xor(v, o);
    return v;
}
__device__ __forceinline__ float bf2f(unsigned int u) {
    return __uint_as_float(u << 16);
}
__device__ __forceinline__ float bflo(unsigned int u) {  // low bf16 of packed pair (1 op)
    return __uint_as_float(u << 16);
}
__device__ __forceinline__ float bfhi(unsigned int u) {  // high bf16 of packed pair (1 op)
    return __uint_as_float(u & 0xFFFF0000u);
}
__device__ __forceinline__ short f2bf(float f) {  // RNE f32->bf16 bits
    unsigned u = __float_as_uint(f);
    u += 0x7FFF + ((u >> 16) & 1);
    return (short)(u >> 16);
}

// ---- weight/bias precompute:
// w[0:4]=w2, [4:8]=w3, [8:11]=cb2, [11:14]=cb3, [16:40]=cbM, [64:128]=bavg1
__global__ void k_wvec(const float* __restrict__ fc2, const float* __restrict__ fc3,
                       const float* __restrict__ b1, const float* __restrict__ b2,
                       const float* __restrict__ b3, const float* __restrict__ bM,
                       float* __restrict__ w) {
    __shared__ float w2[4], w3[4];
    int i = threadIdx.x;
    if (i < 4) {
        float a = 0.f, b = 0.f;
        for (int r = 0; r < T_G; r++) { a += fc2[r * T_G + i]; b += fc3[r * T_G + i]; }
        w2[i] = 0.25f * a; w3[i] = 0.25f * b;
        w[i] = w2[i]; w[4 + i] = w3[i];
    }
    __syncthreads();
    if (i < 3) {
        float c = 0.f;
        for (int t = 0; t < T_G; t++) c += w2[t] * b2[t * 3 + i];
        w[8 + i] = c;
    }
    if (i >= 8 && i < 11) {
        int d = i - 8;
        float c = 0.f;
        for (int t = 0; t < T_G; t++) c += w3[t] * b3[t * 3 + d];
        w[11 + d] = c;
    }
    if (i >= 16 && i < 40) {
        int j = i - 16;
        float c = 0.f;
        for (int t = 0; t < T_G; t++) c += w3[t] * bM[t * 24 + j];
        w[16 + j] = c;
    }
    if (i >= 64 && i < 128) {
        int c = i - 64;
        w[i] = 0.25f * (b1[c] + b1[HID_F + c] + b1[2 * HID_F + c] + b1[3 * HID_F + c]);
    }
}

// ---- one-shot init of all pre-biased accumulators
__global__ void k_init_all(const float* __restrict__ w, float* __restrict__ h1,
                           float* __restrict__ h2, float* __restrict__ h3,
                           float* __restrict__ hM) {
    int i = blockIdx.x * 256 + threadIdx.x;
    if (i < N_NODES * HID_F) h1[i] = w[64 + (i & 63)];
    if (i < N_NODES * 3) { h2[i] = w[8 + i % 3]; h3[i] = w[11 + i % 3]; }
    if (i < N_NODES * 24) hM[i] = w[16 + i % 24];
}

// ---- layer-1 GEMM via MFMA: block = 16 nodes x 64 cols x one t; wave = 16-col tile
__global__ __launch_bounds__(256) void k_gemm1(
    const float* __restrict__ x, const float* __restrict__ W1,
    const float* __restrict__ al1, const float* __restrict__ ar1,
    __hip_bfloat16* __restrict__ feat1, float* __restrict__ el1, float* __restrict__ er1) {
    __shared__ float tile[16][HID_F];
    int t = blockIdx.y;
    int base = blockIdx.x * 16;
    int w = threadIdx.x >> 6, lane = threadIdx.x & 63;
    int lr = lane & 15, lk = lane >> 4;
    const float* xrow = x + (size_t)(base + lr) * IN_F;
    const float* Wt = W1 + (size_t)t * IN_F * HID_F;
    f32x4 acc = {0.f, 0.f, 0.f, 0.f};
#pragma unroll
    for (int ks = 0; ks < 4; ks++) {
        int k0 = ks * 32 + lk * 8;
        const float4* xp = (const float4*)(xrow + k0);
        float4 v0 = xp[0], v1 = xp[1];
        bf16x8 a, b;
        a[0] = f2bf(v0.x); a[1] = f2bf(v0.y); a[2] = f2bf(v0.z); a[3] = f2bf(v0.w);
        a[4] = f2bf(v1.x); a[5] = f2bf(v1.y); a[6] = f2bf(v1.z); a[7] = f2bf(v1.w);
#pragma unroll
        for (int j = 0; j < 8; j++) b[j] = f2bf(Wt[(k0 + j) * HID_F + w * 16 + lr]);
        acc = __builtin_amdgcn_mfma_f32_16x16x32_bf16(a, b, acc, 0, 0, 0);
    }
#pragma unroll
    for (int r = 0; r < 4; r++) tile[lk * 4 + r][w * 16 + lr] = acc[r];
    __syncthreads();
#pragma unroll
    for (int q = 0; q < 4; q++) {
        int e = q * 256 + threadIdx.x;
        int node = e >> 6, c = e & 63;
        feat1[((size_t)t * N_NODES + base + node) * HID_F + c] = __float2bfloat16(tile[node][c]);
    }
    float alv = al1[t * HID_F + lane], arv = ar1[t * HID_F + lane];
#pragma unroll
    for (int q = 0; q < 4; q++) {
        int node = w * 4 + q;
        float f = tile[node][lane];
        float vl = wred_sum(f * alv);
        float vr = wred_sum(f * arv);
        if (lane == 0) {
            el1[t * N_NODES + base + node] = vl;
            er1[t * N_NODES + base + node] = vr;
        }
    }
}

// ==== bucketed CSR build (no global atomics, no random HBM RMW) ====

__global__ __launch_bounds__(256) void k_bcount(const int* __restrict__ edges,
                                                int* __restrict__ hist) {
    int t = blockIdx.y, c = blockIdx.x;
    __shared__ int hl[NBKT];
    if (threadIdx.x < NBKT) hl[threadIdx.x] = 0;
    __syncthreads();
    const int* dst = edges + (t * 2 + 1) * N_EDGES;
    int e0 = c * CHK, e1 = min(e0 + CHK, N_EDGES);
    for (int i = e0 + threadIdx.x; i < e1; i += 256)
        atomicAdd(&hl[dst[i] >> BSH], 1);
    __syncthreads();
    if (threadIdx.x < NBKT) hist[t * HTOT + threadIdx.x * NCHK + c] = hl[threadIdx.x];
}

__global__ __launch_bounds__(1024) void k_bscan(int* __restrict__ hist) {
    int t = blockIdx.x;
    int* H = hist + t * HTOT;
    __shared__ int ws[16];
    __shared__ int carry;
    if (threadIdx.x == 0) carry = 0;
    __syncthreads();
    int lane = threadIdx.x & 63, wid = threadIdx.x >> 6;
    for (int base = 0; base < HTOT; base += 1024) {
        int i = base + threadIdx.x;
        int v = (i < HTOT) ? H[i] : 0;
        int sc = v;
#pragma unroll
        for (int o = 1; o < 64; o <<= 1) { int u = __shfl_up(sc, o); if (lane >= o) sc += u; }
        if (lane == 63) ws[wid] = sc;
        __syncthreads();
        if (wid == 0 && lane < 16) {
            int wv = ws[lane];
#pragma unroll
            for (int o = 1; o < 16; o <<= 1) { int u = __shfl_up(wv, o); if (lane >= o) wv += u; }
            ws[lane] = wv;
        }
        __syncthreads();
        int woff = (wid == 0) ? 0 : ws[wid - 1];
        if (i < HTOT) H[i] = carry + woff + sc - v;  // exclusive
        int tot = ws[15];
        __syncthreads();
        if (threadIdx.x == 0) carry += tot;
        __syncthreads();
    }
}

__global__ __launch_bounds__(256) void k_bscatter(const int* __restrict__ edges,
                                                  const int* __restrict__ hist,
                                                  int2* __restrict__ bedge) {
    int t = blockIdx.y, c = blockIdx.x;
    __shared__ int cur[NBKT];
    if (threadIdx.x < NBKT) cur[threadIdx.x] = hist[t * HTOT + threadIdx.x * NCHK + c];
    __syncthreads();
    const int* srcp = edges + (t * 2 + 0) * N_EDGES;
    const int* dstp = edges + (t * 2 + 1) * N_EDGES;
    int2* be = bedge + (size_t)t * N_EDGES;
    int e0 = c * CHK, e1 = min(e0 + CHK, N_EDGES);
    for (int i = e0 + threadIdx.x; i < e1; i += 256) {
        int d = dstp[i], s = srcp[i];
        int pos = atomicAdd(&cur[d >> BSH], 1);
        be[pos] = make_int2(s, d);
    }
}

__global__ __launch_bounds__(512) void k_bfinal(const int* __restrict__ hist,
                                                const int2* __restrict__ bedge,
                                                int* __restrict__ deg, int* __restrict__ rowptr,
                                                int* __restrict__ csr_src) {
    int t = blockIdx.y, b = blockIdx.x;
    int n0 = b << BSH;
    int nn = min(512, N_NODES - n0);
    __shared__ int degl[512], curl[512], ws[8];
    degl[threadIdx.x] = 0;
    __syncthreads();
    int base = hist[t * HTOT + b * NCHK];
    int end  = (b == NBKT - 1) ? N_EDGES : hist[t * HTOT + (b + 1) * NCHK];
    const int2* be = bedge + (size_t)t * N_EDGES;
    for (int e = base + threadIdx.x; e < end; e += 512)
        atomicAdd(&degl[be[e].y - n0], 1);
    __syncthreads();
    int v = degl[threadIdx.x];
    int lane = threadIdx.x & 63, wid = threadIdx.x >> 6;
    int sc = v;
#pragma unroll
    for (int o = 1; o < 64; o <<= 1) { int u = __shfl_up(sc, o); if (lane >= o) sc += u; }
    if (lane == 63) ws[wid] = sc;
    __syncthreads();
    if (wid == 0 && lane < 8) {
        int wv = ws[lane];
#pragma unroll
        for (int o = 1; o < 8; o <<= 1) { int u = __shfl_up(wv, o); if (lane >= o) wv += u; }
        ws[lane] = wv;
    }
    __syncthreads();
    int excl = ((wid == 0) ? 0 : ws[wid - 1]) + sc - v;
    if (threadIdx.x < nn) {
        rowptr[t * N_NODES + n0 + threadIdx.x] = base + excl;
        deg[t * N_NODES + n0 + threadIdx.x] = v;
    }
    curl[threadIdx.x] = base + excl;
    __syncthreads();
    for (int e = base + threadIdx.x; e < end; e += 512) {
        int2 ed = be[e];
        int pos = atomicAdd(&curl[ed.y - n0], 1);
        csr_src[t * N_EDGES + pos] = ed.x;
    }
}

// ---- fused layer-1 softmax+gather, single pass, 4x-unrolled edge loop (ILP):
//      lane=(edge-group g in [0,8), octant i); 32 edges in flight per wave
__global__ __launch_bounds__(256) void k_sg1(
    const __hip_bfloat16* __restrict__ feat1, const float* __restrict__ el1,
    const float* __restrict__ er1, const int* __restrict__ rowptr,
    const int* __restrict__ deg, const int* __restrict__ cs_all,
    float* __restrict__ h1) {
    __shared__ float xfer[4][HID_F];
    int t = blockIdx.y;
    int w = threadIdx.x >> 6;
    int n = blockIdx.x * 4 + w;
    int lane = threadIdx.x & 63;
    int beg = rowptr[t * N_NODES + n], cnt = deg[t * N_NODES + n];
    int g = lane >> 3, i = lane & 7;
    if (cnt > 0) {  // wave-uniform condition
        const int* cs = cs_all + t * N_EDGES + beg;
        const float* el = el1 + t * N_NODES;
        float ern = er1[t * N_NODES + n];
        const unsigned short* ft = (const unsigned short*)feat1 + (size_t)t * N_NODES * HID_F;
        float acc[8];
#pragma unroll
        for (int j = 0; j < 8; j++) acc[j] = 0.f;
        float sacc = 0.f;
        for (int c0 = 0; c0 < cnt; c0 += 32) {
            int e0 = c0 + g, e1 = c0 + 8 + g, e2 = c0 + 16 + g, e3 = c0 + 24 + g;
            bool v0 = e0 < cnt, v1 = e1 < cnt, v2 = e2 < cnt, v3 = e3 < cnt;
            int s0 = cs[v0 ? e0 : 0];
            int s1 = cs[v1 ? e1 : 0];
            int s2 = cs[v2 ? e2 : 0];
            int s3 = cs[v3 ? e3 : 0];
            float p0 = v0 ? __expf(lrelu(el[s0] + ern)) : 0.f;
            float p1 = v1 ? __expf(lrelu(el[s1] + ern)) : 0.f;
            float p2 = v2 ? __expf(lrelu(el[s2] + ern)) : 0.f;
            float p3 = v3 ? __expf(lrelu(el[s3] + ern)) : 0.f;
            uint4 u0 = *(const uint4*)(ft + (size_t)s0 * HID_F + i * 8);
            uint4 u1 = *(const uint4*)(ft + (size_t)s1 * HID_F + i * 8);
            uint4 u2 = *(const uint4*)(ft + (size_t)s2 * HID_F + i * 8);
            uint4 u3 = *(const uint4*)(ft + (size_t)s3 * HID_F + i * 8);
            acc[0] += p0 * bflo(u0.x) + p1 * bflo(u1.x);
            acc[1] += p0 * bfhi(u0.x) + p1 * bfhi(u1.x);
            acc[2] += p0 * bflo(u0.y) + p1 * bflo(u1.y);
            acc[3] += p0 * bfhi(u0.y) + p1 * bfhi(u1.y);
            acc[4] += p0 * bflo(u0.z) + p1 * bflo(u1.z);
            acc[5] += p0 * bfhi(u0.z) + p1 * bfhi(u1.z);
            acc[6] += p0 * bflo(u0.w) + p1 * bflo(u1.w);
            acc[7] += p0 * bfhi(u0.w) + p1 * bfhi(u1.w);
            acc[0] += p2 * bflo(u2.x) + p3 * bflo(u3.x);
            acc[1] += p2 * bfhi(u2.x) + p3 * bfhi(u3.x);
            acc[2] += p2 * bflo(u2.y) + p3 * bflo(u3.y);
            acc[3] += p2 * bfhi(u2.y) + p3 * bfhi(u3.y);
            acc[4] += p2 * bflo(u2.z) + p3 * bflo(u3.z);
            acc[5] += p2 * bfhi(u2.z) + p3 * bfhi(u3.z);
            acc[6] += p2 * bflo(u2.w) + p3 * bflo(u3.w);
            acc[7] += p2 * bfhi(u2.w) + p3 * bfhi(u3.w);
            sacc += (p0 + p1) + (p2 + p3);
        }
#pragma unroll
        for (int o = 8; o < 64; o <<= 1) {
#pragma unroll
            for (int j = 0; j < 8; j++) acc[j] += __shfl_xor(acc[j], o);
            sacc += __shfl_xor(sacc, o);
        }
        if (g == 0) {
            float inv = 0.25f / sacc;
            // NOTE: acc[2j]/acc[2j+1] hold low/high bf16 halves; low half j maps to
            // column i*8+... wait: with bflo/bfhi both scaled the same, mapping is
            // identical to round 16: acc[0]=col0(lo of u.x), acc[1]=col1(hi of u.x), etc.
#pragma unroll
            for (int j = 0; j < 8; j++) xfer[w][i * 8 + j] = acc[j] * inv;
        }
    }
    __syncthreads();
    if (cnt > 0) atomicAdd(&h1[n * HID_F + lane], xfer[w][lane]);
}

// ---- layer-2 featurization: packed row2[t][n] = float4(f0,f1,f2,el); er2 separate
__global__ __launch_bounds__(256) void k_feat2(
    const float* __restrict__ h1, const float* __restrict__ W2,
    const float* __restrict__ al2, const float* __restrict__ ar2,
    float4* __restrict__ row2, float* __restrict__ er2) {
    __shared__ float Wl[T_G * HID_F * OUT_F];
    __shared__ float Al[T_G * OUT_F], Ar[T_G * OUT_F];
    for (int i = threadIdx.x; i < T_G * HID_F * OUT_F; i += 256) Wl[i] = W2[i];
    if (threadIdx.x < T_G * OUT_F) { Al[threadIdx.x] = al2[threadIdx.x]; Ar[threadIdx.x] = ar2[threadIdx.x]; }
    __syncthreads();
    int n = blockIdx.x * 256 + threadIdx.x;
    if (n >= N_NODES) return;
    float h[HID_F];
    const float4* hp = (const float4*)(h1 + n * HID_F);
#pragma unroll
    for (int i = 0; i < 16; i++) {
        float4 v = hp[i];
        h[4 * i] = v.x; h[4 * i + 1] = v.y; h[4 * i + 2] = v.z; h[4 * i + 3] = v.w;
    }
    for (int t = 0; t < T_G; t++) {
        float f0 = 0.f, f1 = 0.f, f2 = 0.f;
#pragma unroll
        for (int k = 0; k < HID_F; k++) {
            float hv = h[k];
            f0 += hv * Wl[(t * HID_F + k) * 3 + 0];
            f1 += hv * Wl[(t * HID_F + k) * 3 + 1];
            f2 += hv * Wl[(t * HID_F + k) * 3 + 2];
        }
        float el = f0 * Al[t * 3] + f1 * Al[t * 3 + 1] + f2 * Al[t * 3 + 2];
        row2[t * N_NODES + n] = make_float4(f0, f1, f2, el);
        er2[t * N_NODES + n] = f0 * Ar[t * 3] + f1 * Ar[t * 3 + 1] + f2 * Ar[t * 3 + 2];
    }
}

// ---- fused d=3 aggregation (max-free): 4 nodes per wave, 16 lanes per node,
//      2x-unrolled edge loop, intra-group butterfly, atomicAdd into pre-biased hout
__global__ __launch_bounds__(256) void k_gat3f(
    const float4* __restrict__ row, const float* __restrict__ er_,
    const int* __restrict__ rowptr, const int* __restrict__ deg, const int* __restrict__ csr_src,
    const float* __restrict__ wv, float* __restrict__ hout) {
    int t = blockIdx.y;
    int lane = threadIdx.x & 63;
    int w = threadIdx.x >> 6;
    int nq = lane >> 4, e = lane & 15;
    int n = blockIdx.x * 16 + w * 4 + nq;  // 3125*16 == 50000 exact
    int beg = rowptr[t * N_NODES + n], cnt = deg[t * N_NODES + n];
    if (cnt == 0) return;  // group-uniform (16-lane groups share n)
    float erh = er_[t * N_NODES + n];
    const int* cs = csr_src + t * N_EDGES;
    const float4* rt = row + t * N_NODES;
    float s_run = 0.f, a0 = 0.f, a1 = 0.f, a2 = 0.f;
    for (int idx = e; idx < cnt; idx += 32) {
        int i1 = idx + 16;
        bool v1 = i1 < cnt;
        int s0 = cs[beg + idx];
        int s1 = cs[beg + (v1 ? i1 : idx)];
        float4 r0 = rt[s0];
        float4 r1 = rt[s1];
        float p0 = __expf(lrelu(r0.w + erh));
        float p1 = v1 ? __expf(lrelu(r1.w + erh)) : 0.f;
        a0 += p0 * r0.x + p1 * r1.x;
        a1 += p0 * r0.y + p1 * r1.y;
        a2 += p0 * r0.z + p1 * r1.z;
        s_run += p0 + p1;
    }
#pragma unroll
    for (int o = 1; o < 16; o <<= 1) {  // xor<16 stays within the 16-lane group
        a0 += __shfl_xor(a0, o);
        a1 += __shfl_xor(a1, o);
        a2 += __shfl_xor(a2, o);
        s_run += __shfl_xor(s_run, o);
    }
    if (e < 3) {
        float v = (e == 0) ? a0 : (e == 1) ? a1 : a2;
        atomicAdd(&hout[n * 3 + e], wv[t] * v / s_run);
    }
}

// ---- layer-3 featurization (3->3): packed row3 + er3
__global__ void k_feat3(const float* __restrict__ h2, const float* __restrict__ W3,
                        const float* __restrict__ al3, const float* __restrict__ ar3,
                        float4* __restrict__ row3, float* __restrict__ er3) {
    int n = blockIdx.x * 256 + threadIdx.x;
    if (n >= N_NODES) return;
    float h0 = h2[n * 3], h1v = h2[n * 3 + 1], h2v = h2[n * 3 + 2];
    for (int t = 0; t < T_G; t++) {
        float f[3], el = 0.f, er = 0.f;
#pragma unroll
        for (int d = 0; d < 3; d++) {
            f[d] = h0 * W3[(t * 3 + 0) * 3 + d] + h1v * W3[(t * 3 + 1) * 3 + d] + h2v * W3[(t * 3 + 2) * 3 + d];
            el += f[d] * al3[t * 3 + d];
            er += f[d] * ar3[t * 3 + d];
        }
        row3[t * N_NODES + n] = make_float4(f[0], f[1], f[2], el);
        er3[t * N_NODES + n] = er;
    }
}

// ---- layer-M featurization: rowM[t][n][32] bf16 with [h*4+{0,1,2}]=f, [h*4+3]=el; erM f32
__global__ void k_featM(const float* __restrict__ h3, const float* __restrict__ WM,
                        const float* __restrict__ alM, const float* __restrict__ arM,
                        __hip_bfloat16* __restrict__ rowM, float* __restrict__ erM) {
    int n = blockIdx.x * 256 + threadIdx.x;
    if (n >= N_NODES) return;
    float h0 = h3[n * 3], h1v = h3[n * 3 + 1], h2v = h3[n * 3 + 2];
    for (int t = 0; t < T_G; t++) {
        int nb = t * N_NODES + n;
        size_t rb = (size_t)nb * 32;
#pragma unroll
        for (int hh = 0; hh < H_M; hh++) {
            float el = 0.f, er = 0.f;
#pragma unroll
            for (int d = 0; d < 3; d++) {
                int j = hh * 3 + d;
                float f = h0 * WM[(t * 3 + 0) * 24 + j] + h1v * WM[(t * 3 + 1) * 24 + j] + h2v * WM[(t * 3 + 2) * 24 + j];
                rowM[rb + hh * 4 + d] = __float2bfloat16(f);
                el += f * alM[(t * H_M + hh) * 3 + d];
                er += f * arM[(t * H_M + hh) * 3 + d];
            }
            rowM[rb + hh * 4 + 3] = __float2bfloat16(el);
            erM[nb * 8 + hh] = er;
        }
    }
}

// ---- fused layer-M aggregation (max-free): lane=(eo,h), 2x-unrolled (16 edges/iter),
//      one 8B gather per edge-lane, plain butterfly sums over eo
__global__ __launch_bounds__(256) void k_aggMf(
    const __hip_bfloat16* __restrict__ rowM, const float* __restrict__ erM,
    const int* __restrict__ rowptr, const int* __restrict__ deg, const int* __restrict__ csr_src,
    const float* __restrict__ wv, float* __restrict__ hM) {
    int t = blockIdx.y;
    int n = blockIdx.x * 4 + (threadIdx.x >> 6);
    int lane = threadIdx.x & 63;
    int h = lane & 7, eo = lane >> 3;
    int beg = rowptr[t * N_NODES + n], cnt = deg[t * N_NODES + n];
    if (cnt == 0) return;
    float erh = erM[(t * N_NODES + n) * 8 + h];
    const int* cs = csr_src + t * N_EDGES;
    const unsigned short* rt = (const unsigned short*)rowM + (size_t)t * N_NODES * 32;
    float s_run = 0.f, a0 = 0.f, a1 = 0.f, a2 = 0.f;
    for (int idx = eo; idx < cnt; idx += 16) {
        int i1 = idx + 8;
        bool v1 = i1 < cnt;
        int s0 = cs[beg + idx];
        int s1 = cs[beg + (v1 ? i1 : idx)];
        ushort4 u0 = *(const ushort4*)(rt + (size_t)s0 * 32 + h * 4);
        ushort4 u1 = *(const ushort4*)(rt + (size_t)s1 * 32 + h * 4);
        float p0 = __expf(lrelu(bf2f(u0.w) + erh));
        float p1 = v1 ? __expf(lrelu(bf2f(u1.w) + erh)) : 0.f;
        a0 += p0 * bf2f(u0.x) + p1 * bf2f(u1.x);
        a1 += p0 * bf2f(u0.y) + p1 * bf2f(u1.y);
        a2 += p0 * bf2f(u0.z) + p1 * bf2f(u1.z);
        s_run += p0 + p1;
    }
#pragma unroll
    for (int o = 8; o < 64; o <<= 1) {
        a0 += __shfl_xor(a0, o);
        a1 += __shfl_xor(a1, o);
        a2 += __shfl_xor(a2, o);
        s_run += __shfl_xor(s_run, o);
    }
    if (eo == 0) {
        float inv = wv[t] / s_run;
        atomicAdd(&hM[n * 24 + h * 3 + 0], inv * a0);
        atomicAdd(&hM[n * 24 + h * 3 + 1], inv * a1);
        atomicAdd(&hM[n * 24 + h * 3 + 2], inv * a2);
    }
}

// ---- delta norms per head + fused top-16-bit histogram
__global__ void k_norms(const float* __restrict__ hM, float* __restrict__ norms,
                        unsigned int* __restrict__ hist1) {
    int idx = blockIdx.x * 256 + threadIdx.x;
    if (idx >= N_NODES * H_M) return;
    int n = idx >> 3, hh = idx & 7;
    float s = 0.f;
#pragma unroll
    for (int d = 0; d < 3; d++) {
        float cur = hM[n * 24 + hh * 3 + d];
        float prev = (n > 0) ? hM[(n - 1) * 24 + hh * 3 + d] : 0.f;
        float dx = cur - prev;
        s += dx * dx;
    }
    float v = sqrtf(s);
    norms[hh * N_NODES + n] = v;
    unsigned int u = __float_as_uint(v);
    atomicAdd(&hist1[hh * 65536 + (u >> 16)], 1u);
}

__device__ __forceinline__ unsigned int blk_exscan(unsigned int v) {
    int lane = threadIdx.x & 63, wid = threadIdx.x >> 6;
    unsigned int sc = v;
#pragma unroll
    for (int o = 1; o < 64; o <<= 1) { unsigned int u = __shfl_up(sc, o); if (lane >= o) sc += u; }
    __shared__ unsigned int ws[4];
    if (lane == 63) ws[wid] = sc;
    __syncthreads();
    unsigned int woff = 0;
    for (int w = 0; w < wid; w++) woff += ws[w];
    __syncthreads();
    return woff + sc - v;
}

__global__ __launch_bounds__(256) void k_findbin(
    const unsigned int* __restrict__ hist1, int* __restrict__ selbin, int* __restrict__ resrank) {
    int hh = blockIdx.x >> 1, k = blockIdx.x & 1;
    unsigned int rank = N_NODES / 2 - 1 + k;  // 24999 / 25000
    const unsigned int* H = hist1 + hh * 65536;
    int tid = threadIdx.x;
    unsigned int local = 0;
    for (int j = 0; j < 256; j++) local += H[tid * 256 + j];
    unsigned int excl = blk_exscan(local);
    if (rank >= excl && rank < excl + local) {
        unsigned int cum = excl;
        for (int j = 0; j < 256; j++) {
            unsigned int c = H[tid * 256 + j];
            if (cum + c > rank) {
                selbin[hh * 2 + k] = tid * 256 + j;
                resrank[hh * 2 + k] = (int)(rank - cum);
                break;
            }
            cum += c;
        }
    }
}

__global__ void k_h2(const float* __restrict__ norms, const int* __restrict__ selbin,
                     unsigned int* __restrict__ hist2) {
    int idx = blockIdx.x * 256 + threadIdx.x;
    if (idx >= N_NODES * H_M) return;
    int hh = idx / N_NODES;
    unsigned int u = __float_as_uint(norms[idx]);
    int top = (int)(u >> 16);
#pragma unroll
    for (int k = 0; k < 2; k++)
        if (top == selbin[hh * 2 + k])
            atomicAdd(&hist2[(hh * 2 + k) * 65536 + (u & 0xFFFFu)], 1u);
}

__global__ __launch_bounds__(256) void k_findval(
    const unsigned int* __restrict__ hist2, const int* __restrict__ selbin,
    const int* __restrict__ resrank, float* __restrict__ medpair) {
    int hh = blockIdx.x >> 1, k = blockIdx.x & 1;
    unsigned int rank = (unsigned int)resrank[hh * 2 + k];
    const unsigned int* H = hist2 + (hh * 2 + k) * 65536;
    int tid = threadIdx.x;
    unsigned int local = 0;
    for (int j = 0; j < 256; j++) local += H[tid * 256 + j];
    unsigned int excl = blk_exscan(local);
    if (rank >= excl && rank < excl + local) {
        unsigned int cum = excl;
        for (int j = 0; j < 256; j++) {
            unsigned int c = H[tid * 256 + j];
            if (cum + c > rank) {
                unsigned int u = ((unsigned int)selbin[hh * 2 + k] << 16) | (unsigned int)(tid * 256 + j);
                medpair[hh * 2 + k] = __uint_as_float(u);
                break;
            }
            cum += c;
        }
    }
}

__global__ void k_final(const float* __restrict__ hM, const float* __restrict__ medpair,
                        const float* __restrict__ noise, float* __restrict__ out) {
    int idx = blockIdx.x * 256 + threadIdx.x;
    if (idx >= N_NODES * 24) return;
    int hh = (idx / 3) & 7;
    float med = 0.5f * (medpair[hh * 2] + medpair[hh * 2 + 1]) + 1e-4f;
    float v = hM[idx] / med;
    if (isnan(v)) v = 0.f;
    else if (isinf(v)) v = v > 0.f ? 100.f : -100.f;
    out[idx] = v + 0.3f * noise[idx];
}

extern "C" void kernel_launch(void* const* d_in, const int* in_sizes, int n_in,
                              void* d_out, int out_size, void* d_ws, size_t ws_size,
                              hipStream_t stream) {
    const float* x     = (const float*)d_in[0];
    const int*   edges = (const int*)d_in[1];
    const float* noise = (const float*)d_in[2];
    const float* W1  = (const float*)d_in[3];
    const float* al1 = (const float*)d_in[4];
    const float* ar1 = (const float*)d_in[5];
    const float* b1  = (const float*)d_in[6];
    const float* W2  = (const float*)d_in[7];
    const float* al2 = (const float*)d_in[8];
    const float* ar2 = (const float*)d_in[9];
    const float* b2  = (const float*)d_in[10];
    const float* W3  = (const float*)d_in[11];
    const float* al3 = (const float*)d_in[12];
    const float* ar3 = (const float*)d_in[13];
    const float* b3  = (const float*)d_in[14];
    const float* WM  = (const float*)d_in[15];
    const float* alM = (const float*)d_in[16];
    const float* arM = (const float*)d_in[17];
    const float* bM  = (const float*)d_in[18];
    const float* fc2 = (const float*)d_in[19];
    const float* fc3 = (const float*)d_in[20];
    float* out = (float*)d_out;

    char* basep = (char*)d_ws;
    size_t off = 0;
    auto alloc = [&](size_t bytes) -> void* {
        void* p = basep + off;
        off += (bytes + 255) & ~(size_t)255;
        return p;
    };
    // Region A: feat1 bf16 (25.6 MB); rowM (12.8) + erM (6.4) alias it after k_sg1
    char* regA = (char*)alloc((size_t)T_G * N_NODES * HID_F * 2);
    __hip_bfloat16* feat1 = (__hip_bfloat16*)regA;
    __hip_bfloat16* rowM  = (__hip_bfloat16*)regA;                 // T*N*32 bf16 = 12.8MB
    float*          erM   = (float*)(regA + 12800000);             // T*N*8 f32 = 6.4MB
    // Region U (25.6MB): bedge (int2, CSR build only)
    char* regU = (char*)alloc((size_t)T_G * N_EDGES * 8);
    int2*  bedge = (int2*)regU;
    float* el1 = (float*)alloc((size_t)T_G * N_NODES * 4);
    float* er1 = (float*)alloc((size_t)T_G * N_NODES * 4);
    float* h1  = (float*)alloc((size_t)N_NODES * HID_F * 4);
    float4* row2 = (float4*)alloc((size_t)T_G * N_NODES * 16);
    float* er2 = (float*)alloc((size_t)T_G * N_NODES * 4);
    float* h2  = (float*)alloc((size_t)N_NODES * 3 * 4);
    float4* row3 = (float4*)alloc((size_t)T_G * N_NODES * 16);
    float* er3 = (float*)alloc((size_t)T_G * N_NODES * 4);
    float* h3  = (float*)alloc((size_t)N_NODES * 3 * 4);
    float* hM  = (float*)alloc((size_t)N_NODES * 24 * 4);
    float* norms = (float*)alloc((size_t)H_M * N_NODES * 4);
    float* medpair = (float*)alloc(64);
    float* wbuf = (float*)alloc(512);
    int* deg    = (int*)alloc((size_t)T_G * N_NODES * 4);
    int* rowptr = (int*)alloc((size_t)T_G * N_NODES * 4);
    int* hist   = (int*)alloc((size_t)T_G * HTOT * 4);       // 307KB
    int* csr_src = (int*)alloc((size_t)T_G * N_EDGES * 4);
    unsigned int* hist1 = (unsigned int*)alloc((size_t)H_M * 65536 * 4);
    unsigned int* hist2 = (unsigned int*)alloc((size_t)H_M * 2 * 65536 * 4);
    int* selbin  = (int*)alloc(64);
    int* resrank = (int*)alloc(64);

    const int NB = (N_NODES + 255) / 256;   // 196
    const int NW = (N_NODES + 3) / 4;       // 12500
    const int NG = N_NODES / 16;            // 3125 (16 nodes per block)
    const int NE8 = (N_NODES * H_M + 255) / 256;

    hipMemsetAsync(hist1, 0, (size_t)H_M * 65536 * 4, stream);
    hipMemsetAsync(hist2, 0, (size_t)H_M * 2 * 65536 * 4, stream);

    k_wvec<<<1, 128, 0, stream>>>(fc2, fc3, b1, b2, b3, bM, wbuf);
    k_init_all<<<(N_NODES * HID_F + 255) / 256, 256, 0, stream>>>(wbuf, h1, h2, h3, hM);

    // Bucketed CSR build (no global atomics)
    k_bcount<<<dim3(NCHK, T_G), 256, 0, stream>>>(edges, hist);
    k_bscan<<<T_G, 1024, 0, stream>>>(hist);
    k_bscatter<<<dim3(NCHK, T_G), 256, 0, stream>>>(edges, hist, bedge);
    k_bfinal<<<dim3(NBKT, T_G), 512, 0, stream>>>(hist, bedge, deg, rowptr, csr_src);

    // Layer 1 (MFMA GEMM + single-pass fused softmax/gather, 4x unroll)
    k_gemm1<<<dim3(N_NODES / 16, T_G), 256, 0, stream>>>(x, W1, al1, ar1, feat1, el1, er1);
    k_sg1<<<dim3(NW, T_G), 256, 0, stream>>>(feat1, el1, er1, rowptr, deg, csr_src, h1);

    // Layer 2 (fused softmax+gather, 4 nodes/wave)
    k_feat2<<<NB, 256, 0, stream>>>(h1, W2, al2, ar2, row2, er2);
    k_gat3f<<<dim3(NG, T_G), 256, 0, stream>>>(row2, er2, rowptr, deg, csr_src, wbuf + 0, h2);

    // Layer 3 (fused)
    k_feat3<<<NB, 256, 0, stream>>>(h2, W3, al3, ar3, row3, er3);
    k_gat3f<<<dim3(NG, T_G), 256, 0, stream>>>(row3, er3, rowptr, deg, csr_src, wbuf + 4, h3);

    // Layer M (fused; rowM/erM alias feat1 region — feat1 dead after k_sg1)
    k_featM<<<NB, 256, 0, stream>>>(h3, WM, alM, arM, rowM, erM);
    k_aggMf<<<dim3(NW, T_G), 256, 0, stream>>>(rowM, erM, rowptr, deg, csr_src, wbuf + 4, hM);

    // norm_ (telescoped): parallel exact median via 2-level histogram select
    k_norms<<<NE8, 256, 0, stream>>>(hM, norms, hist1);
    k_findbin<<<16, 256, 0, stream>>>(hist1, selbin, resrank);
    k_h2<<<NE8, 256, 0, stream>>>(norms, selbin, hist2);
    k_findval<<<16, 256, 0, stream>>>(hist2, selbin, resrank, medpair);
    k_final<<<(N_NODES * 24 + 255) / 256, 256, 0, stream>>>(hM, medpair, noise, out);
}

// Round 19
// 586.014 us; speedup vs baseline: 1.0784x; 1.0038x over previous
//
#include <hip/hip_runtime.h>
#include <hip/hip_bf16.h>
#include <math.h>

#define N_NODES 50000
#define N_EDGES 800000
#define T_G 4
#define IN_F 128
#define HID_F 64
#define OUT_F 3
#define H_M 8

// bucketed CSR build params
#define BSH 9
#define NBKT 98            // ceil(50000 / 512)
#define CHK 4096
#define NCHK 196           // ceil(800000 / 4096)
#define HTOT (NBKT * NCHK) // 19208

typedef short bf16x8 __attribute__((ext_vector_type(8)));
typedef float f32x4 __attribute__((ext_vector_type(4)));
typedef float f32x2 __attribute__((ext_vector_type(2)));

__device__ __forceinline__ float lrelu(float v) { return v > 0.f ? v : 0.2f * v; }

__device__ __forceinline__ float wred_sum(float v) {
#pragma unroll
    for (int o = 32; o; o >>= 1) v += __shfl_xor(v, o);
    return v;
}
__device__ __forceinline__ float bf2f(unsigned int u) {
    return __uint_as_float(u << 16);
}
__device__ __forceinline__ float bflo(unsigned int u) {  // low bf16 of packed pair (1 op)
    return __uint_as_float(u << 16);
}
__device__ __forceinline__ float bfhi(unsigned int u) {  // high bf16 of packed pair (1 op)
    return __uint_as_float(u & 0xFFFF0000u);
}
__device__ __forceinline__ f32x2 bfpair(unsigned int u) {
    f32x2 r;
    r.x = __uint_as_float(u << 16);
    r.y = __uint_as_float(u & 0xFFFF0000u);
    return r;
}
__device__ __forceinline__ short f2bf(float f) {  // RNE f32->bf16 bits
    unsigned u = __float_as_uint(f);
    u += 0x7FFF + ((u >> 16) & 1);
    return (short)(u >> 16);
}

// ---- weight/bias precompute:
// w[0:4]=w2, [4:8]=w3, [8:11]=cb2, [11:14]=cb3, [16:40]=cbM, [64:128]=bavg1
__global__ void k_wvec(const float* __restrict__ fc2, const float* __restrict__ fc3,
                       const float* __restrict__ b1, const float* __restrict__ b2,
                       const float* __restrict__ b3, const float* __restrict__ bM,
                       float* __restrict__ w) {
    __shared__ float w2[4], w3[4];
    int i = threadIdx.x;
    if (i < 4) {
        float a = 0.f, b = 0.f;
        for (int r = 0; r < T_G; r++) { a += fc2[r * T_G + i]; b += fc3[r * T_G + i]; }
        w2[i] = 0.25f * a; w3[i] = 0.25f * b;
        w[i] = w2[i]; w[4 + i] = w3[i];
    }
    __syncthreads();
    if (i < 3) {
        float c = 0.f;
        for (int t = 0; t < T_G; t++) c += w2[t] * b2[t * 3 + i];
        w[8 + i] = c;
    }
    if (i >= 8 && i < 11) {
        int d = i - 8;
        float c = 0.f;
        for (int t = 0; t < T_G; t++) c += w3[t] * b3[t * 3 + d];
        w[11 + d] = c;
    }
    if (i >= 16 && i < 40) {
        int j = i - 16;
        float c = 0.f;
        for (int t = 0; t < T_G; t++) c += w3[t] * bM[t * 24 + j];
        w[16 + j] = c;
    }
    if (i >= 64 && i < 128) {
        int c = i - 64;
        w[i] = 0.25f * (b1[c] + b1[HID_F + c] + b1[2 * HID_F + c] + b1[3 * HID_F + c]);
    }
}

// ---- init of pre-biased accumulators (h1 handled by k_gemm1 t==0 blocks)
__global__ void k_init_all(const float* __restrict__ w, float* __restrict__ h2,
                           float* __restrict__ h3, float* __restrict__ hM) {
    int i = blockIdx.x * 256 + threadIdx.x;
    if (i < N_NODES * 3) { h2[i] = w[8 + i % 3]; h3[i] = w[11 + i % 3]; }
    if (i < N_NODES * 24) hM[i] = w[16 + i % 24];
}

// ---- layer-1 GEMM via MFMA: block = 16 nodes x 64 cols x one t; wave = 16-col tile.
//      t==0 blocks also write the bias-init of h1 (coalesced, same pattern as feat1)
__global__ __launch_bounds__(256) void k_gemm1(
    const float* __restrict__ x, const float* __restrict__ W1,
    const float* __restrict__ al1, const float* __restrict__ ar1,
    const float* __restrict__ wbuf,
    __hip_bfloat16* __restrict__ feat1, float* __restrict__ el1, float* __restrict__ er1,
    float* __restrict__ h1) {
    __shared__ float tile[16][HID_F];
    int t = blockIdx.y;
    int base = blockIdx.x * 16;
    int w = threadIdx.x >> 6, lane = threadIdx.x & 63;
    int lr = lane & 15, lk = lane >> 4;
    const float* xrow = x + (size_t)(base + lr) * IN_F;
    const float* Wt = W1 + (size_t)t * IN_F * HID_F;
    f32x4 acc = {0.f, 0.f, 0.f, 0.f};
#pragma unroll
    for (int ks = 0; ks < 4; ks++) {
        int k0 = ks * 32 + lk * 8;
        const float4* xp = (const float4*)(xrow + k0);
        float4 v0 = xp[0], v1 = xp[1];
        bf16x8 a, b;
        a[0] = f2bf(v0.x); a[1] = f2bf(v0.y); a[2] = f2bf(v0.z); a[3] = f2bf(v0.w);
        a[4] = f2bf(v1.x); a[5] = f2bf(v1.y); a[6] = f2bf(v1.z); a[7] = f2bf(v1.w);
#pragma unroll
        for (int j = 0; j < 8; j++) b[j] = f2bf(Wt[(k0 + j) * HID_F + w * 16 + lr]);
        acc = __builtin_amdgcn_mfma_f32_16x16x32_bf16(a, b, acc, 0, 0, 0);
    }
#pragma unroll
    for (int r = 0; r < 4; r++) tile[lk * 4 + r][w * 16 + lr] = acc[r];
    __syncthreads();
#pragma unroll
    for (int q = 0; q < 4; q++) {
        int e = q * 256 + threadIdx.x;
        int node = e >> 6, c = e & 63;
        feat1[((size_t)t * N_NODES + base + node) * HID_F + c] = __float2bfloat16(tile[node][c]);
        if (t == 0) h1[(size_t)(base + node) * HID_F + c] = wbuf[64 + c];
    }
    float alv = al1[t * HID_F + lane], arv = ar1[t * HID_F + lane];
#pragma unroll
    for (int q = 0; q < 4; q++) {
        int node = w * 4 + q;
        float f = tile[node][lane];
        float vl = wred_sum(f * alv);
        float vr = wred_sum(f * arv);
        if (lane == 0) {
            el1[t * N_NODES + base + node] = vl;
            er1[t * N_NODES + base + node] = vr;
        }
    }
}

// ==== bucketed CSR build (no global atomics, no random HBM RMW) ====

__global__ __launch_bounds__(256) void k_bcount(const int* __restrict__ edges,
                                                int* __restrict__ hist) {
    int t = blockIdx.y, c = blockIdx.x;
    __shared__ int hl[NBKT];
    if (threadIdx.x < NBKT) hl[threadIdx.x] = 0;
    __syncthreads();
    const int* dst = edges + (t * 2 + 1) * N_EDGES;
    int e0 = c * CHK, e1 = min(e0 + CHK, N_EDGES);
    for (int i = e0 + threadIdx.x; i < e1; i += 256)
        atomicAdd(&hl[dst[i] >> BSH], 1);
    __syncthreads();
    if (threadIdx.x < NBKT) hist[t * HTOT + threadIdx.x * NCHK + c] = hl[threadIdx.x];
}

__global__ __launch_bounds__(1024) void k_bscan(int* __restrict__ hist) {
    int t = blockIdx.x;
    int* H = hist + t * HTOT;
    __shared__ int ws[16];
    __shared__ int carry;
    if (threadIdx.x == 0) carry = 0;
    __syncthreads();
    int lane = threadIdx.x & 63, wid = threadIdx.x >> 6;
    for (int base = 0; base < HTOT; base += 1024) {
        int i = base + threadIdx.x;
        int v = (i < HTOT) ? H[i] : 0;
        int sc = v;
#pragma unroll
        for (int o = 1; o < 64; o <<= 1) { int u = __shfl_up(sc, o); if (lane >= o) sc += u; }
        if (lane == 63) ws[wid] = sc;
        __syncthreads();
        if (wid == 0 && lane < 16) {
            int wv = ws[lane];
#pragma unroll
            for (int o = 1; o < 16; o <<= 1) { int u = __shfl_up(wv, o); if (lane >= o) wv += u; }
            ws[lane] = wv;
        }
        __syncthreads();
        int woff = (wid == 0) ? 0 : ws[wid - 1];
        if (i < HTOT) H[i] = carry + woff + sc - v;  // exclusive
        int tot = ws[15];
        __syncthreads();
        if (threadIdx.x == 0) carry += tot;
        __syncthreads();
    }
}

__global__ __launch_bounds__(256) void k_bscatter(const int* __restrict__ edges,
                                                  const int* __restrict__ hist,
                                                  int2* __restrict__ bedge) {
    int t = blockIdx.y, c = blockIdx.x;
    __shared__ int cur[NBKT];
    if (threadIdx.x < NBKT) cur[threadIdx.x] = hist[t * HTOT + threadIdx.x * NCHK + c];
    __syncthreads();
    const int* srcp = edges + (t * 2 + 0) * N_EDGES;
    const int* dstp = edges + (t * 2 + 1) * N_EDGES;
    int2* be = bedge + (size_t)t * N_EDGES;
    int e0 = c * CHK, e1 = min(e0 + CHK, N_EDGES);
    for (int i = e0 + threadIdx.x; i < e1; i += 256) {
        int d = dstp[i], s = srcp[i];
        int pos = atomicAdd(&cur[d >> BSH], 1);
        be[pos] = make_int2(s, d);
    }
}

__global__ __launch_bounds__(512) void k_bfinal(const int* __restrict__ hist,
                                                const int2* __restrict__ bedge,
                                                int* __restrict__ deg, int* __restrict__ rowptr,
                                                int* __restrict__ csr_src) {
    int t = blockIdx.y, b = blockIdx.x;
    int n0 = b << BSH;
    int nn = min(512, N_NODES - n0);
    __shared__ int degl[512], curl[512], ws[8];
    degl[threadIdx.x] = 0;
    __syncthreads();
    int base = hist[t * HTOT + b * NCHK];
    int end  = (b == NBKT - 1) ? N_EDGES : hist[t * HTOT + (b + 1) * NCHK];
    const int2* be = bedge + (size_t)t * N_EDGES;
    for (int e = base + threadIdx.x; e < end; e += 512)
        atomicAdd(&degl[be[e].y - n0], 1);
    __syncthreads();
    int v = degl[threadIdx.x];
    int lane = threadIdx.x & 63, wid = threadIdx.x >> 6;
    int sc = v;
#pragma unroll
    for (int o = 1; o < 64; o <<= 1) { int u = __shfl_up(sc, o); if (lane >= o) sc += u; }
    if (lane == 63) ws[wid] = sc;
    __syncthreads();
    if (wid == 0 && lane < 8) {
        int wv = ws[lane];
#pragma unroll
        for (int o = 1; o < 8; o <<= 1) { int u = __shfl_up(wv, o); if (lane >= o) wv += u; }
        ws[lane] = wv;
    }
    __syncthreads();
    int excl = ((wid == 0) ? 0 : ws[wid - 1]) + sc - v;
    if (threadIdx.x < nn) {
        rowptr[t * N_NODES + n0 + threadIdx.x] = base + excl;
        deg[t * N_NODES + n0 + threadIdx.x] = v;
    }
    curl[threadIdx.x] = base + excl;
    __syncthreads();
    for (int e = base + threadIdx.x; e < end; e += 512) {
        int2 ed = be[e];
        int pos = atomicAdd(&curl[ed.y - n0], 1);
        csr_src[t * N_EDGES + pos] = ed.x;
    }
}

// ---- fused layer-1 softmax+gather, single pass, 4x-unrolled edge loop,
//      packed-f32 accumulators (v_pk_fma_f32): lane=(edge-group g, octant i)
__global__ __launch_bounds__(256) void k_sg1(
    const __hip_bfloat16* __restrict__ feat1, const float* __restrict__ el1,
    const float* __restrict__ er1, const int* __restrict__ rowptr,
    const int* __restrict__ deg, const int* __restrict__ cs_all,
    float* __restrict__ h1) {
    __shared__ float xfer[4][HID_F];
    int t = blockIdx.y;
    int w = threadIdx.x >> 6;
    int n = blockIdx.x * 4 + w;
    int lane = threadIdx.x & 63;
    int beg = rowptr[t * N_NODES + n], cnt = deg[t * N_NODES + n];
    int g = lane >> 3, i = lane & 7;
    if (cnt > 0) {  // wave-uniform condition
        const int* cs = cs_all + t * N_EDGES + beg;
        const float* el = el1 + t * N_NODES;
        float ern = er1[t * N_NODES + n];
        const unsigned short* ft = (const unsigned short*)feat1 + (size_t)t * N_NODES * HID_F;
        f32x2 acc2[4];
#pragma unroll
        for (int j = 0; j < 4; j++) acc2[j] = (f32x2){0.f, 0.f};
        float sacc = 0.f;
        for (int c0 = 0; c0 < cnt; c0 += 32) {
            int e0 = c0 + g, e1 = c0 + 8 + g, e2 = c0 + 16 + g, e3 = c0 + 24 + g;
            bool v0 = e0 < cnt, v1 = e1 < cnt, v2 = e2 < cnt, v3 = e3 < cnt;
            int s0 = cs[v0 ? e0 : 0];
            int s1 = cs[v1 ? e1 : 0];
            int s2 = cs[v2 ? e2 : 0];
            int s3 = cs[v3 ? e3 : 0];
            float p0 = v0 ? __expf(lrelu(el[s0] + ern)) : 0.f;
            float p1 = v1 ? __expf(lrelu(el[s1] + ern)) : 0.f;
            float p2 = v2 ? __expf(lrelu(el[s2] + ern)) : 0.f;
            float p3 = v3 ? __expf(lrelu(el[s3] + ern)) : 0.f;
            uint4 u0 = *(const uint4*)(ft + (size_t)s0 * HID_F + i * 8);
            uint4 u1 = *(const uint4*)(ft + (size_t)s1 * HID_F + i * 8);
            uint4 u2 = *(const uint4*)(ft + (size_t)s2 * HID_F + i * 8);
            uint4 u3 = *(const uint4*)(ft + (size_t)s3 * HID_F + i * 8);
            f32x2 pv0 = {p0, p0}, pv1 = {p1, p1}, pv2 = {p2, p2}, pv3 = {p3, p3};
            acc2[0] += pv0 * bfpair(u0.x) + pv1 * bfpair(u1.x);
            acc2[1] += pv0 * bfpair(u0.y) + pv1 * bfpair(u1.y);
            acc2[2] += pv0 * bfpair(u0.z) + pv1 * bfpair(u1.z);
            acc2[3] += pv0 * bfpair(u0.w) + pv1 * bfpair(u1.w);
            acc2[0] += pv2 * bfpair(u2.x) + pv3 * bfpair(u3.x);
            acc2[1] += pv2 * bfpair(u2.y) + pv3 * bfpair(u3.y);
            acc2[2] += pv2 * bfpair(u2.z) + pv3 * bfpair(u3.z);
            acc2[3] += pv2 * bfpair(u2.w) + pv3 * bfpair(u3.w);
            sacc += (p0 + p1) + (p2 + p3);
        }
        float acc[8];
#pragma unroll
        for (int j = 0; j < 4; j++) { acc[2 * j] = acc2[j].x; acc[2 * j + 1] = acc2[j].y; }
#pragma unroll
        for (int o = 8; o < 64; o <<= 1) {
#pragma unroll
            for (int j = 0; j < 8; j++) acc[j] += __shfl_xor(acc[j], o);
            sacc += __shfl_xor(sacc, o);
        }
        if (g == 0) {
            float inv = 0.25f / sacc;
#pragma unroll
            for (int j = 0; j < 8; j++) xfer[w][i * 8 + j] = acc[j] * inv;
        }
    }
    __syncthreads();
    if (cnt > 0) atomicAdd(&h1[n * HID_F + lane], xfer[w][lane]);
}

// ---- layer-2 featurization: packed row2[t][n] = float4(f0,f1,f2,el); er2 separate
__global__ __launch_bounds__(256) void k_feat2(
    const float* __restrict__ h1, const float* __restrict__ W2,
    const float* __restrict__ al2, const float* __restrict__ ar2,
    float4* __restrict__ row2, float* __restrict__ er2) {
    __shared__ float Wl[T_G * HID_F * OUT_F];
    __shared__ float Al[T_G * OUT_F], Ar[T_G * OUT_F];
    for (int i = threadIdx.x; i < T_G * HID_F * OUT_F; i += 256) Wl[i] = W2[i];
    if (threadIdx.x < T_G * OUT_F) { Al[threadIdx.x] = al2[threadIdx.x]; Ar[threadIdx.x] = ar2[threadIdx.x]; }
    __syncthreads();
    int n = blockIdx.x * 256 + threadIdx.x;
    if (n >= N_NODES) return;
    float h[HID_F];
    const float4* hp = (const float4*)(h1 + n * HID_F);
#pragma unroll
    for (int i = 0; i < 16; i++) {
        float4 v = hp[i];
        h[4 * i] = v.x; h[4 * i + 1] = v.y; h[4 * i + 2] = v.z; h[4 * i + 3] = v.w;
    }
    for (int t = 0; t < T_G; t++) {
        float f0 = 0.f, f1 = 0.f, f2 = 0.f;
#pragma unroll
        for (int k = 0; k < HID_F; k++) {
            float hv = h[k];
            f0 += hv * Wl[(t * HID_F + k) * 3 + 0];
            f1 += hv * Wl[(t * HID_F + k) * 3 + 1];
            f2 += hv * Wl[(t * HID_F + k) * 3 + 2];
        }
        float el = f0 * Al[t * 3] + f1 * Al[t * 3 + 1] + f2 * Al[t * 3 + 2];
        row2[t * N_NODES + n] = make_float4(f0, f1, f2, el);
        er2[t * N_NODES + n] = f0 * Ar[t * 3] + f1 * Ar[t * 3 + 1] + f2 * Ar[t * 3 + 2];
    }
}

// ---- fused d=3 aggregation (max-free): 4 nodes per wave, 16 lanes per node,
//      2x-unrolled edge loop, intra-group butterfly, atomicAdd into pre-biased hout
__global__ __launch_bounds__(256) void k_gat3f(
    const float4* __restrict__ row, const float* __restrict__ er_,
    const int* __restrict__ rowptr, const int* __restrict__ deg, const int* __restrict__ csr_src,
    const float* __restrict__ wv, float* __restrict__ hout) {
    int t = blockIdx.y;
    int lane = threadIdx.x & 63;
    int w = threadIdx.x >> 6;
    int nq = lane >> 4, e = lane & 15;
    int n = blockIdx.x * 16 + w * 4 + nq;  // 3125*16 == 50000 exact
    int beg = rowptr[t * N_NODES + n], cnt = deg[t * N_NODES + n];
    if (cnt == 0) return;  // group-uniform (16-lane groups share n)
    float erh = er_[t * N_NODES + n];
    const int* cs = csr_src + t * N_EDGES;
    const float4* rt = row + t * N_NODES;
    float s_run = 0.f, a0 = 0.f, a1 = 0.f, a2 = 0.f;
    for (int idx = e; idx < cnt; idx += 32) {
        int i1 = idx + 16;
        bool v1 = i1 < cnt;
        int s0 = cs[beg + idx];
        int s1 = cs[beg + (v1 ? i1 : idx)];
        float4 r0 = rt[s0];
        float4 r1 = rt[s1];
        float p0 = __expf(lrelu(r0.w + erh));
        float p1 = v1 ? __expf(lrelu(r1.w + erh)) : 0.f;
        a0 += p0 * r0.x + p1 * r1.x;
        a1 += p0 * r0.y + p1 * r1.y;
        a2 += p0 * r0.z + p1 * r1.z;
        s_run += p0 + p1;
    }
#pragma unroll
    for (int o = 1; o < 16; o <<= 1) {  // xor<16 stays within the 16-lane group
        a0 += __shfl_xor(a0, o);
        a1 += __shfl_xor(a1, o);
        a2 += __shfl_xor(a2, o);
        s_run += __shfl_xor(s_run, o);
    }
    if (e < 3) {
        float v = (e == 0) ? a0 : (e == 1) ? a1 : a2;
        atomicAdd(&hout[n * 3 + e], wv[t] * v / s_run);
    }
}

// ---- layer-3 featurization (3->3): packed row3 + er3
__global__ void k_feat3(const float* __restrict__ h2, const float* __restrict__ W3,
                        const float* __restrict__ al3, const float* __restrict__ ar3,
                        float4* __restrict__ row3, float* __restrict__ er3) {
    int n = blockIdx.x * 256 + threadIdx.x;
    if (n >= N_NODES) return;
    float h0 = h2[n * 3], h1v = h2[n * 3 + 1], h2v = h2[n * 3 + 2];
    for (int t = 0; t < T_G; t++) {
        float f[3], el = 0.f, er = 0.f;
#pragma unroll
        for (int d = 0; d < 3; d++) {
            f[d] = h0 * W3[(t * 3 + 0) * 3 + d] + h1v * W3[(t * 3 + 1) * 3 + d] + h2v * W3[(t * 3 + 2) * 3 + d];
            el += f[d] * al3[t * 3 + d];
            er += f[d] * ar3[t * 3 + d];
        }
        row3[t * N_NODES + n] = make_float4(f[0], f[1], f[2], el);
        er3[t * N_NODES + n] = er;
    }
}

// ---- layer-M featurization: rowM[t][n][32] bf16 with [h*4+{0,1,2}]=f, [h*4+3]=el; erM f32
__global__ void k_featM(const float* __restrict__ h3, const float* __restrict__ WM,
                        const float* __restrict__ alM, const float* __restrict__ arM,
                        __hip_bfloat16* __restrict__ rowM, float* __restrict__ erM) {
    int n = blockIdx.x * 256 + threadIdx.x;
    if (n >= N_NODES) return;
    float h0 = h3[n * 3], h1v = h3[n * 3 + 1], h2v = h3[n * 3 + 2];
    for (int t = 0; t < T_G; t++) {
        int nb = t * N_NODES + n;
        size_t rb = (size_t)nb * 32;
#pragma unroll
        for (int hh = 0; hh < H_M; hh++) {
            float el = 0.f, er = 0.f;
#pragma unroll
            for (int d = 0; d < 3; d++) {
                int j = hh * 3 + d;
                float f = h0 * WM[(t * 3 + 0) * 24 + j] + h1v * WM[(t * 3 + 1) * 24 + j] + h2v * WM[(t * 3 + 2) * 24 + j];
                rowM[rb + hh * 4 + d] = __float2bfloat16(f);
                el += f * alM[(t * H_M + hh) * 3 + d];
                er += f * arM[(t * H_M + hh) * 3 + d];
            }
            rowM[rb + hh * 4 + 3] = __float2bfloat16(el);
            erM[nb * 8 + hh] = er;
        }
    }
}

// ---- fused layer-M aggregation (max-free): lane=(eo,h), 2x-unrolled (16 edges/iter),
//      one 8B gather per edge-lane, plain butterfly sums over eo
__global__ __launch_bounds__(256) void k_aggMf(
    const __hip_bfloat16* __restrict__ rowM, const float* __restrict__ erM,
    const int* __restrict__ rowptr, const int* __restrict__ deg, const int* __restrict__ csr_src,
    const float* __restrict__ wv, float* __restrict__ hM) {
    int t = blockIdx.y;
    int n = blockIdx.x * 4 + (threadIdx.x >> 6);
    int lane = threadIdx.x & 63;
    int h = lane & 7, eo = lane >> 3;
    int beg = rowptr[t * N_NODES + n], cnt = deg[t * N_NODES + n];
    if (cnt == 0) return;
    float erh = erM[(t * N_NODES + n) * 8 + h];
    const int* cs = csr_src + t * N_EDGES;
    const unsigned short* rt = (const unsigned short*)rowM + (size_t)t * N_NODES * 32;
    float s_run = 0.f, a0 = 0.f, a1 = 0.f, a2 = 0.f;
    for (int idx = eo; idx < cnt; idx += 16) {
        int i1 = idx + 8;
        bool v1 = i1 < cnt;
        int s0 = cs[beg + idx];
        int s1 = cs[beg + (v1 ? i1 : idx)];
        ushort4 u0 = *(const ushort4*)(rt + (size_t)s0 * 32 + h * 4);
        ushort4 u1 = *(const ushort4*)(rt + (size_t)s1 * 32 + h * 4);
        float p0 = __expf(lrelu(bf2f(u0.w) + erh));
        float p1 = v1 ? __expf(lrelu(bf2f(u1.w) + erh)) : 0.f;
        a0 += p0 * bf2f(u0.x) + p1 * bf2f(u1.x);
        a1 += p0 * bf2f(u0.y) + p1 * bf2f(u1.y);
        a2 += p0 * bf2f(u0.z) + p1 * bf2f(u1.z);
        s_run += p0 + p1;
    }
#pragma unroll
    for (int o = 8; o < 64; o <<= 1) {
        a0 += __shfl_xor(a0, o);
        a1 += __shfl_xor(a1, o);
        a2 += __shfl_xor(a2, o);
        s_run += __shfl_xor(s_run, o);
    }
    if (eo == 0) {
        float inv = wv[t] / s_run;
        atomicAdd(&hM[n * 24 + h * 3 + 0], inv * a0);
        atomicAdd(&hM[n * 24 + h * 3 + 1], inv * a1);
        atomicAdd(&hM[n * 24 + h * 3 + 2], inv * a2);
    }
}

// ---- delta norms per head + fused top-16-bit histogram
__global__ void k_norms(const float* __restrict__ hM, float* __restrict__ norms,
                        unsigned int* __restrict__ hist1) {
    int idx = blockIdx.x * 256 + threadIdx.x;
    if (idx >= N_NODES * H_M) return;
    int n = idx >> 3, hh = idx & 7;
    float s = 0.f;
#pragma unroll
    for (int d = 0; d < 3; d++) {
        float cur = hM[n * 24 + hh * 3 + d];
        float prev = (n > 0) ? hM[(n - 1) * 24 + hh * 3 + d] : 0.f;
        float dx = cur - prev;
        s += dx * dx;
    }
    float v = sqrtf(s);
    norms[hh * N_NODES + n] = v;
    unsigned int u = __float_as_uint(v);
    atomicAdd(&hist1[hh * 65536 + (u >> 16)], 1u);
}

__device__ __forceinline__ unsigned int blk_exscan(unsigned int v) {
    int lane = threadIdx.x & 63, wid = threadIdx.x >> 6;
    unsigned int sc = v;
#pragma unroll
    for (int o = 1; o < 64; o <<= 1) { unsigned int u = __shfl_up(sc, o); if (lane >= o) sc += u; }
    __shared__ unsigned int ws[4];
    if (lane == 63) ws[wid] = sc;
    __syncthreads();
    unsigned int woff = 0;
    for (int w = 0; w < wid; w++) woff += ws[w];
    __syncthreads();
    return woff + sc - v;
}

__global__ __launch_bounds__(256) void k_findbin(
    const unsigned int* __restrict__ hist1, int* __restrict__ selbin, int* __restrict__ resrank) {
    int hh = blockIdx.x >> 1, k = blockIdx.x & 1;
    unsigned int rank = N_NODES / 2 - 1 + k;  // 24999 / 25000
    const unsigned int* H = hist1 + hh * 65536;
    int tid = threadIdx.x;
    unsigned int local = 0;
    for (int j = 0; j < 256; j++) local += H[tid * 256 + j];
    unsigned int excl = blk_exscan(local);
    if (rank >= excl && rank < excl + local) {
        unsigned int cum = excl;
        for (int j = 0; j < 256; j++) {
            unsigned int c = H[tid * 256 + j];
            if (cum + c > rank) {
                selbin[hh * 2 + k] = tid * 256 + j;
                resrank[hh * 2 + k] = (int)(rank - cum);
                break;
            }
            cum += c;
        }
    }
}

__global__ void k_h2(const float* __restrict__ norms, const int* __restrict__ selbin,
                     unsigned int* __restrict__ hist2) {
    int idx = blockIdx.x * 256 + threadIdx.x;
    if (idx >= N_NODES * H_M) return;
    int hh = idx / N_NODES;
    unsigned int u = __float_as_uint(norms[idx]);
    int top = (int)(u >> 16);
#pragma unroll
    for (int k = 0; k < 2; k++)
        if (top == selbin[hh * 2 + k])
            atomicAdd(&hist2[(hh * 2 + k) * 65536 + (u & 0xFFFFu)], 1u);
}

__global__ __launch_bounds__(256) void k_findval(
    const unsigned int* __restrict__ hist2, const int* __restrict__ selbin,
    const int* __restrict__ resrank, float* __restrict__ medpair) {
    int hh = blockIdx.x >> 1, k = blockIdx.x & 1;
    unsigned int rank = (unsigned int)resrank[hh * 2 + k];
    const unsigned int* H = hist2 + (hh * 2 + k) * 65536;
    int tid = threadIdx.x;
    unsigned int local = 0;
    for (int j = 0; j < 256; j++) local += H[tid * 256 + j];
    unsigned int excl = blk_exscan(local);
    if (rank >= excl && rank < excl + local) {
        unsigned int cum = excl;
        for (int j = 0; j < 256; j++) {
            unsigned int c = H[tid * 256 + j];
            if (cum + c > rank) {
                unsigned int u = ((unsigned int)selbin[hh * 2 + k] << 16) | (unsigned int)(tid * 256 + j);
                medpair[hh * 2 + k] = __uint_as_float(u);
                break;
            }
            cum += c;
        }
    }
}

__global__ void k_final(const float* __restrict__ hM, const float* __restrict__ medpair,
                        const float* __restrict__ noise, float* __restrict__ out) {
    int idx = blockIdx.x * 256 + threadIdx.x;
    if (idx >= N_NODES * 24) return;
    int hh = (idx / 3) & 7;
    float med = 0.5f * (medpair[hh * 2] + medpair[hh * 2 + 1]) + 1e-4f;
    float v = hM[idx] / med;
    if (isnan(v)) v = 0.f;
    else if (isinf(v)) v = v > 0.f ? 100.f : -100.f;
    out[idx] = v + 0.3f * noise[idx];
}

extern "C" void kernel_launch(void* const* d_in, const int* in_sizes, int n_in,
                              void* d_out, int out_size, void* d_ws, size_t ws_size,
                              hipStream_t stream) {
    const float* x     = (const float*)d_in[0];
    const int*   edges = (const int*)d_in[1];
    const float* noise = (const float*)d_in[2];
    const float* W1  = (const float*)d_in[3];
    const float* al1 = (const float*)d_in[4];
    const float* ar1 = (const float*)d_in[5];
    const float* b1  = (const float*)d_in[6];
    const float* W2  = (const float*)d_in[7];
    const float* al2 = (const float*)d_in[8];
    const float* ar2 = (const float*)d_in[9];
    const float* b2  = (const float*)d_in[10];
    const float* W3  = (const float*)d_in[11];
    const float* al3 = (const float*)d_in[12];
    const float* ar3 = (const float*)d_in[13];
    const float* b3  = (const float*)d_in[14];
    const float* WM  = (const float*)d_in[15];
    const float* alM = (const float*)d_in[16];
    const float* arM = (const float*)d_in[17];
    const float* bM  = (const float*)d_in[18];
    const float* fc2 = (const float*)d_in[19];
    const float* fc3 = (const float*)d_in[20];
    float* out = (float*)d_out;

    char* basep = (char*)d_ws;
    size_t off = 0;
    auto alloc = [&](size_t bytes) -> void* {
        void* p = basep + off;
        off += (bytes + 255) & ~(size_t)255;
        return p;
    };
    // Region A: feat1 bf16 (25.6 MB); rowM (12.8) + erM (6.4) alias it after k_sg1
    char* regA = (char*)alloc((size_t)T_G * N_NODES * HID_F * 2);
    __hip_bfloat16* feat1 = (__hip_bfloat16*)regA;
    __hip_bfloat16* rowM  = (__hip_bfloat16*)regA;                 // T*N*32 bf16 = 12.8MB
    float*          erM   = (float*)(regA + 12800000);             // T*N*8 f32 = 6.4MB
    // Region U (25.6MB): bedge (int2, CSR build only)
    char* regU = (char*)alloc((size_t)T_G * N_EDGES * 8);
    int2*  bedge = (int2*)regU;
    float* el1 = (float*)alloc((size_t)T_G * N_NODES * 4);
    float* er1 = (float*)alloc((size_t)T_G * N_NODES * 4);
    float* h1  = (float*)alloc((size_t)N_NODES * HID_F * 4);
    float4* row2 = (float4*)alloc((size_t)T_G * N_NODES * 16);
    float* er2 = (float*)alloc((size_t)T_G * N_NODES * 4);
    float* h2  = (float*)alloc((size_t)N_NODES * 3 * 4);
    float4* row3 = (float4*)alloc((size_t)T_G * N_NODES * 16);
    float* er3 = (float*)alloc((size_t)T_G * N_NODES * 4);
    float* h3  = (float*)alloc((size_t)N_NODES * 3 * 4);
    float* hM  = (float*)alloc((size_t)N_NODES * 24 * 4);
    float* norms = (float*)alloc((size_t)H_M * N_NODES * 4);
    float* medpair = (float*)alloc(64);
    float* wbuf = (float*)alloc(512);
    int* deg    = (int*)alloc((size_t)T_G * N_NODES * 4);
    int* rowptr = (int*)alloc((size_t)T_G * N_NODES * 4);
    int* hist   = (int*)alloc((size_t)T_G * HTOT * 4);       // 307KB
    int* csr_src = (int*)alloc((size_t)T_G * N_EDGES * 4);
    unsigned int* hist1 = (unsigned int*)alloc((size_t)H_M * 65536 * 4);
    unsigned int* hist2 = (unsigned int*)alloc((size_t)H_M * 2 * 65536 * 4);
    int* selbin  = (int*)alloc(64);
    int* resrank = (int*)alloc(64);

    const int NB = (N_NODES + 255) / 256;   // 196
    const int NW = (N_NODES + 3) / 4;       // 12500
    const int NG = N_NODES / 16;            // 3125 (16 nodes per block)
    const int NE8 = (N_NODES * H_M + 255) / 256;

    hipMemsetAsync(hist1, 0, (size_t)H_M * 65536 * 4, stream);
    hipMemsetAsync(hist2, 0, (size_t)H_M * 2 * 65536 * 4, stream);

    k_wvec<<<1, 128, 0, stream>>>(fc2, fc3, b1, b2, b3, bM, wbuf);
    k_init_all<<<(N_NODES * 24 + 255) / 256, 256, 0, stream>>>(wbuf, h2, h3, hM);

    // Bucketed CSR build (no global atomics)
    k_bcount<<<dim3(NCHK, T_G), 256, 0, stream>>>(edges, hist);
    k_bscan<<<T_G, 1024, 0, stream>>>(hist);
    k_bscatter<<<dim3(NCHK, T_G), 256, 0, stream>>>(edges, hist, bedge);
    k_bfinal<<<dim3(NBKT, T_G), 512, 0, stream>>>(hist, bedge, deg, rowptr, csr_src);

    // Layer 1 (MFMA GEMM with fused h1 bias-init; packed-math fused softmax/gather)
    k_gemm1<<<dim3(N_NODES / 16, T_G), 256, 0, stream>>>(x, W1, al1, ar1, wbuf, feat1, el1, er1, h1);
    k_sg1<<<dim3(NW, T_G), 256, 0, stream>>>(feat1, el1, er1, rowptr, deg, csr_src, h1);

    // Layer 2 (fused softmax+gather, 4 nodes/wave)
    k_feat2<<<NB, 256, 0, stream>>>(h1, W2, al2, ar2, row2, er2);
    k_gat3f<<<dim3(NG, T_G), 256, 0, stream>>>(row2, er2, rowptr, deg, csr_src, wbuf + 0, h2);

    // Layer 3 (fused)
    k_feat3<<<NB, 256, 0, stream>>>(h2, W3, al3, ar3, row3, er3);
    k_gat3f<<<dim3(NG, T_G), 256, 0, stream>>>(row3, er3, rowptr, deg, csr_src, wbuf + 4, h3);

    // Layer M (fused; rowM/erM alias feat1 region — feat1 dead after k_sg1)
    k_featM<<<NB, 256, 0, stream>>>(h3, WM, alM, arM, rowM, erM);
    k_aggMf<<<dim3(NW, T_G), 256, 0, stream>>>(rowM, erM, rowptr, deg, csr_src, wbuf + 4, hM);

    // norm_ (telescoped): parallel exact median via 2-level histogram select
    k_norms<<<NE8, 256, 0, stream>>>(hM, norms, hist1);
    k_findbin<<<16, 256, 0, stream>>>(hist1, selbin, resrank);
    k_h2<<<NE8, 256, 0, stream>>>(norms, selbin, hist2);
    k_findval<<<16, 256, 0, stream>>>(hist2, selbin, resrank, medpair);
    k_final<<<(N_NODES * 24 + 255) / 256, 256, 0, stream>>>(hM, medpair, noise, out);
}

// Round 20
// 569.150 us; speedup vs baseline: 1.1103x; 1.0296x over previous
//
#include <hip/hip_runtime.h>
#include <hip/hip_bf16.h>
#include <math.h>

#define N_NODES 50000
#define N_EDGES 800000
#define T_G 4
#define IN_F 128
#define HID_F 64
#define OUT_F 3
#define H_M 8

// bucketed CSR build params
#define BSH 9
#define NBKT 98            // ceil(50000 / 512)
#define CHK 4096
#define NCHK 196           // ceil(800000 / 4096)
#define HTOT (NBKT * NCHK) // 19208

typedef short bf16x8 __attribute__((ext_vector_type(8)));
typedef float f32x4 __attribute__((ext_vector_type(4)));
typedef float f32x2 __attribute__((ext_vector_type(2)));

__device__ __forceinline__ float lrelu(float v) { return v > 0.f ? v : 0.2f * v; }

__device__ __forceinline__ float wred_sum(float v) {
#pragma unroll
    for (int o = 32; o; o >>= 1) v += __shfl_xor(v, o);
    return v;
}
__device__ __forceinline__ float bf2f(unsigned int u) {
    return __uint_as_float(u << 16);
}
__device__ __forceinline__ f32x2 bfpair(unsigned int u) {
    f32x2 r;
    r.x = __uint_as_float(u << 16);
    r.y = __uint_as_float(u & 0xFFFF0000u);
    return r;
}
__device__ __forceinline__ short f2bf(float f) {  // RNE f32->bf16 bits
    unsigned u = __float_as_uint(f);
    u += 0x7FFF + ((u >> 16) & 1);
    return (short)(u >> 16);
}

// ---- weight/bias precompute:
// w[0:4]=w2, [4:8]=w3, [8:11]=cb2, [11:14]=cb3, [16:40]=cbM, [64:128]=bavg1
__global__ void k_wvec(const float* __restrict__ fc2, const float* __restrict__ fc3,
                       const float* __restrict__ b1, const float* __restrict__ b2,
                       const float* __restrict__ b3, const float* __restrict__ bM,
                       float* __restrict__ w) {
    __shared__ float w2[4], w3[4];
    int i = threadIdx.x;
    if (i < 4) {
        float a = 0.f, b = 0.f;
        for (int r = 0; r < T_G; r++) { a += fc2[r * T_G + i]; b += fc3[r * T_G + i]; }
        w2[i] = 0.25f * a; w3[i] = 0.25f * b;
        w[i] = w2[i]; w[4 + i] = w3[i];
    }
    __syncthreads();
    if (i < 3) {
        float c = 0.f;
        for (int t = 0; t < T_G; t++) c += w2[t] * b2[t * 3 + i];
        w[8 + i] = c;
    }
    if (i >= 8 && i < 11) {
        int d = i - 8;
        float c = 0.f;
        for (int t = 0; t < T_G; t++) c += w3[t] * b3[t * 3 + d];
        w[11 + d] = c;
    }
    if (i >= 16 && i < 40) {
        int j = i - 16;
        float c = 0.f;
        for (int t = 0; t < T_G; t++) c += w3[t] * bM[t * 24 + j];
        w[16 + j] = c;
    }
    if (i >= 64 && i < 128) {
        int c = i - 64;
        w[i] = 0.25f * (b1[c] + b1[HID_F + c] + b1[2 * HID_F + c] + b1[3 * HID_F + c]);
    }
}

// ---- init of pre-biased accumulators (h1 handled by k_gemm1 t==0 blocks)
__global__ void k_init_all(const float* __restrict__ w, float* __restrict__ h2,
                           float* __restrict__ h3, float* __restrict__ hM) {
    int i = blockIdx.x * 256 + threadIdx.x;
    if (i < N_NODES * 3) { h2[i] = w[8 + i % 3]; h3[i] = w[11 + i % 3]; }
    if (i < N_NODES * 24) hM[i] = w[16 + i % 24];
}

// ---- layer-1 GEMM via MFMA: block = 16 nodes x 64 cols x one t; wave = 16-col tile.
//      t==0 blocks also write the bias-init of h1 (coalesced, same pattern as feat1)
__global__ __launch_bounds__(256) void k_gemm1(
    const float* __restrict__ x, const float* __restrict__ W1,
    const float* __restrict__ al1, const float* __restrict__ ar1,
    const float* __restrict__ wbuf,
    __hip_bfloat16* __restrict__ feat1, float* __restrict__ el1, float* __restrict__ er1,
    float* __restrict__ h1) {
    __shared__ float tile[16][HID_F];
    int t = blockIdx.y;
    int base = blockIdx.x * 16;
    int w = threadIdx.x >> 6, lane = threadIdx.x & 63;
    int lr = lane & 15, lk = lane >> 4;
    const float* xrow = x + (size_t)(base + lr) * IN_F;
    const float* Wt = W1 + (size_t)t * IN_F * HID_F;
    f32x4 acc = {0.f, 0.f, 0.f, 0.f};
#pragma unroll
    for (int ks = 0; ks < 4; ks++) {
        int k0 = ks * 32 + lk * 8;
        const float4* xp = (const float4*)(xrow + k0);
        float4 v0 = xp[0], v1 = xp[1];
        bf16x8 a, b;
        a[0] = f2bf(v0.x); a[1] = f2bf(v0.y); a[2] = f2bf(v0.z); a[3] = f2bf(v0.w);
        a[4] = f2bf(v1.x); a[5] = f2bf(v1.y); a[6] = f2bf(v1.z); a[7] = f2bf(v1.w);
#pragma unroll
        for (int j = 0; j < 8; j++) b[j] = f2bf(Wt[(k0 + j) * HID_F + w * 16 + lr]);
        acc = __builtin_amdgcn_mfma_f32_16x16x32_bf16(a, b, acc, 0, 0, 0);
    }
#pragma unroll
    for (int r = 0; r < 4; r++) tile[lk * 4 + r][w * 16 + lr] = acc[r];
    __syncthreads();
#pragma unroll
    for (int q = 0; q < 4; q++) {
        int e = q * 256 + threadIdx.x;
        int node = e >> 6, c = e & 63;
        feat1[((size_t)t * N_NODES + base + node) * HID_F + c] = __float2bfloat16(tile[node][c]);
        if (t == 0) h1[(size_t)(base + node) * HID_F + c] = wbuf[64 + c];
    }
    float alv = al1[t * HID_F + lane], arv = ar1[t * HID_F + lane];
#pragma unroll
    for (int q = 0; q < 4; q++) {
        int node = w * 4 + q;
        float f = tile[node][lane];
        float vl = wred_sum(f * alv);
        float vr = wred_sum(f * arv);
        if (lane == 0) {
            el1[t * N_NODES + base + node] = vl;
            er1[t * N_NODES + base + node] = vr;
        }
    }
}

// ==== bucketed CSR build (no global atomics, no random HBM RMW) ====

__global__ __launch_bounds__(256) void k_bcount(const int* __restrict__ edges,
                                                int* __restrict__ hist) {
    int t = blockIdx.y, c = blockIdx.x;
    __shared__ int hl[NBKT];
    if (threadIdx.x < NBKT) hl[threadIdx.x] = 0;
    __syncthreads();
    const int* dst = edges + (t * 2 + 1) * N_EDGES;
    int e0 = c * CHK, e1 = min(e0 + CHK, N_EDGES);
    for (int i = e0 + threadIdx.x; i < e1; i += 256)
        atomicAdd(&hl[dst[i] >> BSH], 1);
    __syncthreads();
    if (threadIdx.x < NBKT) hist[t * HTOT + threadIdx.x * NCHK + c] = hl[threadIdx.x];
}

__global__ __launch_bounds__(1024) void k_bscan(int* __restrict__ hist) {
    int t = blockIdx.x;
    int* H = hist + t * HTOT;
    __shared__ int ws[16];
    __shared__ int carry;
    if (threadIdx.x == 0) carry = 0;
    __syncthreads();
    int lane = threadIdx.x & 63, wid = threadIdx.x >> 6;
    for (int base = 0; base < HTOT; base += 1024) {
        int i = base + threadIdx.x;
        int v = (i < HTOT) ? H[i] : 0;
        int sc = v;
#pragma unroll
        for (int o = 1; o < 64; o <<= 1) { int u = __shfl_up(sc, o); if (lane >= o) sc += u; }
        if (lane == 63) ws[wid] = sc;
        __syncthreads();
        if (wid == 0 && lane < 16) {
            int wv = ws[lane];
#pragma unroll
            for (int o = 1; o < 16; o <<= 1) { int u = __shfl_up(wv, o); if (lane >= o) wv += u; }
            ws[lane] = wv;
        }
        __syncthreads();
        int woff = (wid == 0) ? 0 : ws[wid - 1];
        if (i < HTOT) H[i] = carry + woff + sc - v;  // exclusive
        int tot = ws[15];
        __syncthreads();
        if (threadIdx.x == 0) carry += tot;
        __syncthreads();
    }
}

__global__ __launch_bounds__(256) void k_bscatter(const int* __restrict__ edges,
                                                  const int* __restrict__ hist,
                                                  int2* __restrict__ bedge) {
    int t = blockIdx.y, c = blockIdx.x;
    __shared__ int cur[NBKT];
    if (threadIdx.x < NBKT) cur[threadIdx.x] = hist[t * HTOT + threadIdx.x * NCHK + c];
    __syncthreads();
    const int* srcp = edges + (t * 2 + 0) * N_EDGES;
    const int* dstp = edges + (t * 2 + 1) * N_EDGES;
    int2* be = bedge + (size_t)t * N_EDGES;
    int e0 = c * CHK, e1 = min(e0 + CHK, N_EDGES);
    for (int i = e0 + threadIdx.x; i < e1; i += 256) {
        int d = dstp[i], s = srcp[i];
        int pos = atomicAdd(&cur[d >> BSH], 1);
        be[pos] = make_int2(s, d);
    }
}

__global__ __launch_bounds__(512) void k_bfinal(const int* __restrict__ hist,
                                                const int2* __restrict__ bedge,
                                                int* __restrict__ deg, int* __restrict__ rowptr,
                                                int* __restrict__ csr_src) {
    int t = blockIdx.y, b = blockIdx.x;
    int n0 = b << BSH;
    int nn = min(512, N_NODES - n0);
    __shared__ int degl[512], curl[512], ws[8];
    degl[threadIdx.x] = 0;
    __syncthreads();
    int base = hist[t * HTOT + b * NCHK];
    int end  = (b == NBKT - 1) ? N_EDGES : hist[t * HTOT + (b + 1) * NCHK];
    const int2* be = bedge + (size_t)t * N_EDGES;
    for (int e = base + threadIdx.x; e < end; e += 512)
        atomicAdd(&degl[be[e].y - n0], 1);
    __syncthreads();
    int v = degl[threadIdx.x];
    int lane = threadIdx.x & 63, wid = threadIdx.x >> 6;
    int sc = v;
#pragma unroll
    for (int o = 1; o < 64; o <<= 1) { int u = __shfl_up(sc, o); if (lane >= o) sc += u; }
    if (lane == 63) ws[wid] = sc;
    __syncthreads();
    if (wid == 0 && lane < 8) {
        int wv = ws[lane];
#pragma unroll
        for (int o = 1; o < 8; o <<= 1) { int u = __shfl_up(wv, o); if (lane >= o) wv += u; }
        ws[lane] = wv;
    }
    __syncthreads();
    int excl = ((wid == 0) ? 0 : ws[wid - 1]) + sc - v;
    if (threadIdx.x < nn) {
        rowptr[t * N_NODES + n0 + threadIdx.x] = base + excl;
        deg[t * N_NODES + n0 + threadIdx.x] = v;
    }
    curl[threadIdx.x] = base + excl;
    __syncthreads();
    for (int e = base + threadIdx.x; e < end; e += 512) {
        int2 ed = be[e];
        int pos = atomicAdd(&curl[ed.y - n0], 1);
        csr_src[t * N_EDGES + pos] = ed.x;
    }
}

// ---- fused layer-1 softmax+gather, 2 NODES PER WAVE, 4-chain ILP:
//      lane = (node-half nh, g in [0,4), octant i in [0,8));
//      16 edge slots/node/iter from 4 independent chains; butterfly over g only
__global__ __launch_bounds__(256) void k_sg1(
    const __hip_bfloat16* __restrict__ feat1, const float* __restrict__ el1,
    const float* __restrict__ er1, const int* __restrict__ rowptr,
    const int* __restrict__ deg, const int* __restrict__ cs_all,
    float* __restrict__ h1) {
    __shared__ float xfer[8][HID_F];
    int t = blockIdx.y;
    int w = threadIdx.x >> 6;
    int lane = threadIdx.x & 63;
    int nh = lane >> 5, sub = lane & 31;
    int g = sub >> 3, i = sub & 7;
    int n = blockIdx.x * 8 + w * 2 + nh;
    int beg = rowptr[t * N_NODES + n], cnt = deg[t * N_NODES + n];
    if (cnt > 0) {  // half-wave-uniform condition
        const int* cs = cs_all + t * N_EDGES + beg;
        const float* el = el1 + t * N_NODES;
        float ern = er1[t * N_NODES + n];
        const unsigned short* ft = (const unsigned short*)feat1 + (size_t)t * N_NODES * HID_F;
        f32x2 acc2[4];
#pragma unroll
        for (int j = 0; j < 4; j++) acc2[j] = (f32x2){0.f, 0.f};
        float sacc = 0.f;
        for (int c0 = 0; c0 < cnt; c0 += 16) {
            int e0 = c0 + g, e1 = c0 + 4 + g, e2 = c0 + 8 + g, e3 = c0 + 12 + g;
            bool v0 = e0 < cnt, v1 = e1 < cnt, v2 = e2 < cnt, v3 = e3 < cnt;
            int s0 = cs[v0 ? e0 : 0];
            int s1 = cs[v1 ? e1 : 0];
            int s2 = cs[v2 ? e2 : 0];
            int s3 = cs[v3 ? e3 : 0];
            float p0 = v0 ? __expf(lrelu(el[s0] + ern)) : 0.f;
            float p1 = v1 ? __expf(lrelu(el[s1] + ern)) : 0.f;
            float p2 = v2 ? __expf(lrelu(el[s2] + ern)) : 0.f;
            float p3 = v3 ? __expf(lrelu(el[s3] + ern)) : 0.f;
            uint4 u0 = *(const uint4*)(ft + (size_t)s0 * HID_F + i * 8);
            uint4 u1 = *(const uint4*)(ft + (size_t)s1 * HID_F + i * 8);
            uint4 u2 = *(const uint4*)(ft + (size_t)s2 * HID_F + i * 8);
            uint4 u3 = *(const uint4*)(ft + (size_t)s3 * HID_F + i * 8);
            f32x2 pv0 = {p0, p0}, pv1 = {p1, p1}, pv2 = {p2, p2}, pv3 = {p3, p3};
            acc2[0] += pv0 * bfpair(u0.x) + pv1 * bfpair(u1.x);
            acc2[1] += pv0 * bfpair(u0.y) + pv1 * bfpair(u1.y);
            acc2[2] += pv0 * bfpair(u0.z) + pv1 * bfpair(u1.z);
            acc2[3] += pv0 * bfpair(u0.w) + pv1 * bfpair(u1.w);
            acc2[0] += pv2 * bfpair(u2.x) + pv3 * bfpair(u3.x);
            acc2[1] += pv2 * bfpair(u2.y) + pv3 * bfpair(u3.y);
            acc2[2] += pv2 * bfpair(u2.z) + pv3 * bfpair(u3.z);
            acc2[3] += pv2 * bfpair(u2.w) + pv3 * bfpair(u3.w);
            sacc += (p0 + p1) + (p2 + p3);
        }
        float acc[8];
#pragma unroll
        for (int j = 0; j < 4; j++) { acc[2 * j] = acc2[j].x; acc[2 * j + 1] = acc2[j].y; }
#pragma unroll
        for (int o = 8; o < 32; o <<= 1) {  // reduce over g only (bits 3,4)
#pragma unroll
            for (int j = 0; j < 8; j++) acc[j] += __shfl_xor(acc[j], o);
            sacc += __shfl_xor(sacc, o);
        }
        if (g == 0) {
            float inv = 0.25f / sacc;
#pragma unroll
            for (int j = 0; j < 8; j++) xfer[w * 2 + nh][i * 8 + j] = acc[j] * inv;
        }
    }
    __syncthreads();
    if (cnt > 0) {
        atomicAdd(&h1[(size_t)n * HID_F + sub], xfer[w * 2 + nh][sub]);
        atomicAdd(&h1[(size_t)n * HID_F + sub + 32], xfer[w * 2 + nh][sub + 32]);
    }
}

// ---- layer-2 featurization: packed row2[t][n] = float4(f0,f1,f2,el); er2 separate
__global__ __launch_bounds__(256) void k_feat2(
    const float* __restrict__ h1, const float* __restrict__ W2,
    const float* __restrict__ al2, const float* __restrict__ ar2,
    float4* __restrict__ row2, float* __restrict__ er2) {
    __shared__ float Wl[T_G * HID_F * OUT_F];
    __shared__ float Al[T_G * OUT_F], Ar[T_G * OUT_F];
    for (int i = threadIdx.x; i < T_G * HID_F * OUT_F; i += 256) Wl[i] = W2[i];
    if (threadIdx.x < T_G * OUT_F) { Al[threadIdx.x] = al2[threadIdx.x]; Ar[threadIdx.x] = ar2[threadIdx.x]; }
    __syncthreads();
    int n = blockIdx.x * 256 + threadIdx.x;
    if (n >= N_NODES) return;
    float h[HID_F];
    const float4* hp = (const float4*)(h1 + n * HID_F);
#pragma unroll
    for (int i = 0; i < 16; i++) {
        float4 v = hp[i];
        h[4 * i] = v.x; h[4 * i + 1] = v.y; h[4 * i + 2] = v.z; h[4 * i + 3] = v.w;
    }
    for (int t = 0; t < T_G; t++) {
        float f0 = 0.f, f1 = 0.f, f2 = 0.f;
#pragma unroll
        for (int k = 0; k < HID_F; k++) {
            float hv = h[k];
            f0 += hv * Wl[(t * HID_F + k) * 3 + 0];
            f1 += hv * Wl[(t * HID_F + k) * 3 + 1];
            f2 += hv * Wl[(t * HID_F + k) * 3 + 2];
        }
        float el = f0 * Al[t * 3] + f1 * Al[t * 3 + 1] + f2 * Al[t * 3 + 2];
        row2[t * N_NODES + n] = make_float4(f0, f1, f2, el);
        er2[t * N_NODES + n] = f0 * Ar[t * 3] + f1 * Ar[t * 3 + 1] + f2 * Ar[t * 3 + 2];
    }
}

// ---- fused d=3 aggregation (max-free): 4 nodes per wave, 16 lanes per node,
//      2x-unrolled edge loop, intra-group butterfly, atomicAdd into pre-biased hout
__global__ __launch_bounds__(256) void k_gat3f(
    const float4* __restrict__ row, const float* __restrict__ er_,
    const int* __restrict__ rowptr, const int* __restrict__ deg, const int* __restrict__ csr_src,
    const float* __restrict__ wv, float* __restrict__ hout) {
    int t = blockIdx.y;
    int lane = threadIdx.x & 63;
    int w = threadIdx.x >> 6;
    int nq = lane >> 4, e = lane & 15;
    int n = blockIdx.x * 16 + w * 4 + nq;  // 3125*16 == 50000 exact
    int beg = rowptr[t * N_NODES + n], cnt = deg[t * N_NODES + n];
    if (cnt == 0) return;  // group-uniform (16-lane groups share n)
    float erh = er_[t * N_NODES + n];
    const int* cs = csr_src + t * N_EDGES;
    const float4* rt = row + t * N_NODES;
    float s_run = 0.f, a0 = 0.f, a1 = 0.f, a2 = 0.f;
    for (int idx = e; idx < cnt; idx += 32) {
        int i1 = idx + 16;
        bool v1 = i1 < cnt;
        int s0 = cs[beg + idx];
        int s1 = cs[beg + (v1 ? i1 : idx)];
        float4 r0 = rt[s0];
        float4 r1 = rt[s1];
        float p0 = __expf(lrelu(r0.w + erh));
        float p1 = v1 ? __expf(lrelu(r1.w + erh)) : 0.f;
        a0 += p0 * r0.x + p1 * r1.x;
        a1 += p0 * r0.y + p1 * r1.y;
        a2 += p0 * r0.z + p1 * r1.z;
        s_run += p0 + p1;
    }
#pragma unroll
    for (int o = 1; o < 16; o <<= 1) {  // xor<16 stays within the 16-lane group
        a0 += __shfl_xor(a0, o);
        a1 += __shfl_xor(a1, o);
        a2 += __shfl_xor(a2, o);
        s_run += __shfl_xor(s_run, o);
    }
    if (e < 3) {
        float v = (e == 0) ? a0 : (e == 1) ? a1 : a2;
        atomicAdd(&hout[n * 3 + e], wv[t] * v / s_run);
    }
}

// ---- layer-3 featurization (3->3): packed row3 + er3
__global__ void k_feat3(const float* __restrict__ h2, const float* __restrict__ W3,
                        const float* __restrict__ al3, const float* __restrict__ ar3,
                        float4* __restrict__ row3, float* __restrict__ er3) {
    int n = blockIdx.x * 256 + threadIdx.x;
    if (n >= N_NODES) return;
    float h0 = h2[n * 3], h1v = h2[n * 3 + 1], h2v = h2[n * 3 + 2];
    for (int t = 0; t < T_G; t++) {
        float f[3], el = 0.f, er = 0.f;
#pragma unroll
        for (int d = 0; d < 3; d++) {
            f[d] = h0 * W3[(t * 3 + 0) * 3 + d] + h1v * W3[(t * 3 + 1) * 3 + d] + h2v * W3[(t * 3 + 2) * 3 + d];
            el += f[d] * al3[t * 3 + d];
            er += f[d] * ar3[t * 3 + d];
        }
        row3[t * N_NODES + n] = make_float4(f[0], f[1], f[2], el);
        er3[t * N_NODES + n] = er;
    }
}

// ---- layer-M featurization: rowM[t][n][32] bf16 with [h*4+{0,1,2}]=f, [h*4+3]=el; erM f32
__global__ void k_featM(const float* __restrict__ h3, const float* __restrict__ WM,
                        const float* __restrict__ alM, const float* __restrict__ arM,
                        __hip_bfloat16* __restrict__ rowM, float* __restrict__ erM) {
    int n = blockIdx.x * 256 + threadIdx.x;
    if (n >= N_NODES) return;
    float h0 = h3[n * 3], h1v = h3[n * 3 + 1], h2v = h3[n * 3 + 2];
    for (int t = 0; t < T_G; t++) {
        int nb = t * N_NODES + n;
        size_t rb = (size_t)nb * 32;
#pragma unroll
        for (int hh = 0; hh < H_M; hh++) {
            float el = 0.f, er = 0.f;
#pragma unroll
            for (int d = 0; d < 3; d++) {
                int j = hh * 3 + d;
                float f = h0 * WM[(t * 3 + 0) * 24 + j] + h1v * WM[(t * 3 + 1) * 24 + j] + h2v * WM[(t * 3 + 2) * 24 + j];
                rowM[rb + hh * 4 + d] = __float2bfloat16(f);
                el += f * alM[(t * H_M + hh) * 3 + d];
                er += f * arM[(t * H_M + hh) * 3 + d];
            }
            rowM[rb + hh * 4 + 3] = __float2bfloat16(el);
            erM[nb * 8 + hh] = er;
        }
    }
}

// ---- fused layer-M aggregation (max-free): lane=(eo,h), 2x-unrolled (16 edges/iter),
//      one 8B gather per edge-lane, plain butterfly sums over eo
__global__ __launch_bounds__(256) void k_aggMf(
    const __hip_bfloat16* __restrict__ rowM, const float* __restrict__ erM,
    const int* __restrict__ rowptr, const int* __restrict__ deg, const int* __restrict__ csr_src,
    const float* __restrict__ wv, float* __restrict__ hM) {
    int t = blockIdx.y;
    int n = blockIdx.x * 4 + (threadIdx.x >> 6);
    int lane = threadIdx.x & 63;
    int h = lane & 7, eo = lane >> 3;
    int beg = rowptr[t * N_NODES + n], cnt = deg[t * N_NODES + n];
    if (cnt == 0) return;
    float erh = erM[(t * N_NODES + n) * 8 + h];
    const int* cs = csr_src + t * N_EDGES;
    const unsigned short* rt = (const unsigned short*)rowM + (size_t)t * N_NODES * 32;
    float s_run = 0.f, a0 = 0.f, a1 = 0.f, a2 = 0.f;
    for (int idx = eo; idx < cnt; idx += 16) {
        int i1 = idx + 8;
        bool v1 = i1 < cnt;
        int s0 = cs[beg + idx];
        int s1 = cs[beg + (v1 ? i1 : idx)];
        ushort4 u0 = *(const ushort4*)(rt + (size_t)s0 * 32 + h * 4);
        ushort4 u1 = *(const ushort4*)(rt + (size_t)s1 * 32 + h * 4);
        float p0 = __expf(lrelu(bf2f(u0.w) + erh));
        float p1 = v1 ? __expf(lrelu(bf2f(u1.w) + erh)) : 0.f;
        a0 += p0 * bf2f(u0.x) + p1 * bf2f(u1.x);
        a1 += p0 * bf2f(u0.y) + p1 * bf2f(u1.y);
        a2 += p0 * bf2f(u0.z) + p1 * bf2f(u1.z);
        s_run += p0 + p1;
    }
#pragma unroll
    for (int o = 8; o < 64; o <<= 1) {
        a0 += __shfl_xor(a0, o);
        a1 += __shfl_xor(a1, o);
        a2 += __shfl_xor(a2, o);
        s_run += __shfl_xor(s_run, o);
    }
    if (eo == 0) {
        float inv = wv[t] / s_run;
        atomicAdd(&hM[n * 24 + h * 3 + 0], inv * a0);
        atomicAdd(&hM[n * 24 + h * 3 + 1], inv * a1);
        atomicAdd(&hM[n * 24 + h * 3 + 2], inv * a2);
    }
}

// ---- delta norms per head + fused top-16-bit histogram
__global__ void k_norms(const float* __restrict__ hM, float* __restrict__ norms,
                        unsigned int* __restrict__ hist1) {
    int idx = blockIdx.x * 256 + threadIdx.x;
    if (idx >= N_NODES * H_M) return;
    int n = idx >> 3, hh = idx & 7;
    float s = 0.f;
#pragma unroll
    for (int d = 0; d < 3; d++) {
        float cur = hM[n * 24 + hh * 3 + d];
        float prev = (n > 0) ? hM[(n - 1) * 24 + hh * 3 + d] : 0.f;
        float dx = cur - prev;
        s += dx * dx;
    }
    float v = sqrtf(s);
    norms[hh * N_NODES + n] = v;
    unsigned int u = __float_as_uint(v);
    atomicAdd(&hist1[hh * 65536 + (u >> 16)], 1u);
}

__device__ __forceinline__ unsigned int blk_exscan(unsigned int v) {
    int lane = threadIdx.x & 63, wid = threadIdx.x >> 6;
    unsigned int sc = v;
#pragma unroll
    for (int o = 1; o < 64; o <<= 1) { unsigned int u = __shfl_up(sc, o); if (lane >= o) sc += u; }
    __shared__ unsigned int ws[4];
    if (lane == 63) ws[wid] = sc;
    __syncthreads();
    unsigned int woff = 0;
    for (int w = 0; w < wid; w++) woff += ws[w];
    __syncthreads();
    return woff + sc - v;
}

__global__ __launch_bounds__(256) void k_findbin(
    const unsigned int* __restrict__ hist1, int* __restrict__ selbin, int* __restrict__ resrank) {
    int hh = blockIdx.x >> 1, k = blockIdx.x & 1;
    unsigned int rank = N_NODES / 2 - 1 + k;  // 24999 / 25000
    const unsigned int* H = hist1 + hh * 65536;
    int tid = threadIdx.x;
    unsigned int local = 0;
    for (int j = 0; j < 256; j++) local += H[tid * 256 + j];
    unsigned int excl = blk_exscan(local);
    if (rank >= excl && rank < excl + local) {
        unsigned int cum = excl;
        for (int j = 0; j < 256; j++) {
            unsigned int c = H[tid * 256 + j];
            if (cum + c > rank) {
                selbin[hh * 2 + k] = tid * 256 + j;
                resrank[hh * 2 + k] = (int)(rank - cum);
                break;
            }
            cum += c;
        }
    }
}

__global__ void k_h2(const float* __restrict__ norms, const int* __restrict__ selbin,
                     unsigned int* __restrict__ hist2) {
    int idx = blockIdx.x * 256 + threadIdx.x;
    if (idx >= N_NODES * H_M) return;
    int hh = idx / N_NODES;
    unsigned int u = __float_as_uint(norms[idx]);
    int top = (int)(u >> 16);
#pragma unroll
    for (int k = 0; k < 2; k++)
        if (top == selbin[hh * 2 + k])
            atomicAdd(&hist2[(hh * 2 + k) * 65536 + (u & 0xFFFFu)], 1u);
}

__global__ __launch_bounds__(256) void k_findval(
    const unsigned int* __restrict__ hist2, const int* __restrict__ selbin,
    const int* __restrict__ resrank, float* __restrict__ medpair) {
    int hh = blockIdx.x >> 1, k = blockIdx.x & 1;
    unsigned int rank = (unsigned int)resrank[hh * 2 + k];
    const unsigned int* H = hist2 + (hh * 2 + k) * 65536;
    int tid = threadIdx.x;
    unsigned int local = 0;
    for (int j = 0; j < 256; j++) local += H[tid * 256 + j];
    unsigned int excl = blk_exscan(local);
    if (rank >= excl && rank < excl + local) {
        unsigned int cum = excl;
        for (int j = 0; j < 256; j++) {
            unsigned int c = H[tid * 256 + j];
            if (cum + c > rank) {
                unsigned int u = ((unsigned int)selbin[hh * 2 + k] << 16) | (unsigned int)(tid * 256 + j);
                medpair[hh * 2 + k] = __uint_as_float(u);
                break;
            }
            cum += c;
        }
    }
}

__global__ void k_final(const float* __restrict__ hM, const float* __restrict__ medpair,
                        const float* __restrict__ noise, float* __restrict__ out) {
    int idx = blockIdx.x * 256 + threadIdx.x;
    if (idx >= N_NODES * 24) return;
    int hh = (idx / 3) & 7;
    float med = 0.5f * (medpair[hh * 2] + medpair[hh * 2 + 1]) + 1e-4f;
    float v = hM[idx] / med;
    if (isnan(v)) v = 0.f;
    else if (isinf(v)) v = v > 0.f ? 100.f : -100.f;
    out[idx] = v + 0.3f * noise[idx];
}

extern "C" void kernel_launch(void* const* d_in, const int* in_sizes, int n_in,
                              void* d_out, int out_size, void* d_ws, size_t ws_size,
                              hipStream_t stream) {
    const float* x     = (const float*)d_in[0];
    const int*   edges = (const int*)d_in[1];
    const float* noise = (const float*)d_in[2];
    const float* W1  = (const float*)d_in[3];
    const float* al1 = (const float*)d_in[4];
    const float* ar1 = (const float*)d_in[5];
    const float* b1  = (const float*)d_in[6];
    const float* W2  = (const float*)d_in[7];
    const float* al2 = (const float*)d_in[8];
    const float* ar2 = (const float*)d_in[9];
    const float* b2  = (const float*)d_in[10];
    const float* W3  = (const float*)d_in[11];
    const float* al3 = (const float*)d_in[12];
    const float* ar3 = (const float*)d_in[13];
    const float* b3  = (const float*)d_in[14];
    const float* WM  = (const float*)d_in[15];
    const float* alM = (const float*)d_in[16];
    const float* arM = (const float*)d_in[17];
    const float* bM  = (const float*)d_in[18];
    const float* fc2 = (const float*)d_in[19];
    const float* fc3 = (const float*)d_in[20];
    float* out = (float*)d_out;

    char* basep = (char*)d_ws;
    size_t off = 0;
    auto alloc = [&](size_t bytes) -> void* {
        void* p = basep + off;
        off += (bytes + 255) & ~(size_t)255;
        return p;
    };
    // Region A: feat1 bf16 (25.6 MB); rowM (12.8) + erM (6.4) alias it after k_sg1
    char* regA = (char*)alloc((size_t)T_G * N_NODES * HID_F * 2);
    __hip_bfloat16* feat1 = (__hip_bfloat16*)regA;
    __hip_bfloat16* rowM  = (__hip_bfloat16*)regA;                 // T*N*32 bf16 = 12.8MB
    float*          erM   = (float*)(regA + 12800000);             // T*N*8 f32 = 6.4MB
    // Region U (25.6MB): bedge (int2, CSR build only)
    char* regU = (char*)alloc((size_t)T_G * N_EDGES * 8);
    int2*  bedge = (int2*)regU;
    float* el1 = (float*)alloc((size_t)T_G * N_NODES * 4);
    float* er1 = (float*)alloc((size_t)T_G * N_NODES * 4);
    float* h1  = (float*)alloc((size_t)N_NODES * HID_F * 4);
    float4* row2 = (float4*)alloc((size_t)T_G * N_NODES * 16);
    float* er2 = (float*)alloc((size_t)T_G * N_NODES * 4);
    float* h2  = (float*)alloc((size_t)N_NODES * 3 * 4);
    float4* row3 = (float4*)alloc((size_t)T_G * N_NODES * 16);
    float* er3 = (float*)alloc((size_t)T_G * N_NODES * 4);
    float* h3  = (float*)alloc((size_t)N_NODES * 3 * 4);
    float* hM  = (float*)alloc((size_t)N_NODES * 24 * 4);
    float* norms = (float*)alloc((size_t)H_M * N_NODES * 4);
    float* medpair = (float*)alloc(64);
    float* wbuf = (float*)alloc(512);
    int* deg    = (int*)alloc((size_t)T_G * N_NODES * 4);
    int* rowptr = (int*)alloc((size_t)T_G * N_NODES * 4);
    int* hist   = (int*)alloc((size_t)T_G * HTOT * 4);       // 307KB
    int* csr_src = (int*)alloc((size_t)T_G * N_EDGES * 4);
    unsigned int* hist1 = (unsigned int*)alloc((size_t)H_M * 65536 * 4);
    unsigned int* hist2 = (unsigned int*)alloc((size_t)H_M * 2 * 65536 * 4);
    int* selbin  = (int*)alloc(64);
    int* resrank = (int*)alloc(64);

    const int NB = (N_NODES + 255) / 256;   // 196
    const int NW8 = N_NODES / 8;            // 6250 (8 nodes per block, 2 per wave)
    const int NG = N_NODES / 16;            // 3125 (16 nodes per block)
    const int NW = (N_NODES + 3) / 4;       // 12500 (4 nodes per block, 1 per wave)
    const int NE8 = (N_NODES * H_M + 255) / 256;

    hipMemsetAsync(hist1, 0, (size_t)H_M * 65536 * 4, stream);
    hipMemsetAsync(hist2, 0, (size_t)H_M * 2 * 65536 * 4, stream);

    k_wvec<<<1, 128, 0, stream>>>(fc2, fc3, b1, b2, b3, bM, wbuf);
    k_init_all<<<(N_NODES * 24 + 255) / 256, 256, 0, stream>>>(wbuf, h2, h3, hM);

    // Bucketed CSR build (no global atomics)
    k_bcount<<<dim3(NCHK, T_G), 256, 0, stream>>>(edges, hist);
    k_bscan<<<T_G, 1024, 0, stream>>>(hist);
    k_bscatter<<<dim3(NCHK, T_G), 256, 0, stream>>>(edges, hist, bedge);
    k_bfinal<<<dim3(NBKT, T_G), 512, 0, stream>>>(hist, bedge, deg, rowptr, csr_src);

    // Layer 1 (MFMA GEMM with fused h1 bias-init; 2-node/wave fused softmax/gather)
    k_gemm1<<<dim3(N_NODES / 16, T_G), 256, 0, stream>>>(x, W1, al1, ar1, wbuf, feat1, el1, er1, h1);
    k_sg1<<<dim3(NW8, T_G), 256, 0, stream>>>(feat1, el1, er1, rowptr, deg, csr_src, h1);

    // Layer 2 (fused softmax+gather, 4 nodes/wave)
    k_feat2<<<NB, 256, 0, stream>>>(h1, W2, al2, ar2, row2, er2);
    k_gat3f<<<dim3(NG, T_G), 256, 0, stream>>>(row2, er2, rowptr, deg, csr_src, wbuf + 0, h2);

    // Layer 3 (fused)
    k_feat3<<<NB, 256, 0, stream>>>(h2, W3, al3, ar3, row3, er3);
    k_gat3f<<<dim3(NG, T_G), 256, 0, stream>>>(row3, er3, rowptr, deg, csr_src, wbuf + 4, h3);

    // Layer M (fused; rowM/erM alias feat1 region — feat1 dead after k_sg1)
    k_featM<<<NB, 256, 0, stream>>>(h3, WM, alM, arM, rowM, erM);
    k_aggMf<<<dim3(NW, T_G), 256, 0, stream>>>(rowM, erM, rowptr, deg, csr_src, wbuf + 4, hM);

    // norm_ (telescoped): parallel exact median via 2-level histogram select
    k_norms<<<NE8, 256, 0, stream>>>(hM, norms, hist1);
    k_findbin<<<16, 256, 0, stream>>>(hist1, selbin, resrank);
    k_h2<<<NE8, 256, 0, stream>>>(norms, selbin, hist2);
    k_findval<<<16, 256, 0, stream>>>(hist2, selbin, resrank, medpair);
    k_final<<<(N_NODES * 24 + 255) / 256, 256, 0, stream>>>(hM, medpair, noise, out);
}

// Round 21
// 454.200 us; speedup vs baseline: 1.3913x; 1.2531x over previous
//
#include <hip/hip_runtime.h>
#include <hip/hip_bf16.h>
#include <math.h>

#define N_NODES 50000
#define N_EDGES 800000
#define T_G 4
#define IN_F 128
#define HID_F 64
#define OUT_F 3
#define H_M 8

// bucketed CSR build params
#define BSH 9
#define NBKT 98            // ceil(50000 / 512)
#define CHK 4096
#define NCHK 196           // ceil(800000 / 4096)
#define HTOT (NBKT * NCHK) // 19208

typedef short bf16x8 __attribute__((ext_vector_type(8)));
typedef float f32x4 __attribute__((ext_vector_type(4)));
typedef float f32x2 __attribute__((ext_vector_type(2)));

__device__ __forceinline__ float lrelu(float v) { return v > 0.f ? v : 0.2f * v; }

__device__ __forceinline__ float wred_sum(float v) {
#pragma unroll
    for (int o = 32; o; o >>= 1) v += __shfl_xor(v, o);
    return v;
}
__device__ __forceinline__ float bf2f(unsigned int u) {
    return __uint_as_float(u << 16);
}
__device__ __forceinline__ f32x2 bfpair(unsigned int u) {
    f32x2 r;
    r.x = __uint_as_float(u << 16);
    r.y = __uint_as_float(u & 0xFFFF0000u);
    return r;
}
__device__ __forceinline__ short f2bf(float f) {  // RNE f32->bf16 bits
    unsigned u = __float_as_uint(f);
    u += 0x7FFF + ((u >> 16) & 1);
    return (short)(u >> 16);
}

// ---- weight/bias precompute:
// w[0:4]=w2, [4:8]=w3, [8:11]=cb2, [11:14]=cb3, [16:40]=cbM, [64:128]=bavg1
__global__ void k_wvec(const float* __restrict__ fc2, const float* __restrict__ fc3,
                       const float* __restrict__ b1, const float* __restrict__ b2,
                       const float* __restrict__ b3, const float* __restrict__ bM,
                       float* __restrict__ w) {
    __shared__ float w2[4], w3[4];
    int i = threadIdx.x;
    if (i < 4) {
        float a = 0.f, b = 0.f;
        for (int r = 0; r < T_G; r++) { a += fc2[r * T_G + i]; b += fc3[r * T_G + i]; }
        w2[i] = 0.25f * a; w3[i] = 0.25f * b;
        w[i] = w2[i]; w[4 + i] = w3[i];
    }
    __syncthreads();
    if (i < 3) {
        float c = 0.f;
        for (int t = 0; t < T_G; t++) c += w2[t] * b2[t * 3 + i];
        w[8 + i] = c;
    }
    if (i >= 8 && i < 11) {
        int d = i - 8;
        float c = 0.f;
        for (int t = 0; t < T_G; t++) c += w3[t] * b3[t * 3 + d];
        w[11 + d] = c;
    }
    if (i >= 16 && i < 40) {
        int j = i - 16;
        float c = 0.f;
        for (int t = 0; t < T_G; t++) c += w3[t] * bM[t * 24 + j];
        w[16 + j] = c;
    }
    if (i >= 64 && i < 128) {
        int c = i - 64;
        w[i] = 0.25f * (b1[c] + b1[HID_F + c] + b1[2 * HID_F + c] + b1[3 * HID_F + c]);
    }
}

// ---- init of pre-biased accumulators (h1 handled by k_gemm1 t==0 blocks)
__global__ void k_init_all(const float* __restrict__ w, float* __restrict__ h2,
                           float* __restrict__ h3, float* __restrict__ hM) {
    int i = blockIdx.x * 256 + threadIdx.x;
    if (i < N_NODES * 3) { h2[i] = w[8 + i % 3]; h3[i] = w[11 + i % 3]; }
    if (i < N_NODES * 24) hM[i] = w[16 + i % 24];
}

// ---- layer-1 GEMM via MFMA: block = 16 nodes x 64 cols x one t; wave = 16-col tile.
//      t==0 blocks also write the bias-init of h1 (coalesced, same pattern as feat1)
__global__ __launch_bounds__(256) void k_gemm1(
    const float* __restrict__ x, const float* __restrict__ W1,
    const float* __restrict__ al1, const float* __restrict__ ar1,
    const float* __restrict__ wbuf,
    __hip_bfloat16* __restrict__ feat1, float* __restrict__ el1, float* __restrict__ er1,
    float* __restrict__ h1) {
    __shared__ float tile[16][HID_F];
    int t = blockIdx.y;
    int base = blockIdx.x * 16;
    int w = threadIdx.x >> 6, lane = threadIdx.x & 63;
    int lr = lane & 15, lk = lane >> 4;
    const float* xrow = x + (size_t)(base + lr) * IN_F;
    const float* Wt = W1 + (size_t)t * IN_F * HID_F;
    f32x4 acc = {0.f, 0.f, 0.f, 0.f};
#pragma unroll
    for (int ks = 0; ks < 4; ks++) {
        int k0 = ks * 32 + lk * 8;
        const float4* xp = (const float4*)(xrow + k0);
        float4 v0 = xp[0], v1 = xp[1];
        bf16x8 a, b;
        a[0] = f2bf(v0.x); a[1] = f2bf(v0.y); a[2] = f2bf(v0.z); a[3] = f2bf(v0.w);
        a[4] = f2bf(v1.x); a[5] = f2bf(v1.y); a[6] = f2bf(v1.z); a[7] = f2bf(v1.w);
#pragma unroll
        for (int j = 0; j < 8; j++) b[j] = f2bf(Wt[(k0 + j) * HID_F + w * 16 + lr]);
        acc = __builtin_amdgcn_mfma_f32_16x16x32_bf16(a, b, acc, 0, 0, 0);
    }
#pragma unroll
    for (int r = 0; r < 4; r++) tile[lk * 4 + r][w * 16 + lr] = acc[r];
    __syncthreads();
#pragma unroll
    for (int q = 0; q < 4; q++) {
        int e = q * 256 + threadIdx.x;
        int node = e >> 6, c = e & 63;
        feat1[((size_t)t * N_NODES + base + node) * HID_F + c] = __float2bfloat16(tile[node][c]);
        if (t == 0) h1[(size_t)(base + node) * HID_F + c] = wbuf[64 + c];
    }
    float alv = al1[t * HID_F + lane], arv = ar1[t * HID_F + lane];
#pragma unroll
    for (int q = 0; q < 4; q++) {
        int node = w * 4 + q;
        float f = tile[node][lane];
        float vl = wred_sum(f * alv);
        float vr = wred_sum(f * arv);
        if (lane == 0) {
            el1[t * N_NODES + base + node] = vl;
            er1[t * N_NODES + base + node] = vr;
        }
    }
}

// ==== bucketed CSR build (no global atomics, no random HBM RMW) ====

__global__ __launch_bounds__(256) void k_bcount(const int* __restrict__ edges,
                                                int* __restrict__ hist) {
    int t = blockIdx.y, c = blockIdx.x;
    __shared__ int hl[NBKT];
    if (threadIdx.x < NBKT) hl[threadIdx.x] = 0;
    __syncthreads();
    const int* dst = edges + (t * 2 + 1) * N_EDGES;
    int e0 = c * CHK, e1 = min(e0 + CHK, N_EDGES);
    for (int i = e0 + threadIdx.x; i < e1; i += 256)
        atomicAdd(&hl[dst[i] >> BSH], 1);
    __syncthreads();
    if (threadIdx.x < NBKT) hist[t * HTOT + threadIdx.x * NCHK + c] = hl[threadIdx.x];
}

__global__ __launch_bounds__(1024) void k_bscan(int* __restrict__ hist) {
    int t = blockIdx.x;
    int* H = hist + t * HTOT;
    __shared__ int ws[16];
    __shared__ int carry;
    if (threadIdx.x == 0) carry = 0;
    __syncthreads();
    int lane = threadIdx.x & 63, wid = threadIdx.x >> 6;
    for (int base = 0; base < HTOT; base += 1024) {
        int i = base + threadIdx.x;
        int v = (i < HTOT) ? H[i] : 0;
        int sc = v;
#pragma unroll
        for (int o = 1; o < 64; o <<= 1) { int u = __shfl_up(sc, o); if (lane >= o) sc += u; }
        if (lane == 63) ws[wid] = sc;
        __syncthreads();
        if (wid == 0 && lane < 16) {
            int wv = ws[lane];
#pragma unroll
            for (int o = 1; o < 16; o <<= 1) { int u = __shfl_up(wv, o); if (lane >= o) wv += u; }
            ws[lane] = wv;
        }
        __syncthreads();
        int woff = (wid == 0) ? 0 : ws[wid - 1];
        if (i < HTOT) H[i] = carry + woff + sc - v;  // exclusive
        int tot = ws[15];
        __syncthreads();
        if (threadIdx.x == 0) carry += tot;
        __syncthreads();
    }
}

__global__ __launch_bounds__(256) void k_bscatter(const int* __restrict__ edges,
                                                  const int* __restrict__ hist,
                                                  int2* __restrict__ bedge) {
    int t = blockIdx.y, c = blockIdx.x;
    __shared__ int cur[NBKT];
    if (threadIdx.x < NBKT) cur[threadIdx.x] = hist[t * HTOT + threadIdx.x * NCHK + c];
    __syncthreads();
    const int* srcp = edges + (t * 2 + 0) * N_EDGES;
    const int* dstp = edges + (t * 2 + 1) * N_EDGES;
    int2* be = bedge + (size_t)t * N_EDGES;
    int e0 = c * CHK, e1 = min(e0 + CHK, N_EDGES);
    for (int i = e0 + threadIdx.x; i < e1; i += 256) {
        int d = dstp[i], s = srcp[i];
        int pos = atomicAdd(&cur[d >> BSH], 1);
        be[pos] = make_int2(s, d);
    }
}

__global__ __launch_bounds__(512) void k_bfinal(const int* __restrict__ hist,
                                                const int2* __restrict__ bedge,
                                                int* __restrict__ deg, int* __restrict__ rowptr,
                                                int* __restrict__ csr_src) {
    int t = blockIdx.y, b = blockIdx.x;
    int n0 = b << BSH;
    int nn = min(512, N_NODES - n0);
    __shared__ int degl[512], curl[512], ws[8];
    degl[threadIdx.x] = 0;
    __syncthreads();
    int base = hist[t * HTOT + b * NCHK];
    int end  = (b == NBKT - 1) ? N_EDGES : hist[t * HTOT + (b + 1) * NCHK];
    const int2* be = bedge + (size_t)t * N_EDGES;
    for (int e = base + threadIdx.x; e < end; e += 512)
        atomicAdd(&degl[be[e].y - n0], 1);
    __syncthreads();
    int v = degl[threadIdx.x];
    int lane = threadIdx.x & 63, wid = threadIdx.x >> 6;
    int sc = v;
#pragma unroll
    for (int o = 1; o < 64; o <<= 1) { int u = __shfl_up(sc, o); if (lane >= o) sc += u; }
    if (lane == 63) ws[wid] = sc;
    __syncthreads();
    if (wid == 0 && lane < 8) {
        int wv = ws[lane];
#pragma unroll
        for (int o = 1; o < 8; o <<= 1) { int u = __shfl_up(wv, o); if (lane >= o) wv += u; }
        ws[lane] = wv;
    }
    __syncthreads();
    int excl = ((wid == 0) ? 0 : ws[wid - 1]) + sc - v;
    if (threadIdx.x < nn) {
        rowptr[t * N_NODES + n0 + threadIdx.x] = base + excl;
        deg[t * N_NODES + n0 + threadIdx.x] = v;
    }
    curl[threadIdx.x] = base + excl;
    __syncthreads();
    for (int e = base + threadIdx.x; e < end; e += 512) {
        int2 ed = be[e];
        int pos = atomicAdd(&curl[ed.y - n0], 1);
        csr_src[t * N_EDGES + pos] = ed.x;
    }
}

// ---- fused layer-1 softmax+gather, 2 NODES PER WAVE, 4-chain ILP
__global__ __launch_bounds__(256) void k_sg1(
    const __hip_bfloat16* __restrict__ feat1, const float* __restrict__ el1,
    const float* __restrict__ er1, const int* __restrict__ rowptr,
    const int* __restrict__ deg, const int* __restrict__ cs_all,
    float* __restrict__ h1) {
    __shared__ float xfer[8][HID_F];
    int t = blockIdx.y;
    int w = threadIdx.x >> 6;
    int lane = threadIdx.x & 63;
    int nh = lane >> 5, sub = lane & 31;
    int g = sub >> 3, i = sub & 7;
    int n = blockIdx.x * 8 + w * 2 + nh;
    int beg = rowptr[t * N_NODES + n], cnt = deg[t * N_NODES + n];
    if (cnt > 0) {  // half-wave-uniform condition
        const int* cs = cs_all + t * N_EDGES + beg;
        const float* el = el1 + t * N_NODES;
        float ern = er1[t * N_NODES + n];
        const unsigned short* ft = (const unsigned short*)feat1 + (size_t)t * N_NODES * HID_F;
        f32x2 acc2[4];
#pragma unroll
        for (int j = 0; j < 4; j++) acc2[j] = (f32x2){0.f, 0.f};
        float sacc = 0.f;
        for (int c0 = 0; c0 < cnt; c0 += 16) {
            int e0 = c0 + g, e1 = c0 + 4 + g, e2 = c0 + 8 + g, e3 = c0 + 12 + g;
            bool v0 = e0 < cnt, v1 = e1 < cnt, v2 = e2 < cnt, v3 = e3 < cnt;
            int s0 = cs[v0 ? e0 : 0];
            int s1 = cs[v1 ? e1 : 0];
            int s2 = cs[v2 ? e2 : 0];
            int s3 = cs[v3 ? e3 : 0];
            float p0 = v0 ? __expf(lrelu(el[s0] + ern)) : 0.f;
            float p1 = v1 ? __expf(lrelu(el[s1] + ern)) : 0.f;
            float p2 = v2 ? __expf(lrelu(el[s2] + ern)) : 0.f;
            float p3 = v3 ? __expf(lrelu(el[s3] + ern)) : 0.f;
            uint4 u0 = *(const uint4*)(ft + (size_t)s0 * HID_F + i * 8);
            uint4 u1 = *(const uint4*)(ft + (size_t)s1 * HID_F + i * 8);
            uint4 u2 = *(const uint4*)(ft + (size_t)s2 * HID_F + i * 8);
            uint4 u3 = *(const uint4*)(ft + (size_t)s3 * HID_F + i * 8);
            f32x2 pv0 = {p0, p0}, pv1 = {p1, p1}, pv2 = {p2, p2}, pv3 = {p3, p3};
            acc2[0] += pv0 * bfpair(u0.x) + pv1 * bfpair(u1.x);
            acc2[1] += pv0 * bfpair(u0.y) + pv1 * bfpair(u1.y);
            acc2[2] += pv0 * bfpair(u0.z) + pv1 * bfpair(u1.z);
            acc2[3] += pv0 * bfpair(u0.w) + pv1 * bfpair(u1.w);
            acc2[0] += pv2 * bfpair(u2.x) + pv3 * bfpair(u3.x);
            acc2[1] += pv2 * bfpair(u2.y) + pv3 * bfpair(u3.y);
            acc2[2] += pv2 * bfpair(u2.z) + pv3 * bfpair(u3.z);
            acc2[3] += pv2 * bfpair(u2.w) + pv3 * bfpair(u3.w);
            sacc += (p0 + p1) + (p2 + p3);
        }
        float acc[8];
#pragma unroll
        for (int j = 0; j < 4; j++) { acc[2 * j] = acc2[j].x; acc[2 * j + 1] = acc2[j].y; }
#pragma unroll
        for (int o = 8; o < 32; o <<= 1) {  // reduce over g only (bits 3,4)
#pragma unroll
            for (int j = 0; j < 8; j++) acc[j] += __shfl_xor(acc[j], o);
            sacc += __shfl_xor(sacc, o);
        }
        if (g == 0) {
            float inv = 0.25f / sacc;
#pragma unroll
            for (int j = 0; j < 8; j++) xfer[w * 2 + nh][i * 8 + j] = acc[j] * inv;
        }
    }
    __syncthreads();
    if (cnt > 0) {
        atomicAdd(&h1[(size_t)n * HID_F + sub], xfer[w * 2 + nh][sub]);
        atomicAdd(&h1[(size_t)n * HID_F + sub + 32], xfer[w * 2 + nh][sub + 32]);
    }
}

// ---- layer-2 featurization: packed row2[t][n] = float4(f0,f1,f2,el); er2 separate
__global__ __launch_bounds__(256) void k_feat2(
    const float* __restrict__ h1, const float* __restrict__ W2,
    const float* __restrict__ al2, const float* __restrict__ ar2,
    float4* __restrict__ row2, float* __restrict__ er2) {
    __shared__ float Wl[T_G * HID_F * OUT_F];
    __shared__ float Al[T_G * OUT_F], Ar[T_G * OUT_F];
    for (int i = threadIdx.x; i < T_G * HID_F * OUT_F; i += 256) Wl[i] = W2[i];
    if (threadIdx.x < T_G * OUT_F) { Al[threadIdx.x] = al2[threadIdx.x]; Ar[threadIdx.x] = ar2[threadIdx.x]; }
    __syncthreads();
    int n = blockIdx.x * 256 + threadIdx.x;
    if (n >= N_NODES) return;
    float h[HID_F];
    const float4* hp = (const float4*)(h1 + n * HID_F);
#pragma unroll
    for (int i = 0; i < 16; i++) {
        float4 v = hp[i];
        h[4 * i] = v.x; h[4 * i + 1] = v.y; h[4 * i + 2] = v.z; h[4 * i + 3] = v.w;
    }
    for (int t = 0; t < T_G; t++) {
        float f0 = 0.f, f1 = 0.f, f2 = 0.f;
#pragma unroll
        for (int k = 0; k < HID_F; k++) {
            float hv = h[k];
            f0 += hv * Wl[(t * HID_F + k) * 3 + 0];
            f1 += hv * Wl[(t * HID_F + k) * 3 + 1];
            f2 += hv * Wl[(t * HID_F + k) * 3 + 2];
        }
        float el = f0 * Al[t * 3] + f1 * Al[t * 3 + 1] + f2 * Al[t * 3 + 2];
        row2[t * N_NODES + n] = make_float4(f0, f1, f2, el);
        er2[t * N_NODES + n] = f0 * Ar[t * 3] + f1 * Ar[t * 3 + 1] + f2 * Ar[t * 3 + 2];
    }
}

// ---- fused d=3 aggregation (max-free): 4 nodes per wave, 16 lanes per node,
//      2x-unrolled edge loop, intra-group butterfly, atomicAdd into pre-biased hout
__global__ __launch_bounds__(256) void k_gat3f(
    const float4* __restrict__ row, const float* __restrict__ er_,
    const int* __restrict__ rowptr, const int* __restrict__ deg, const int* __restrict__ csr_src,
    const float* __restrict__ wv, float* __restrict__ hout) {
    int t = blockIdx.y;
    int lane = threadIdx.x & 63;
    int w = threadIdx.x >> 6;
    int nq = lane >> 4, e = lane & 15;
    int n = blockIdx.x * 16 + w * 4 + nq;  // 3125*16 == 50000 exact
    int beg = rowptr[t * N_NODES + n], cnt = deg[t * N_NODES + n];
    if (cnt == 0) return;  // group-uniform (16-lane groups share n)
    float erh = er_[t * N_NODES + n];
    const int* cs = csr_src + t * N_EDGES;
    const float4* rt = row + t * N_NODES;
    float s_run = 0.f, a0 = 0.f, a1 = 0.f, a2 = 0.f;
    for (int idx = e; idx < cnt; idx += 32) {
        int i1 = idx + 16;
        bool v1 = i1 < cnt;
        int s0 = cs[beg + idx];
        int s1 = cs[beg + (v1 ? i1 : idx)];
        float4 r0 = rt[s0];
        float4 r1 = rt[s1];
        float p0 = __expf(lrelu(r0.w + erh));
        float p1 = v1 ? __expf(lrelu(r1.w + erh)) : 0.f;
        a0 += p0 * r0.x + p1 * r1.x;
        a1 += p0 * r0.y + p1 * r1.y;
        a2 += p0 * r0.z + p1 * r1.z;
        s_run += p0 + p1;
    }
#pragma unroll
    for (int o = 1; o < 16; o <<= 1) {  // xor<16 stays within the 16-lane group
        a0 += __shfl_xor(a0, o);
        a1 += __shfl_xor(a1, o);
        a2 += __shfl_xor(a2, o);
        s_run += __shfl_xor(s_run, o);
    }
    if (e < 3) {
        float v = (e == 0) ? a0 : (e == 1) ? a1 : a2;
        atomicAdd(&hout[n * 3 + e], wv[t] * v / s_run);
    }
}

// ---- layer-3 featurization (3->3): packed row3 + er3
__global__ void k_feat3(const float* __restrict__ h2, const float* __restrict__ W3,
                        const float* __restrict__ al3, const float* __restrict__ ar3,
                        float4* __restrict__ row3, float* __restrict__ er3) {
    int n = blockIdx.x * 256 + threadIdx.x;
    if (n >= N_NODES) return;
    float h0 = h2[n * 3], h1v = h2[n * 3 + 1], h2v = h2[n * 3 + 2];
    for (int t = 0; t < T_G; t++) {
        float f[3], el = 0.f, er = 0.f;
#pragma unroll
        for (int d = 0; d < 3; d++) {
            f[d] = h0 * W3[(t * 3 + 0) * 3 + d] + h1v * W3[(t * 3 + 1) * 3 + d] + h2v * W3[(t * 3 + 2) * 3 + d];
            el += f[d] * al3[t * 3 + d];
            er += f[d] * ar3[t * 3 + d];
        }
        row3[t * N_NODES + n] = make_float4(f[0], f[1], f[2], el);
        er3[t * N_NODES + n] = er;
    }
}

// ---- layer-M featurization: rowM[t][n][32] bf16 with [h*4+{0,1,2}]=f, [h*4+3]=el; erM f32
__global__ void k_featM(const float* __restrict__ h3, const float* __restrict__ WM,
                        const float* __restrict__ alM, const float* __restrict__ arM,
                        __hip_bfloat16* __restrict__ rowM, float* __restrict__ erM) {
    int n = blockIdx.x * 256 + threadIdx.x;
    if (n >= N_NODES) return;
    float h0 = h3[n * 3], h1v = h3[n * 3 + 1], h2v = h3[n * 3 + 2];
    for (int t = 0; t < T_G; t++) {
        int nb = t * N_NODES + n;
        size_t rb = (size_t)nb * 32;
#pragma unroll
        for (int hh = 0; hh < H_M; hh++) {
            float el = 0.f, er = 0.f;
#pragma unroll
            for (int d = 0; d < 3; d++) {
                int j = hh * 3 + d;
                float f = h0 * WM[(t * 3 + 0) * 24 + j] + h1v * WM[(t * 3 + 1) * 24 + j] + h2v * WM[(t * 3 + 2) * 24 + j];
                rowM[rb + hh * 4 + d] = __float2bfloat16(f);
                el += f * alM[(t * H_M + hh) * 3 + d];
                er += f * arM[(t * H_M + hh) * 3 + d];
            }
            rowM[rb + hh * 4 + 3] = __float2bfloat16(el);
            erM[nb * 8 + hh] = er;
        }
    }
}

// ---- fused layer-M aggregation (max-free): lane=(eo,h), 2x-unrolled (16 edges/iter)
__global__ __launch_bounds__(256) void k_aggMf(
    const __hip_bfloat16* __restrict__ rowM, const float* __restrict__ erM,
    const int* __restrict__ rowptr, const int* __restrict__ deg, const int* __restrict__ csr_src,
    const float* __restrict__ wv, float* __restrict__ hM) {
    int t = blockIdx.y;
    int n = blockIdx.x * 4 + (threadIdx.x >> 6);
    int lane = threadIdx.x & 63;
    int h = lane & 7, eo = lane >> 3;
    int beg = rowptr[t * N_NODES + n], cnt = deg[t * N_NODES + n];
    if (cnt == 0) return;
    float erh = erM[(t * N_NODES + n) * 8 + h];
    const int* cs = csr_src + t * N_EDGES;
    const unsigned short* rt = (const unsigned short*)rowM + (size_t)t * N_NODES * 32;
    float s_run = 0.f, a0 = 0.f, a1 = 0.f, a2 = 0.f;
    for (int idx = eo; idx < cnt; idx += 16) {
        int i1 = idx + 8;
        bool v1 = i1 < cnt;
        int s0 = cs[beg + idx];
        int s1 = cs[beg + (v1 ? i1 : idx)];
        ushort4 u0 = *(const ushort4*)(rt + (size_t)s0 * 32 + h * 4);
        ushort4 u1 = *(const ushort4*)(rt + (size_t)s1 * 32 + h * 4);
        float p0 = __expf(lrelu(bf2f(u0.w) + erh));
        float p1 = v1 ? __expf(lrelu(bf2f(u1.w) + erh)) : 0.f;
        a0 += p0 * bf2f(u0.x) + p1 * bf2f(u1.x);
        a1 += p0 * bf2f(u0.y) + p1 * bf2f(u1.y);
        a2 += p0 * bf2f(u0.z) + p1 * bf2f(u1.z);
        s_run += p0 + p1;
    }
#pragma unroll
    for (int o = 8; o < 64; o <<= 1) {
        a0 += __shfl_xor(a0, o);
        a1 += __shfl_xor(a1, o);
        a2 += __shfl_xor(a2, o);
        s_run += __shfl_xor(s_run, o);
    }
    if (eo == 0) {
        float inv = wv[t] / s_run;
        atomicAdd(&hM[n * 24 + h * 3 + 0], inv * a0);
        atomicAdd(&hM[n * 24 + h * 3 + 1], inv * a1);
        atomicAdd(&hM[n * 24 + h * 3 + 2], inv * a2);
    }
}

// ---- delta norms per head (no histogram — atomics moved to LDS-privatized k_hist1)
__global__ void k_norms(const float* __restrict__ hM, float* __restrict__ norms) {
    int idx = blockIdx.x * 256 + threadIdx.x;
    if (idx >= N_NODES * H_M) return;
    int n = idx >> 3, hh = idx & 7;
    float s = 0.f;
#pragma unroll
    for (int d = 0; d < 3; d++) {
        float cur = hM[n * 24 + hh * 3 + d];
        float prev = (n > 0) ? hM[(n - 1) * 24 + hh * 3 + d] : 0.f;
        float dx = cur - prev;
        s += dx * dx;
    }
    norms[hh * N_NODES + n] = sqrtf(s);
}

// ---- level-1 histogram: bits [31:20] (4096 bins), LDS-privatized per block.
//      grid (32, 8): blockIdx.y = head, blockIdx.x = node chunk
#define NCHUNK 32
#define CHNK_N ((N_NODES + NCHUNK - 1) / NCHUNK)  // 1563
__global__ __launch_bounds__(256) void k_hist1(const float* __restrict__ norms,
                                               unsigned int* __restrict__ hist1g) {
    __shared__ unsigned int hl[4096];
    int hh = blockIdx.y, c = blockIdx.x;
    for (int j = threadIdx.x; j < 4096; j += 256) hl[j] = 0u;
    __syncthreads();
    int i0 = c * CHNK_N, i1 = min(i0 + CHNK_N, N_NODES);
    const float* v = norms + (size_t)hh * N_NODES;
    for (int i = i0 + threadIdx.x; i < i1; i += 256) {
        unsigned int u = __float_as_uint(v[i]);
        atomicAdd(&hl[u >> 20], 1u);
    }
    __syncthreads();
    unsigned int* Hg = hist1g + (size_t)hh * 4096;
    for (int j = threadIdx.x; j < 4096; j += 256)
        if (hl[j]) atomicAdd(&Hg[j], hl[j]);
}

__device__ __forceinline__ unsigned int blk_exscan(unsigned int v) {
    int lane = threadIdx.x & 63, wid = threadIdx.x >> 6;
    unsigned int sc = v;
#pragma unroll
    for (int o = 1; o < 64; o <<= 1) { unsigned int u = __shfl_up(sc, o); if (lane >= o) sc += u; }
    __shared__ unsigned int ws[4];
    if (lane == 63) ws[wid] = sc;
    __syncthreads();
    unsigned int woff = 0;
    for (int w = 0; w < wid; w++) woff += ws[w];
    __syncthreads();
    return woff + sc - v;
}

// ---- level-1 select among 4096 bins -> selbin1 (bits 31:20), resrank1
__global__ __launch_bounds__(256) void k_find1(
    const unsigned int* __restrict__ hist1g, int* __restrict__ selbin1, int* __restrict__ resrank1) {
    int hh = blockIdx.x >> 1, k = blockIdx.x & 1;
    unsigned int rank = N_NODES / 2 - 1 + k;  // 24999 / 25000
    const unsigned int* H = hist1g + (size_t)hh * 4096;
    int tid = threadIdx.x;
    unsigned int local = 0;
    for (int j = 0; j < 16; j++) local += H[tid * 16 + j];
    unsigned int excl = blk_exscan(local);
    if (rank >= excl && rank < excl + local) {
        unsigned int cum = excl;
        for (int j = 0; j < 16; j++) {
            unsigned int c = H[tid * 16 + j];
            if (cum + c > rank) {
                selbin1[hh * 2 + k] = tid * 16 + j;
                resrank1[hh * 2 + k] = (int)(rank - cum);
                break;
            }
            cum += c;
        }
    }
}

// ---- level-2 histogram: bits [19:4] (65536 bins), restricted to selected top-12 bin
__global__ void k_h2(const float* __restrict__ norms, const int* __restrict__ selbin1,
                     unsigned int* __restrict__ hist2) {
    int idx = blockIdx.x * 256 + threadIdx.x;
    if (idx >= N_NODES * H_M) return;
    int hh = idx / N_NODES;
    unsigned int u = __float_as_uint(norms[idx]);
    int top = (int)(u >> 20);
#pragma unroll
    for (int k = 0; k < 2; k++)
        if (top == selbin1[hh * 2 + k])
            atomicAdd(&hist2[(size_t)(hh * 2 + k) * 65536 + ((u >> 4) & 0xFFFFu)], 1u);
}

// ---- level-2 select among 65536 bins -> selbin2 (bits 19:4), resrank2
__global__ __launch_bounds__(256) void k_find2(
    const unsigned int* __restrict__ hist2, const int* __restrict__ resrank1,
    int* __restrict__ selbin2, int* __restrict__ resrank2) {
    int hh = blockIdx.x >> 1, k = blockIdx.x & 1;
    unsigned int rank = (unsigned int)resrank1[hh * 2 + k];
    const unsigned int* H = hist2 + (size_t)(hh * 2 + k) * 65536;
    int tid = threadIdx.x;
    unsigned int local = 0;
    for (int j = 0; j < 256; j++) local += H[tid * 256 + j];
    unsigned int excl = blk_exscan(local);
    if (rank >= excl && rank < excl + local) {
        unsigned int cum = excl;
        for (int j = 0; j < 256; j++) {
            unsigned int c = H[tid * 256 + j];
            if (cum + c > rank) {
                selbin2[hh * 2 + k] = tid * 256 + j;
                resrank2[hh * 2 + k] = (int)(rank - cum);
                break;
            }
            cum += c;
        }
    }
}

// ---- level-3 histogram: bits [3:0] (16 bins), restricted to selected 28-bit prefix
__global__ void k_h3(const float* __restrict__ norms, const int* __restrict__ selbin1,
                     const int* __restrict__ selbin2, unsigned int* __restrict__ hist3) {
    int idx = blockIdx.x * 256 + threadIdx.x;
    if (idx >= N_NODES * H_M) return;
    int hh = idx / N_NODES;
    unsigned int u = __float_as_uint(norms[idx]);
#pragma unroll
    for (int k = 0; k < 2; k++) {
        unsigned int pref = ((unsigned int)selbin1[hh * 2 + k] << 16) | (unsigned int)selbin2[hh * 2 + k];
        if ((u >> 4) == pref)
            atomicAdd(&hist3[(hh * 2 + k) * 16 + (u & 15u)], 1u);
    }
}

// ---- level-3 select (16 bins) -> exact order statistics
__global__ void k_find3(const unsigned int* __restrict__ hist3, const int* __restrict__ selbin1,
                        const int* __restrict__ selbin2, const int* __restrict__ resrank2,
                        float* __restrict__ medpair) {
    int hh = blockIdx.x >> 1, k = blockIdx.x & 1;
    if (threadIdx.x != 0) return;
    unsigned int rank = (unsigned int)resrank2[hh * 2 + k];
    const unsigned int* H = hist3 + (hh * 2 + k) * 16;
    unsigned int cum = 0;
    for (int b = 0; b < 16; b++) {
        unsigned int c = H[b];
        if (cum + c > rank) {
            unsigned int u = ((unsigned int)selbin1[hh * 2 + k] << 20)
                           | ((unsigned int)selbin2[hh * 2 + k] << 4) | (unsigned int)b;
            medpair[hh * 2 + k] = __uint_as_float(u);
            return;
        }
        cum += c;
    }
}

__global__ void k_final(const float* __restrict__ hM, const float* __restrict__ medpair,
                        const float* __restrict__ noise, float* __restrict__ out) {
    int idx = blockIdx.x * 256 + threadIdx.x;
    if (idx >= N_NODES * 24) return;
    int hh = (idx / 3) & 7;
    float med = 0.5f * (medpair[hh * 2] + medpair[hh * 2 + 1]) + 1e-4f;
    float v = hM[idx] / med;
    if (isnan(v)) v = 0.f;
    else if (isinf(v)) v = v > 0.f ? 100.f : -100.f;
    out[idx] = v + 0.3f * noise[idx];
}

extern "C" void kernel_launch(void* const* d_in, const int* in_sizes, int n_in,
                              void* d_out, int out_size, void* d_ws, size_t ws_size,
                              hipStream_t stream) {
    const float* x     = (const float*)d_in[0];
    const int*   edges = (const int*)d_in[1];
    const float* noise = (const float*)d_in[2];
    const float* W1  = (const float*)d_in[3];
    const float* al1 = (const float*)d_in[4];
    const float* ar1 = (const float*)d_in[5];
    const float* b1  = (const float*)d_in[6];
    const float* W2  = (const float*)d_in[7];
    const float* al2 = (const float*)d_in[8];
    const float* ar2 = (const float*)d_in[9];
    const float* b2  = (const float*)d_in[10];
    const float* W3  = (const float*)d_in[11];
    const float* al3 = (const float*)d_in[12];
    const float* ar3 = (const float*)d_in[13];
    const float* b3  = (const float*)d_in[14];
    const float* WM  = (const float*)d_in[15];
    const float* alM = (const float*)d_in[16];
    const float* arM = (const float*)d_in[17];
    const float* bM  = (const float*)d_in[18];
    const float* fc2 = (const float*)d_in[19];
    const float* fc3 = (const float*)d_in[20];
    float* out = (float*)d_out;

    char* basep = (char*)d_ws;
    size_t off = 0;
    auto alloc = [&](size_t bytes) -> void* {
        void* p = basep + off;
        off += (bytes + 255) & ~(size_t)255;
        return p;
    };
    // Region A: feat1 bf16 (25.6 MB); rowM (12.8) + erM (6.4) alias it after k_sg1
    char* regA = (char*)alloc((size_t)T_G * N_NODES * HID_F * 2);
    __hip_bfloat16* feat1 = (__hip_bfloat16*)regA;
    __hip_bfloat16* rowM  = (__hip_bfloat16*)regA;                 // T*N*32 bf16 = 12.8MB
    float*          erM   = (float*)(regA + 12800000);             // T*N*8 f32 = 6.4MB
    // Region U (25.6MB): bedge (int2, CSR build only)
    char* regU = (char*)alloc((size_t)T_G * N_EDGES * 8);
    int2*  bedge = (int2*)regU;
    float* el1 = (float*)alloc((size_t)T_G * N_NODES * 4);
    float* er1 = (float*)alloc((size_t)T_G * N_NODES * 4);
    float* h1  = (float*)alloc((size_t)N_NODES * HID_F * 4);
    float4* row2 = (float4*)alloc((size_t)T_G * N_NODES * 16);
    float* er2 = (float*)alloc((size_t)T_G * N_NODES * 4);
    float* h2  = (float*)alloc((size_t)N_NODES * 3 * 4);
    float4* row3 = (float4*)alloc((size_t)T_G * N_NODES * 16);
    float* er3 = (float*)alloc((size_t)T_G * N_NODES * 4);
    float* h3  = (float*)alloc((size_t)N_NODES * 3 * 4);
    float* hM  = (float*)alloc((size_t)N_NODES * 24 * 4);
    float* norms = (float*)alloc((size_t)H_M * N_NODES * 4);
    float* medpair = (float*)alloc(64);
    float* wbuf = (float*)alloc(512);
    int* deg    = (int*)alloc((size_t)T_G * N_NODES * 4);
    int* rowptr = (int*)alloc((size_t)T_G * N_NODES * 4);
    int* hist   = (int*)alloc((size_t)T_G * HTOT * 4);       // 307KB
    int* csr_src = (int*)alloc((size_t)T_G * N_EDGES * 4);
    unsigned int* hist1g = (unsigned int*)alloc((size_t)H_M * 4096 * 4);      // 128KB
    unsigned int* hist2 = (unsigned int*)alloc((size_t)H_M * 2 * 65536 * 4);  // 4MB
    unsigned int* hist3 = (unsigned int*)alloc((size_t)H_M * 2 * 16 * 4);     // 1KB
    int* selbin1  = (int*)alloc(64);
    int* resrank1 = (int*)alloc(64);
    int* selbin2  = (int*)alloc(64);
    int* resrank2 = (int*)alloc(64);

    const int NB = (N_NODES + 255) / 256;   // 196
    const int NW8 = N_NODES / 8;            // 6250 (8 nodes per block, 2 per wave)
    const int NG = N_NODES / 16;            // 3125 (16 nodes per block)
    const int NW = (N_NODES + 3) / 4;       // 12500 (4 nodes per block, 1 per wave)
    const int NE8 = (N_NODES * H_M + 255) / 256;

    hipMemsetAsync(hist1g, 0, (size_t)H_M * 4096 * 4, stream);
    hipMemsetAsync(hist2, 0, (size_t)H_M * 2 * 65536 * 4, stream);
    hipMemsetAsync(hist3, 0, (size_t)H_M * 2 * 16 * 4, stream);

    k_wvec<<<1, 128, 0, stream>>>(fc2, fc3, b1, b2, b3, bM, wbuf);
    k_init_all<<<(N_NODES * 24 + 255) / 256, 256, 0, stream>>>(wbuf, h2, h3, hM);

    // Bucketed CSR build (no global atomics)
    k_bcount<<<dim3(NCHK, T_G), 256, 0, stream>>>(edges, hist);
    k_bscan<<<T_G, 1024, 0, stream>>>(hist);
    k_bscatter<<<dim3(NCHK, T_G), 256, 0, stream>>>(edges, hist, bedge);
    k_bfinal<<<dim3(NBKT, T_G), 512, 0, stream>>>(hist, bedge, deg, rowptr, csr_src);

    // Layer 1 (MFMA GEMM with fused h1 bias-init; 2-node/wave fused softmax/gather)
    k_gemm1<<<dim3(N_NODES / 16, T_G), 256, 0, stream>>>(x, W1, al1, ar1, wbuf, feat1, el1, er1, h1);
    k_sg1<<<dim3(NW8, T_G), 256, 0, stream>>>(feat1, el1, er1, rowptr, deg, csr_src, h1);

    // Layer 2 (fused softmax+gather, 4 nodes/wave)
    k_feat2<<<NB, 256, 0, stream>>>(h1, W2, al2, ar2, row2, er2);
    k_gat3f<<<dim3(NG, T_G), 256, 0, stream>>>(row2, er2, rowptr, deg, csr_src, wbuf + 0, h2);

    // Layer 3 (fused)
    k_feat3<<<NB, 256, 0, stream>>>(h2, W3, al3, ar3, row3, er3);
    k_gat3f<<<dim3(NG, T_G), 256, 0, stream>>>(row3, er3, rowptr, deg, csr_src, wbuf + 4, h3);

    // Layer M (fused; rowM/erM alias feat1 region — feat1 dead after k_sg1)
    k_featM<<<NB, 256, 0, stream>>>(h3, WM, alM, arM, rowM, erM);
    k_aggMf<<<dim3(NW, T_G), 256, 0, stream>>>(rowM, erM, rowptr, deg, csr_src, wbuf + 4, hM);

    // norm_ (telescoped): contention-free 3-level exact median select
    k_norms<<<NE8, 256, 0, stream>>>(hM, norms);
    k_hist1<<<dim3(NCHUNK, H_M), 256, 0, stream>>>(norms, hist1g);
    k_find1<<<16, 256, 0, stream>>>(hist1g, selbin1, resrank1);
    k_h2<<<NE8, 256, 0, stream>>>(norms, selbin1, hist2);
    k_find2<<<16, 256, 0, stream>>>(hist2, resrank1, selbin2, resrank2);
    k_h3<<<NE8, 256, 0, stream>>>(norms, selbin1, selbin2, hist3);
    k_find3<<<16, 64, 0, stream>>>(hist3, selbin1, selbin2, resrank2, medpair);
    k_final<<<(N_NODES * 24 + 255) / 256, 256, 0, stream>>>(hM, medpair, noise, out);
}

// Round 22
// 432.542 us; speedup vs baseline: 1.4610x; 1.0501x over previous
//
#include <hip/hip_runtime.h>
#include <hip/hip_bf16.h>
#include <math.h>

#define N_NODES 50000
#define N_EDGES 800000
#define T_G 4
#define IN_F 128
#define HID_F 64
#define OUT_F 3
#define H_M 8

// bucketed CSR build params
#define BSH 9
#define NBKT 98            // ceil(50000 / 512)
#define CHK 4096
#define NCHK 196           // ceil(800000 / 4096)
#define HTOT (NBKT * NCHK) // 19208

typedef short bf16x8 __attribute__((ext_vector_type(8)));
typedef float f32x4 __attribute__((ext_vector_type(4)));
typedef float f32x2 __attribute__((ext_vector_type(2)));

__device__ __forceinline__ float lrelu(float v) { return v > 0.f ? v : 0.2f * v; }

__device__ __forceinline__ float wred_sum(float v) {
#pragma unroll
    for (int o = 32; o; o >>= 1) v += __shfl_xor(v, o);
    return v;
}
__device__ __forceinline__ float bf2f(unsigned int u) {
    return __uint_as_float(u << 16);
}
__device__ __forceinline__ f32x2 bfpair(unsigned int u) {
    f32x2 r;
    r.x = __uint_as_float(u << 16);
    r.y = __uint_as_float(u & 0xFFFF0000u);
    return r;
}
__device__ __forceinline__ short f2bf(float f) {  // RNE f32->bf16 bits
    unsigned u = __float_as_uint(f);
    u += 0x7FFF + ((u >> 16) & 1);
    return (short)(u >> 16);
}

// ---- weight/bias precompute:
// w[0:4]=w2, [4:8]=w3, [8:11]=cb2, [11:14]=cb3, [16:40]=cbM, [64:128]=bavg1
__global__ void k_wvec(const float* __restrict__ fc2, const float* __restrict__ fc3,
                       const float* __restrict__ b1, const float* __restrict__ b2,
                       const float* __restrict__ b3, const float* __restrict__ bM,
                       float* __restrict__ w) {
    __shared__ float w2[4], w3[4];
    int i = threadIdx.x;
    if (i < 4) {
        float a = 0.f, b = 0.f;
        for (int r = 0; r < T_G; r++) { a += fc2[r * T_G + i]; b += fc3[r * T_G + i]; }
        w2[i] = 0.25f * a; w3[i] = 0.25f * b;
        w[i] = w2[i]; w[4 + i] = w3[i];
    }
    __syncthreads();
    if (i < 3) {
        float c = 0.f;
        for (int t = 0; t < T_G; t++) c += w2[t] * b2[t * 3 + i];
        w[8 + i] = c;
    }
    if (i >= 8 && i < 11) {
        int d = i - 8;
        float c = 0.f;
        for (int t = 0; t < T_G; t++) c += w3[t] * b3[t * 3 + d];
        w[11 + d] = c;
    }
    if (i >= 16 && i < 40) {
        int j = i - 16;
        float c = 0.f;
        for (int t = 0; t < T_G; t++) c += w3[t] * bM[t * 24 + j];
        w[16 + j] = c;
    }
    if (i >= 64 && i < 128) {
        int c = i - 64;
        w[i] = 0.25f * (b1[c] + b1[HID_F + c] + b1[2 * HID_F + c] + b1[3 * HID_F + c]);
    }
}

// ---- init of pre-biased accumulators (h1 handled by k_gemm1 t==0 blocks)
__global__ void k_init_all(const float* __restrict__ w, float* __restrict__ h2,
                           float* __restrict__ h3, float* __restrict__ hM) {
    int i = blockIdx.x * 256 + threadIdx.x;
    if (i < N_NODES * 3) { h2[i] = w[8 + i % 3]; h3[i] = w[11 + i % 3]; }
    if (i < N_NODES * 24) hM[i] = w[16 + i % 24];
}

// ---- layer-1 GEMM via MFMA: block = 16 nodes x 64 cols x one t; wave = 16-col tile.
//      t==0 blocks also write the bias-init of h1 (coalesced, same pattern as feat1)
__global__ __launch_bounds__(256) void k_gemm1(
    const float* __restrict__ x, const float* __restrict__ W1,
    const float* __restrict__ al1, const float* __restrict__ ar1,
    const float* __restrict__ wbuf,
    __hip_bfloat16* __restrict__ feat1, float* __restrict__ el1, float* __restrict__ er1,
    float* __restrict__ h1) {
    __shared__ float tile[16][HID_F];
    int t = blockIdx.y;
    int base = blockIdx.x * 16;
    int w = threadIdx.x >> 6, lane = threadIdx.x & 63;
    int lr = lane & 15, lk = lane >> 4;
    const float* xrow = x + (size_t)(base + lr) * IN_F;
    const float* Wt = W1 + (size_t)t * IN_F * HID_F;
    f32x4 acc = {0.f, 0.f, 0.f, 0.f};
#pragma unroll
    for (int ks = 0; ks < 4; ks++) {
        int k0 = ks * 32 + lk * 8;
        const float4* xp = (const float4*)(xrow + k0);
        float4 v0 = xp[0], v1 = xp[1];
        bf16x8 a, b;
        a[0] = f2bf(v0.x); a[1] = f2bf(v0.y); a[2] = f2bf(v0.z); a[3] = f2bf(v0.w);
        a[4] = f2bf(v1.x); a[5] = f2bf(v1.y); a[6] = f2bf(v1.z); a[7] = f2bf(v1.w);
#pragma unroll
        for (int j = 0; j < 8; j++) b[j] = f2bf(Wt[(k0 + j) * HID_F + w * 16 + lr]);
        acc = __builtin_amdgcn_mfma_f32_16x16x32_bf16(a, b, acc, 0, 0, 0);
    }
#pragma unroll
    for (int r = 0; r < 4; r++) tile[lk * 4 + r][w * 16 + lr] = acc[r];
    __syncthreads();
#pragma unroll
    for (int q = 0; q < 4; q++) {
        int e = q * 256 + threadIdx.x;
        int node = e >> 6, c = e & 63;
        feat1[((size_t)t * N_NODES + base + node) * HID_F + c] = __float2bfloat16(tile[node][c]);
        if (t == 0) h1[(size_t)(base + node) * HID_F + c] = wbuf[64 + c];
    }
    float alv = al1[t * HID_F + lane], arv = ar1[t * HID_F + lane];
#pragma unroll
    for (int q = 0; q < 4; q++) {
        int node = w * 4 + q;
        float f = tile[node][lane];
        float vl = wred_sum(f * alv);
        float vr = wred_sum(f * arv);
        if (lane == 0) {
            el1[t * N_NODES + base + node] = vl;
            er1[t * N_NODES + base + node] = vr;
        }
    }
}

// ==== bucketed CSR build (no global atomics, no random HBM RMW) ====

__global__ __launch_bounds__(256) void k_bcount(const int* __restrict__ edges,
                                                int* __restrict__ hist) {
    int t = blockIdx.y, c = blockIdx.x;
    __shared__ int hl[NBKT];
    if (threadIdx.x < NBKT) hl[threadIdx.x] = 0;
    __syncthreads();
    const int* dst = edges + (t * 2 + 1) * N_EDGES;
    int e0 = c * CHK, e1 = min(e0 + CHK, N_EDGES);
    for (int i = e0 + threadIdx.x; i < e1; i += 256)
        atomicAdd(&hl[dst[i] >> BSH], 1);
    __syncthreads();
    if (threadIdx.x < NBKT) hist[t * HTOT + threadIdx.x * NCHK + c] = hl[threadIdx.x];
}

__global__ __launch_bounds__(1024) void k_bscan(int* __restrict__ hist) {
    int t = blockIdx.x;
    int* H = hist + t * HTOT;
    __shared__ int ws[16];
    __shared__ int carry;
    if (threadIdx.x == 0) carry = 0;
    __syncthreads();
    int lane = threadIdx.x & 63, wid = threadIdx.x >> 6;
    for (int base = 0; base < HTOT; base += 1024) {
        int i = base + threadIdx.x;
        int v = (i < HTOT) ? H[i] : 0;
        int sc = v;
#pragma unroll
        for (int o = 1; o < 64; o <<= 1) { int u = __shfl_up(sc, o); if (lane >= o) sc += u; }
        if (lane == 63) ws[wid] = sc;
        __syncthreads();
        if (wid == 0 && lane < 16) {
            int wv = ws[lane];
#pragma unroll
            for (int o = 1; o < 16; o <<= 1) { int u = __shfl_up(wv, o); if (lane >= o) wv += u; }
            ws[lane] = wv;
        }
        __syncthreads();
        int woff = (wid == 0) ? 0 : ws[wid - 1];
        if (i < HTOT) H[i] = carry + woff + sc - v;  // exclusive
        int tot = ws[15];
        __syncthreads();
        if (threadIdx.x == 0) carry += tot;
        __syncthreads();
    }
}

__global__ __launch_bounds__(256) void k_bscatter(const int* __restrict__ edges,
                                                  const int* __restrict__ hist,
                                                  int2* __restrict__ bedge) {
    int t = blockIdx.y, c = blockIdx.x;
    __shared__ int cur[NBKT];
    if (threadIdx.x < NBKT) cur[threadIdx.x] = hist[t * HTOT + threadIdx.x * NCHK + c];
    __syncthreads();
    const int* srcp = edges + (t * 2 + 0) * N_EDGES;
    const int* dstp = edges + (t * 2 + 1) * N_EDGES;
    int2* be = bedge + (size_t)t * N_EDGES;
    int e0 = c * CHK, e1 = min(e0 + CHK, N_EDGES);
    for (int i = e0 + threadIdx.x; i < e1; i += 256) {
        int d = dstp[i], s = srcp[i];
        int pos = atomicAdd(&cur[d >> BSH], 1);
        be[pos] = make_int2(s, d);
    }
}

__global__ __launch_bounds__(512) void k_bfinal(const int* __restrict__ hist,
                                                const int2* __restrict__ bedge,
                                                int* __restrict__ deg, int* __restrict__ rowptr,
                                                int* __restrict__ csr_src) {
    int t = blockIdx.y, b = blockIdx.x;
    int n0 = b << BSH;
    int nn = min(512, N_NODES - n0);
    __shared__ int degl[512], curl[512], ws[8];
    degl[threadIdx.x] = 0;
    __syncthreads();
    int base = hist[t * HTOT + b * NCHK];
    int end  = (b == NBKT - 1) ? N_EDGES : hist[t * HTOT + (b + 1) * NCHK];
    const int2* be = bedge + (size_t)t * N_EDGES;
    for (int e = base + threadIdx.x; e < end; e += 512)
        atomicAdd(&degl[be[e].y - n0], 1);
    __syncthreads();
    int v = degl[threadIdx.x];
    int lane = threadIdx.x & 63, wid = threadIdx.x >> 6;
    int sc = v;
#pragma unroll
    for (int o = 1; o < 64; o <<= 1) { int u = __shfl_up(sc, o); if (lane >= o) sc += u; }
    if (lane == 63) ws[wid] = sc;
    __syncthreads();
    if (wid == 0 && lane < 8) {
        int wv = ws[lane];
#pragma unroll
        for (int o = 1; o < 8; o <<= 1) { int u = __shfl_up(wv, o); if (lane >= o) wv += u; }
        ws[lane] = wv;
    }
    __syncthreads();
    int excl = ((wid == 0) ? 0 : ws[wid - 1]) + sc - v;
    if (threadIdx.x < nn) {
        rowptr[t * N_NODES + n0 + threadIdx.x] = base + excl;
        deg[t * N_NODES + n0 + threadIdx.x] = v;
    }
    curl[threadIdx.x] = base + excl;
    __syncthreads();
    for (int e = base + threadIdx.x; e < end; e += 512) {
        int2 ed = be[e];
        int pos = atomicAdd(&curl[ed.y - n0], 1);
        csr_src[t * N_EDGES + pos] = ed.x;
    }
}

// ---- fused layer-1 softmax+gather, 2 NODES PER WAVE, 4-chain ILP
__global__ __launch_bounds__(256) void k_sg1(
    const __hip_bfloat16* __restrict__ feat1, const float* __restrict__ el1,
    const float* __restrict__ er1, const int* __restrict__ rowptr,
    const int* __restrict__ deg, const int* __restrict__ cs_all,
    float* __restrict__ h1) {
    __shared__ float xfer[8][HID_F];
    int t = blockIdx.y;
    int w = threadIdx.x >> 6;
    int lane = threadIdx.x & 63;
    int nh = lane >> 5, sub = lane & 31;
    int g = sub >> 3, i = sub & 7;
    int n = blockIdx.x * 8 + w * 2 + nh;
    int beg = rowptr[t * N_NODES + n], cnt = deg[t * N_NODES + n];
    if (cnt > 0) {  // half-wave-uniform condition
        const int* cs = cs_all + t * N_EDGES + beg;
        const float* el = el1 + t * N_NODES;
        float ern = er1[t * N_NODES + n];
        const unsigned short* ft = (const unsigned short*)feat1 + (size_t)t * N_NODES * HID_F;
        f32x2 acc2[4];
#pragma unroll
        for (int j = 0; j < 4; j++) acc2[j] = (f32x2){0.f, 0.f};
        float sacc = 0.f;
        for (int c0 = 0; c0 < cnt; c0 += 16) {
            int e0 = c0 + g, e1 = c0 + 4 + g, e2 = c0 + 8 + g, e3 = c0 + 12 + g;
            bool v0 = e0 < cnt, v1 = e1 < cnt, v2 = e2 < cnt, v3 = e3 < cnt;
            int s0 = cs[v0 ? e0 : 0];
            int s1 = cs[v1 ? e1 : 0];
            int s2 = cs[v2 ? e2 : 0];
            int s3 = cs[v3 ? e3 : 0];
            float p0 = v0 ? __expf(lrelu(el[s0] + ern)) : 0.f;
            float p1 = v1 ? __expf(lrelu(el[s1] + ern)) : 0.f;
            float p2 = v2 ? __expf(lrelu(el[s2] + ern)) : 0.f;
            float p3 = v3 ? __expf(lrelu(el[s3] + ern)) : 0.f;
            uint4 u0 = *(const uint4*)(ft + (size_t)s0 * HID_F + i * 8);
            uint4 u1 = *(const uint4*)(ft + (size_t)s1 * HID_F + i * 8);
            uint4 u2 = *(const uint4*)(ft + (size_t)s2 * HID_F + i * 8);
            uint4 u3 = *(const uint4*)(ft + (size_t)s3 * HID_F + i * 8);
            f32x2 pv0 = {p0, p0}, pv1 = {p1, p1}, pv2 = {p2, p2}, pv3 = {p3, p3};
            acc2[0] += pv0 * bfpair(u0.x) + pv1 * bfpair(u1.x);
            acc2[1] += pv0 * bfpair(u0.y) + pv1 * bfpair(u1.y);
            acc2[2] += pv0 * bfpair(u0.z) + pv1 * bfpair(u1.z);
            acc2[3] += pv0 * bfpair(u0.w) + pv1 * bfpair(u1.w);
            acc2[0] += pv2 * bfpair(u2.x) + pv3 * bfpair(u3.x);
            acc2[1] += pv2 * bfpair(u2.y) + pv3 * bfpair(u3.y);
            acc2[2] += pv2 * bfpair(u2.z) + pv3 * bfpair(u3.z);
            acc2[3] += pv2 * bfpair(u2.w) + pv3 * bfpair(u3.w);
            sacc += (p0 + p1) + (p2 + p3);
        }
        float acc[8];
#pragma unroll
        for (int j = 0; j < 4; j++) { acc[2 * j] = acc2[j].x; acc[2 * j + 1] = acc2[j].y; }
#pragma unroll
        for (int o = 8; o < 32; o <<= 1) {  // reduce over g only (bits 3,4)
#pragma unroll
            for (int j = 0; j < 8; j++) acc[j] += __shfl_xor(acc[j], o);
            sacc += __shfl_xor(sacc, o);
        }
        if (g == 0) {
            float inv = 0.25f / sacc;
#pragma unroll
            for (int j = 0; j < 8; j++) xfer[w * 2 + nh][i * 8 + j] = acc[j] * inv;
        }
    }
    __syncthreads();
    if (cnt > 0) {
        atomicAdd(&h1[(size_t)n * HID_F + sub], xfer[w * 2 + nh][sub]);
        atomicAdd(&h1[(size_t)n * HID_F + sub + 32], xfer[w * 2 + nh][sub + 32]);
    }
}

// ---- layer-2 featurization: packed row2[t][n] = float4(f0,f1,f2,el); er2 separate
__global__ __launch_bounds__(256) void k_feat2(
    const float* __restrict__ h1, const float* __restrict__ W2,
    const float* __restrict__ al2, const float* __restrict__ ar2,
    float4* __restrict__ row2, float* __restrict__ er2) {
    __shared__ float Wl[T_G * HID_F * OUT_F];
    __shared__ float Al[T_G * OUT_F], Ar[T_G * OUT_F];
    for (int i = threadIdx.x; i < T_G * HID_F * OUT_F; i += 256) Wl[i] = W2[i];
    if (threadIdx.x < T_G * OUT_F) { Al[threadIdx.x] = al2[threadIdx.x]; Ar[threadIdx.x] = ar2[threadIdx.x]; }
    __syncthreads();
    int n = blockIdx.x * 256 + threadIdx.x;
    if (n >= N_NODES) return;
    float h[HID_F];
    const float4* hp = (const float4*)(h1 + n * HID_F);
#pragma unroll
    for (int i = 0; i < 16; i++) {
        float4 v = hp[i];
        h[4 * i] = v.x; h[4 * i + 1] = v.y; h[4 * i + 2] = v.z; h[4 * i + 3] = v.w;
    }
    for (int t = 0; t < T_G; t++) {
        float f0 = 0.f, f1 = 0.f, f2 = 0.f;
#pragma unroll
        for (int k = 0; k < HID_F; k++) {
            float hv = h[k];
            f0 += hv * Wl[(t * HID_F + k) * 3 + 0];
            f1 += hv * Wl[(t * HID_F + k) * 3 + 1];
            f2 += hv * Wl[(t * HID_F + k) * 3 + 2];
        }
        float el = f0 * Al[t * 3] + f1 * Al[t * 3 + 1] + f2 * Al[t * 3 + 2];
        row2[t * N_NODES + n] = make_float4(f0, f1, f2, el);
        er2[t * N_NODES + n] = f0 * Ar[t * 3] + f1 * Ar[t * 3 + 1] + f2 * Ar[t * 3 + 2];
    }
}

// ---- fused d=3 aggregation (max-free): 4 nodes per wave, 16 lanes per node,
//      2x-unrolled edge loop, intra-group butterfly, atomicAdd into pre-biased hout
__global__ __launch_bounds__(256) void k_gat3f(
    const float4* __restrict__ row, const float* __restrict__ er_,
    const int* __restrict__ rowptr, const int* __restrict__ deg, const int* __restrict__ csr_src,
    const float* __restrict__ wv, float* __restrict__ hout) {
    int t = blockIdx.y;
    int lane = threadIdx.x & 63;
    int w = threadIdx.x >> 6;
    int nq = lane >> 4, e = lane & 15;
    int n = blockIdx.x * 16 + w * 4 + nq;  // 3125*16 == 50000 exact
    int beg = rowptr[t * N_NODES + n], cnt = deg[t * N_NODES + n];
    if (cnt == 0) return;  // group-uniform (16-lane groups share n)
    float erh = er_[t * N_NODES + n];
    const int* cs = csr_src + t * N_EDGES;
    const float4* rt = row + t * N_NODES;
    float s_run = 0.f, a0 = 0.f, a1 = 0.f, a2 = 0.f;
    for (int idx = e; idx < cnt; idx += 32) {
        int i1 = idx + 16;
        bool v1 = i1 < cnt;
        int s0 = cs[beg + idx];
        int s1 = cs[beg + (v1 ? i1 : idx)];
        float4 r0 = rt[s0];
        float4 r1 = rt[s1];
        float p0 = __expf(lrelu(r0.w + erh));
        float p1 = v1 ? __expf(lrelu(r1.w + erh)) : 0.f;
        a0 += p0 * r0.x + p1 * r1.x;
        a1 += p0 * r0.y + p1 * r1.y;
        a2 += p0 * r0.z + p1 * r1.z;
        s_run += p0 + p1;
    }
#pragma unroll
    for (int o = 1; o < 16; o <<= 1) {  // xor<16 stays within the 16-lane group
        a0 += __shfl_xor(a0, o);
        a1 += __shfl_xor(a1, o);
        a2 += __shfl_xor(a2, o);
        s_run += __shfl_xor(s_run, o);
    }
    if (e < 3) {
        float v = (e == 0) ? a0 : (e == 1) ? a1 : a2;
        atomicAdd(&hout[n * 3 + e], wv[t] * v / s_run);
    }
}

// ---- layer-3 featurization (3->3): packed row3 + er3
__global__ void k_feat3(const float* __restrict__ h2, const float* __restrict__ W3,
                        const float* __restrict__ al3, const float* __restrict__ ar3,
                        float4* __restrict__ row3, float* __restrict__ er3) {
    int n = blockIdx.x * 256 + threadIdx.x;
    if (n >= N_NODES) return;
    float h0 = h2[n * 3], h1v = h2[n * 3 + 1], h2v = h2[n * 3 + 2];
    for (int t = 0; t < T_G; t++) {
        float f[3], el = 0.f, er = 0.f;
#pragma unroll
        for (int d = 0; d < 3; d++) {
            f[d] = h0 * W3[(t * 3 + 0) * 3 + d] + h1v * W3[(t * 3 + 1) * 3 + d] + h2v * W3[(t * 3 + 2) * 3 + d];
            el += f[d] * al3[t * 3 + d];
            er += f[d] * ar3[t * 3 + d];
        }
        row3[t * N_NODES + n] = make_float4(f[0], f[1], f[2], el);
        er3[t * N_NODES + n] = er;
    }
}

// ---- layer-M featurization: rowM[t][n][32] bf16 with [h*4+{0,1,2}]=f, [h*4+3]=el; erM f32
__global__ void k_featM(const float* __restrict__ h3, const float* __restrict__ WM,
                        const float* __restrict__ alM, const float* __restrict__ arM,
                        __hip_bfloat16* __restrict__ rowM, float* __restrict__ erM) {
    int n = blockIdx.x * 256 + threadIdx.x;
    if (n >= N_NODES) return;
    float h0 = h3[n * 3], h1v = h3[n * 3 + 1], h2v = h3[n * 3 + 2];
    for (int t = 0; t < T_G; t++) {
        int nb = t * N_NODES + n;
        size_t rb = (size_t)nb * 32;
#pragma unroll
        for (int hh = 0; hh < H_M; hh++) {
            float el = 0.f, er = 0.f;
#pragma unroll
            for (int d = 0; d < 3; d++) {
                int j = hh * 3 + d;
                float f = h0 * WM[(t * 3 + 0) * 24 + j] + h1v * WM[(t * 3 + 1) * 24 + j] + h2v * WM[(t * 3 + 2) * 24 + j];
                rowM[rb + hh * 4 + d] = __float2bfloat16(f);
                el += f * alM[(t * H_M + hh) * 3 + d];
                er += f * arM[(t * H_M + hh) * 3 + d];
            }
            rowM[rb + hh * 4 + 3] = __float2bfloat16(el);
            erM[nb * 8 + hh] = er;
        }
    }
}

// ---- fused layer-M aggregation (max-free): 2 NODES PER WAVE, lane=(nh, eo in [0,4), h),
//      2x-unrolled (8 edge-slots/node/iter), butterfly over eo (offsets 8,16 within half)
__global__ __launch_bounds__(256) void k_aggMf(
    const __hip_bfloat16* __restrict__ rowM, const float* __restrict__ erM,
    const int* __restrict__ rowptr, const int* __restrict__ deg, const int* __restrict__ csr_src,
    const float* __restrict__ wv, float* __restrict__ hM) {
    int t = blockIdx.y;
    int w = threadIdx.x >> 6;
    int lane = threadIdx.x & 63;
    int nh = lane >> 5, sub = lane & 31;
    int h = sub & 7, eo = sub >> 3;  // eo in [0,4)
    int n = blockIdx.x * 8 + w * 2 + nh;
    int beg = rowptr[t * N_NODES + n], cnt = deg[t * N_NODES + n];
    if (cnt == 0) return;  // half-wave-uniform
    float erh = erM[(t * N_NODES + n) * 8 + h];
    const int* cs = csr_src + t * N_EDGES;
    const unsigned short* rt = (const unsigned short*)rowM + (size_t)t * N_NODES * 32;
    float s_run = 0.f, a0 = 0.f, a1 = 0.f, a2 = 0.f;
    for (int idx = eo; idx < cnt; idx += 8) {
        int i1 = idx + 4;
        bool v1 = i1 < cnt;
        int s0 = cs[beg + idx];
        int s1 = cs[beg + (v1 ? i1 : idx)];
        ushort4 u0 = *(const ushort4*)(rt + (size_t)s0 * 32 + h * 4);
        ushort4 u1 = *(const ushort4*)(rt + (size_t)s1 * 32 + h * 4);
        float p0 = __expf(lrelu(bf2f(u0.w) + erh));
        float p1 = v1 ? __expf(lrelu(bf2f(u1.w) + erh)) : 0.f;
        a0 += p0 * bf2f(u0.x) + p1 * bf2f(u1.x);
        a1 += p0 * bf2f(u0.y) + p1 * bf2f(u1.y);
        a2 += p0 * bf2f(u0.z) + p1 * bf2f(u1.z);
        s_run += p0 + p1;
    }
#pragma unroll
    for (int o = 8; o < 32; o <<= 1) {  // reduce over eo only (bits 3,4), within half
        a0 += __shfl_xor(a0, o);
        a1 += __shfl_xor(a1, o);
        a2 += __shfl_xor(a2, o);
        s_run += __shfl_xor(s_run, o);
    }
    if (eo == 0) {
        float inv = wv[t] / s_run;
        atomicAdd(&hM[n * 24 + h * 3 + 0], inv * a0);
        atomicAdd(&hM[n * 24 + h * 3 + 1], inv * a1);
        atomicAdd(&hM[n * 24 + h * 3 + 2], inv * a2);
    }
}

// ---- delta norms per head (no histogram — atomics moved to LDS-privatized k_hist1)
__global__ void k_norms(const float* __restrict__ hM, float* __restrict__ norms) {
    int idx = blockIdx.x * 256 + threadIdx.x;
    if (idx >= N_NODES * H_M) return;
    int n = idx >> 3, hh = idx & 7;
    float s = 0.f;
#pragma unroll
    for (int d = 0; d < 3; d++) {
        float cur = hM[n * 24 + hh * 3 + d];
        float prev = (n > 0) ? hM[(n - 1) * 24 + hh * 3 + d] : 0.f;
        float dx = cur - prev;
        s += dx * dx;
    }
    norms[hh * N_NODES + n] = sqrtf(s);
}

// ---- level-1 histogram: bits [31:20] (4096 bins), LDS-privatized per block.
//      grid (32, 8): blockIdx.y = head, blockIdx.x = node chunk
#define NCHUNK 32
#define CHNK_N ((N_NODES + NCHUNK - 1) / NCHUNK)  // 1563
__global__ __launch_bounds__(256) void k_hist1(const float* __restrict__ norms,
                                               unsigned int* __restrict__ hist1g) {
    __shared__ unsigned int hl[4096];
    int hh = blockIdx.y, c = blockIdx.x;
    for (int j = threadIdx.x; j < 4096; j += 256) hl[j] = 0u;
    __syncthreads();
    int i0 = c * CHNK_N, i1 = min(i0 + CHNK_N, N_NODES);
    const float* v = norms + (size_t)hh * N_NODES;
    for (int i = i0 + threadIdx.x; i < i1; i += 256) {
        unsigned int u = __float_as_uint(v[i]);
        atomicAdd(&hl[u >> 20], 1u);
    }
    __syncthreads();
    unsigned int* Hg = hist1g + (size_t)hh * 4096;
    for (int j = threadIdx.x; j < 4096; j += 256)
        if (hl[j]) atomicAdd(&Hg[j], hl[j]);
}

__device__ __forceinline__ unsigned int blk_exscan(unsigned int v) {
    int lane = threadIdx.x & 63, wid = threadIdx.x >> 6;
    unsigned int sc = v;
#pragma unroll
    for (int o = 1; o < 64; o <<= 1) { unsigned int u = __shfl_up(sc, o); if (lane >= o) sc += u; }
    __shared__ unsigned int ws[4];
    if (lane == 63) ws[wid] = sc;
    __syncthreads();
    unsigned int woff = 0;
    for (int w = 0; w < wid; w++) woff += ws[w];
    __syncthreads();
    return woff + sc - v;
}

// ---- level-1 select among 4096 bins -> selbin1 (bits 31:20), resrank1
__global__ __launch_bounds__(256) void k_find1(
    const unsigned int* __restrict__ hist1g, int* __restrict__ selbin1, int* __restrict__ resrank1) {
    int hh = blockIdx.x >> 1, k = blockIdx.x & 1;
    unsigned int rank = N_NODES / 2 - 1 + k;  // 24999 / 25000
    const unsigned int* H = hist1g + (size_t)hh * 4096;
    int tid = threadIdx.x;
    unsigned int local = 0;
    for (int j = 0; j < 16; j++) local += H[tid * 16 + j];
    unsigned int excl = blk_exscan(local);
    if (rank >= excl && rank < excl + local) {
        unsigned int cum = excl;
        for (int j = 0; j < 16; j++) {
            unsigned int c = H[tid * 16 + j];
            if (cum + c > rank) {
                selbin1[hh * 2 + k] = tid * 16 + j;
                resrank1[hh * 2 + k] = (int)(rank - cum);
                break;
            }
            cum += c;
        }
    }
}

// ---- level-2 histogram: bits [19:4] (65536 bins), restricted to selected top-12 bin
__global__ void k_h2(const float* __restrict__ norms, const int* __restrict__ selbin1,
                     unsigned int* __restrict__ hist2) {
    int idx = blockIdx.x * 256 + threadIdx.x;
    if (idx >= N_NODES * H_M) return;
    int hh = idx / N_NODES;
    unsigned int u = __float_as_uint(norms[idx]);
    int top = (int)(u >> 20);
#pragma unroll
    for (int k = 0; k < 2; k++)
        if (top == selbin1[hh * 2 + k])
            atomicAdd(&hist2[(size_t)(hh * 2 + k) * 65536 + ((u >> 4) & 0xFFFFu)], 1u);
}

// ---- level-2 select among 65536 bins -> selbin2 (bits 19:4), resrank2
__global__ __launch_bounds__(256) void k_find2(
    const unsigned int* __restrict__ hist2, const int* __restrict__ resrank1,
    int* __restrict__ selbin2, int* __restrict__ resrank2) {
    int hh = blockIdx.x >> 1, k = blockIdx.x & 1;
    unsigned int rank = (unsigned int)resrank1[hh * 2 + k];
    const unsigned int* H = hist2 + (size_t)(hh * 2 + k) * 65536;
    int tid = threadIdx.x;
    unsigned int local = 0;
    for (int j = 0; j < 256; j++) local += H[tid * 256 + j];
    unsigned int excl = blk_exscan(local);
    if (rank >= excl && rank < excl + local) {
        unsigned int cum = excl;
        for (int j = 0; j < 256; j++) {
            unsigned int c = H[tid * 256 + j];
            if (cum + c > rank) {
                selbin2[hh * 2 + k] = tid * 256 + j;
                resrank2[hh * 2 + k] = (int)(rank - cum);
                break;
            }
            cum += c;
        }
    }
}

// ---- level-3 histogram: bits [3:0] (16 bins), restricted to selected 28-bit prefix
__global__ void k_h3(const float* __restrict__ norms, const int* __restrict__ selbin1,
                     const int* __restrict__ selbin2, unsigned int* __restrict__ hist3) {
    int idx = blockIdx.x * 256 + threadIdx.x;
    if (idx >= N_NODES * H_M) return;
    int hh = idx / N_NODES;
    unsigned int u = __float_as_uint(norms[idx]);
#pragma unroll
    for (int k = 0; k < 2; k++) {
        unsigned int pref = ((unsigned int)selbin1[hh * 2 + k] << 16) | (unsigned int)selbin2[hh * 2 + k];
        if ((u >> 4) == pref)
            atomicAdd(&hist3[(hh * 2 + k) * 16 + (u & 15u)], 1u);
    }
}

// ---- level-3 select (16 bins) -> exact order statistics
__global__ void k_find3(const unsigned int* __restrict__ hist3, const int* __restrict__ selbin1,
                        const int* __restrict__ selbin2, const int* __restrict__ resrank2,
                        float* __restrict__ medpair) {
    int hh = blockIdx.x >> 1, k = blockIdx.x & 1;
    if (threadIdx.x != 0) return;
    unsigned int rank = (unsigned int)resrank2[hh * 2 + k];
    const unsigned int* H = hist3 + (hh * 2 + k) * 16;
    unsigned int cum = 0;
    for (int b = 0; b < 16; b++) {
        unsigned int c = H[b];
        if (cum + c > rank) {
            unsigned int u = ((unsigned int)selbin1[hh * 2 + k] << 20)
                           | ((unsigned int)selbin2[hh * 2 + k] << 4) | (unsigned int)b;
            medpair[hh * 2 + k] = __uint_as_float(u);
            return;
        }
        cum += c;
    }
}

__global__ void k_final(const float* __restrict__ hM, const float* __restrict__ medpair,
                        const float* __restrict__ noise, float* __restrict__ out) {
    int idx = blockIdx.x * 256 + threadIdx.x;
    if (idx >= N_NODES * 24) return;
    int hh = (idx / 3) & 7;
    float med = 0.5f * (medpair[hh * 2] + medpair[hh * 2 + 1]) + 1e-4f;
    float v = hM[idx] / med;
    if (isnan(v)) v = 0.f;
    else if (isinf(v)) v = v > 0.f ? 100.f : -100.f;
    out[idx] = v + 0.3f * noise[idx];
}

extern "C" void kernel_launch(void* const* d_in, const int* in_sizes, int n_in,
                              void* d_out, int out_size, void* d_ws, size_t ws_size,
                              hipStream_t stream) {
    const float* x     = (const float*)d_in[0];
    const int*   edges = (const int*)d_in[1];
    const float* noise = (const float*)d_in[2];
    const float* W1  = (const float*)d_in[3];
    const float* al1 = (const float*)d_in[4];
    const float* ar1 = (const float*)d_in[5];
    const float* b1  = (const float*)d_in[6];
    const float* W2  = (const float*)d_in[7];
    const float* al2 = (const float*)d_in[8];
    const float* ar2 = (const float*)d_in[9];
    const float* b2  = (const float*)d_in[10];
    const float* W3  = (const float*)d_in[11];
    const float* al3 = (const float*)d_in[12];
    const float* ar3 = (const float*)d_in[13];
    const float* b3  = (const float*)d_in[14];
    const float* WM  = (const float*)d_in[15];
    const float* alM = (const float*)d_in[16];
    const float* arM = (const float*)d_in[17];
    const float* bM  = (const float*)d_in[18];
    const float* fc2 = (const float*)d_in[19];
    const float* fc3 = (const float*)d_in[20];
    float* out = (float*)d_out;

    char* basep = (char*)d_ws;
    size_t off = 0;
    auto alloc = [&](size_t bytes) -> void* {
        void* p = basep + off;
        off += (bytes + 255) & ~(size_t)255;
        return p;
    };
    // Region A: feat1 bf16 (25.6 MB); rowM (12.8) + erM (6.4) alias it after k_sg1
    char* regA = (char*)alloc((size_t)T_G * N_NODES * HID_F * 2);
    __hip_bfloat16* feat1 = (__hip_bfloat16*)regA;
    __hip_bfloat16* rowM  = (__hip_bfloat16*)regA;                 // T*N*32 bf16 = 12.8MB
    float*          erM   = (float*)(regA + 12800000);             // T*N*8 f32 = 6.4MB
    // Region U (25.6MB): bedge (int2, CSR build only)
    char* regU = (char*)alloc((size_t)T_G * N_EDGES * 8);
    int2*  bedge = (int2*)regU;
    float* el1 = (float*)alloc((size_t)T_G * N_NODES * 4);
    float* er1 = (float*)alloc((size_t)T_G * N_NODES * 4);
    float* h1  = (float*)alloc((size_t)N_NODES * HID_F * 4);
    float4* row2 = (float4*)alloc((size_t)T_G * N_NODES * 16);
    float* er2 = (float*)alloc((size_t)T_G * N_NODES * 4);
    float* h2  = (float*)alloc((size_t)N_NODES * 3 * 4);
    float4* row3 = (float4*)alloc((size_t)T_G * N_NODES * 16);
    float* er3 = (float*)alloc((size_t)T_G * N_NODES * 4);
    float* h3  = (float*)alloc((size_t)N_NODES * 3 * 4);
    float* hM  = (float*)alloc((size_t)N_NODES * 24 * 4);
    float* norms = (float*)alloc((size_t)H_M * N_NODES * 4);
    float* medpair = (float*)alloc(64);
    float* wbuf = (float*)alloc(512);
    int* deg    = (int*)alloc((size_t)T_G * N_NODES * 4);
    int* rowptr = (int*)alloc((size_t)T_G * N_NODES * 4);
    int* hist   = (int*)alloc((size_t)T_G * HTOT * 4);       // 307KB
    int* csr_src = (int*)alloc((size_t)T_G * N_EDGES * 4);
    unsigned int* hist1g = (unsigned int*)alloc((size_t)H_M * 4096 * 4);      // 128KB
    unsigned int* hist2 = (unsigned int*)alloc((size_t)H_M * 2 * 65536 * 4);  // 4MB
    unsigned int* hist3 = (unsigned int*)alloc((size_t)H_M * 2 * 16 * 4);     // 1KB
    int* selbin1  = (int*)alloc(64);
    int* resrank1 = (int*)alloc(64);
    int* selbin2  = (int*)alloc(64);
    int* resrank2 = (int*)alloc(64);

    const int NB = (N_NODES + 255) / 256;   // 196
    const int NW8 = N_NODES / 8;            // 6250 (8 nodes per block, 2 per wave)
    const int NG = N_NODES / 16;            // 3125 (16 nodes per block)
    const int NE8 = (N_NODES * H_M + 255) / 256;

    hipMemsetAsync(hist1g, 0, (size_t)H_M * 4096 * 4, stream);
    hipMemsetAsync(hist2, 0, (size_t)H_M * 2 * 65536 * 4, stream);
    hipMemsetAsync(hist3, 0, (size_t)H_M * 2 * 16 * 4, stream);

    k_wvec<<<1, 128, 0, stream>>>(fc2, fc3, b1, b2, b3, bM, wbuf);
    k_init_all<<<(N_NODES * 24 + 255) / 256, 256, 0, stream>>>(wbuf, h2, h3, hM);

    // Bucketed CSR build (no global atomics)
    k_bcount<<<dim3(NCHK, T_G), 256, 0, stream>>>(edges, hist);
    k_bscan<<<T_G, 1024, 0, stream>>>(hist);
    k_bscatter<<<dim3(NCHK, T_G), 256, 0, stream>>>(edges, hist, bedge);
    k_bfinal<<<dim3(NBKT, T_G), 512, 0, stream>>>(hist, bedge, deg, rowptr, csr_src);

    // Layer 1 (MFMA GEMM with fused h1 bias-init; 2-node/wave fused softmax/gather)
    k_gemm1<<<dim3(N_NODES / 16, T_G), 256, 0, stream>>>(x, W1, al1, ar1, wbuf, feat1, el1, er1, h1);
    k_sg1<<<dim3(NW8, T_G), 256, 0, stream>>>(feat1, el1, er1, rowptr, deg, csr_src, h1);

    // Layer 2 (fused softmax+gather, 4 nodes/wave)
    k_feat2<<<NB, 256, 0, stream>>>(h1, W2, al2, ar2, row2, er2);
    k_gat3f<<<dim3(NG, T_G), 256, 0, stream>>>(row2, er2, rowptr, deg, csr_src, wbuf + 0, h2);

    // Layer 3 (fused)
    k_feat3<<<NB, 256, 0, stream>>>(h2, W3, al3, ar3, row3, er3);
    k_gat3f<<<dim3(NG, T_G), 256, 0, stream>>>(row3, er3, rowptr, deg, csr_src, wbuf + 4, h3);

    // Layer M (fused, 2 nodes/wave; rowM/erM alias feat1 region — feat1 dead after k_sg1)
    k_featM<<<NB, 256, 0, stream>>>(h3, WM, alM, arM, rowM, erM);
    k_aggMf<<<dim3(NW8, T_G), 256, 0, stream>>>(rowM, erM, rowptr, deg, csr_src, wbuf + 4, hM);

    // norm_ (telescoped): contention-free 3-level exact median select
    k_norms<<<NE8, 256, 0, stream>>>(hM, norms);
    k_hist1<<<dim3(NCHUNK, H_M), 256, 0, stream>>>(norms, hist1g);
    k_find1<<<16, 256, 0, stream>>>(hist1g, selbin1, resrank1);
    k_h2<<<NE8, 256, 0, stream>>>(norms, selbin1, hist2);
    k_find2<<<16, 256, 0, stream>>>(hist2, resrank1, selbin2, resrank2);
    k_h3<<<NE8, 256, 0, stream>>>(norms, selbin1, selbin2, hist3);
    k_find3<<<16, 64, 0, stream>>>(hist3, selbin1, selbin2, resrank2, medpair);
    k_final<<<(N_NODES * 24 + 255) / 256, 256, 0, stream>>>(hM, medpair, noise, out);
}